// Round 2
// baseline (14154.752 us; speedup 1.0000x reference)
//
#include <hip/hip_runtime.h>

#define B_   2048
#define T_   120
#define E_   144
#define L_   4
#define NH_  8
#define HD_  18
#define FF_  576
#define H_   144
#define GIN_ 288
#define TH_  432   // 3*E = 3*H
#define FUT_ 24
#define BT_  (B_*T_)

typedef unsigned short u16;
typedef unsigned int   u32;

__device__ __forceinline__ float bf2f(u16 u) {
    u32 x = ((u32)u) << 16;
    return __uint_as_float(x);
}
__device__ __forceinline__ u16 f2bf(float f) {
    u32 x = __float_as_uint(f);
    u32 r = (x + 0x7fffu + ((x >> 16) & 1u)) >> 16;
    return (u16)r;
}

struct F4 { float x, y, z, w; };

__device__ __forceinline__ F4 load4(const float* p) {
    float4 v = *(const float4*)p;
    return {v.x, v.y, v.z, v.w};
}
__device__ __forceinline__ F4 load4(const u16* p) {
    ushort4 v = *(const ushort4*)p;
    return {bf2f(v.x), bf2f(v.y), bf2f(v.z), bf2f(v.w)};
}
__device__ __forceinline__ void store1(float* p, float v) { *p = v; }
__device__ __forceinline__ void store1(u16* p, float v)   { *p = f2bf(v); }

// ---------------- generic GEMM: C[M,N] = A[M,K] @ W[N,K]^T (+bias)(+res)(relu) ----
// M must be a multiple of 64. K must be a multiple of 16. N arbitrary (guarded).
template<typename AT, typename OT, bool BIAS, bool RELU, bool RES>
__global__ __launch_bounds__(256) void gemm_kernel(
    const AT* __restrict__ A, const float* __restrict__ W, int ldw,
    const float* __restrict__ bias, const float* __restrict__ res,
    OT* __restrict__ C, int M, int N, int K)
{
    constexpr int BM = 64, BN = 64, BK = 16;
    __shared__ float As[BK][BM + 4];
    __shared__ float Ws[BK][BN + 4];
    const int tid = threadIdx.x;
    const int bm = blockIdx.y * BM;
    const int bn = blockIdx.x * BN;
    const int tx = tid & 15, ty = tid >> 4;
    const int lr = tid >> 2;          // 0..63
    const int lc = (tid & 3) << 2;    // 0,4,8,12

    float acc[4][4];
#pragma unroll
    for (int i = 0; i < 4; i++)
#pragma unroll
        for (int j = 0; j < 4; j++) acc[i][j] = 0.f;

    for (int k0 = 0; k0 < K; k0 += BK) {
        F4 av = load4(A + (size_t)(bm + lr) * K + k0 + lc);
        As[lc + 0][lr] = av.x; As[lc + 1][lr] = av.y;
        As[lc + 2][lr] = av.z; As[lc + 3][lr] = av.w;

        int n = bn + lr;
        F4 wv = {0.f, 0.f, 0.f, 0.f};
        if (n < N) {
            float4 t = *(const float4*)(W + (size_t)n * ldw + k0 + lc);
            wv = {t.x, t.y, t.z, t.w};
        }
        Ws[lc + 0][lr] = wv.x; Ws[lc + 1][lr] = wv.y;
        Ws[lc + 2][lr] = wv.z; Ws[lc + 3][lr] = wv.w;
        __syncthreads();

#pragma unroll
        for (int kk = 0; kk < BK; ++kk) {
            float a[4], wr[4];
#pragma unroll
            for (int i = 0; i < 4; i++) a[i] = As[kk][ty * 4 + i];
#pragma unroll
            for (int j = 0; j < 4; j++) wr[j] = Ws[kk][tx * 4 + j];
#pragma unroll
            for (int i = 0; i < 4; i++)
#pragma unroll
                for (int j = 0; j < 4; j++) acc[i][j] += a[i] * wr[j];
        }
        __syncthreads();
    }

#pragma unroll
    for (int i = 0; i < 4; i++) {
        int m = bm + ty * 4 + i;
#pragma unroll
        for (int j = 0; j < 4; j++) {
            int n = bn + tx * 4 + j;
            if (n < N) {
                float v = acc[i][j];
                if (BIAS) v += bias[n];
                if (RES)  v += res[(size_t)m * N + n];
                if (RELU) v = fmaxf(v, 0.f);
                store1(&C[(size_t)m * N + n], v);
            }
        }
    }
}

// ---------------- attention: one block per (b, head) ---------------------------
__global__ __launch_bounds__(128) void attn_kernel(const u16* __restrict__ qkv,
                                                   u16* __restrict__ o)
{
    const int bh = blockIdx.x;
    const int b = bh >> 3, h = bh & 7;
    __shared__ float ks[T_][HD_];
    __shared__ float vs[T_][HD_];
    const size_t base = (size_t)b * T_ * TH_;
    const int tid = threadIdx.x;
    for (int idx = tid; idx < T_ * HD_; idx += 128) {
        int t = idx / HD_, d = idx % HD_;
        ks[t][d] = bf2f(qkv[base + (size_t)t * TH_ + E_ + h * HD_ + d]);
        vs[t][d] = bf2f(qkv[base + (size_t)t * TH_ + 2 * E_ + h * HD_ + d]);
    }
    __syncthreads();
    if (tid < T_) {
        float q[HD_];
#pragma unroll
        for (int d = 0; d < HD_; d++)
            q[d] = bf2f(qkv[base + (size_t)tid * TH_ + h * HD_ + d]);
        const float scale = 0.23570226039551584f; // 1/sqrt(18)
        float m = -1e30f, l = 0.f;
        for (int j = 0; j < T_; j++) {
            float s = 0.f;
#pragma unroll
            for (int d = 0; d < HD_; d++) s += q[d] * ks[j][d];
            s *= scale;
            if (s > m) { l = l * __expf(m - s) + 1.f; m = s; }
            else       { l += __expf(s - m); }
        }
        float inv_l = 1.f / l;
        float acc[HD_];
#pragma unroll
        for (int d = 0; d < HD_; d++) acc[d] = 0.f;
        for (int j = 0; j < T_; j++) {
            float s = 0.f;
#pragma unroll
            for (int d = 0; d < HD_; d++) s += q[d] * ks[j][d];
            float p = __expf(s * scale - m);
#pragma unroll
            for (int d = 0; d < HD_; d++) acc[d] += p * vs[j][d];
        }
        u16* op = o + ((size_t)b * T_ + tid) * E_ + h * HD_;
#pragma unroll
        for (int d = 0; d < HD_; d++) op[d] = f2bf(acc[d] * inv_l);
    }
}

// ---------------- LayerNorm over rows of 144 (wave per row) --------------------
__global__ __launch_bounds__(256) void ln_kernel(const float* __restrict__ y,
                                                 const float* __restrict__ w,
                                                 const float* __restrict__ bsc,
                                                 float* __restrict__ out, int rows)
{
    int wid = threadIdx.x >> 6, lane = threadIdx.x & 63;
    int row = blockIdx.x * 4 + wid;
    if (row >= rows) return;
    const float* yr = y + (size_t)row * E_;
    float v0 = yr[lane], v1 = yr[lane + 64];
    float v2 = (lane < 16) ? yr[lane + 128] : 0.f;
    float s = v0 + v1 + v2;
    for (int off = 32; off; off >>= 1) s += __shfl_xor(s, off);
    float mean = s * (1.f / 144.f);
    float d0 = v0 - mean, d1 = v1 - mean;
    float d2 = (lane < 16) ? (v2 - mean) : 0.f;
    float q = d0 * d0 + d1 * d1 + d2 * d2;
    for (int off = 32; off; off >>= 1) q += __shfl_xor(q, off);
    float rstd = rsqrtf(q * (1.f / 144.f) + 1e-5f);
    float* orow = out + (size_t)row * E_;
    orow[lane]      = d0 * rstd * w[lane]      + bsc[lane];
    orow[lane + 64] = d1 * rstd * w[lane + 64] + bsc[lane + 64];
    if (lane < 16)
        orow[lane + 128] = d2 * rstd * w[lane + 128] + bsc[lane + 128];
}

// ---------------- mean over T (one chunk of nb batches) -------------------------
__global__ void mean_kernel(const float* __restrict__ x, float* __restrict__ out,
                            int nb)
{
    int idx = blockIdx.x * blockDim.x + threadIdx.x;
    if (idx >= nb * E_) return;
    int b = idx / E_, e = idx % E_;
    const float* p = x + (size_t)b * T_ * E_ + e;
    float s = 0.f;
    for (int t = 0; t < T_; t++) s += p[(size_t)t * E_];
    out[idx] = s * (1.f / 120.f);
}

__global__ void zero_kernel(float* __restrict__ p, int n)
{
    int i = blockIdx.x * blockDim.x + threadIdx.x;
    if (i < n) p[i] = 0.f;
}

__device__ __forceinline__ float sigmoidf_(float x) {
    return 1.f / (1.f + __expf(-x));
}

// ---------------- one GRU decode step (fused) -----------------------------------
__global__ __launch_bounds__(256) void gru_step_kernel(
    const float* __restrict__ inp, int inp_stride,
    const float* __restrict__ gctx,   // [B, 432] = ctx-half of gi + b_ih
    float* __restrict__ h,            // [B, 144]
    const float* __restrict__ w_ih,   // [432, 288] (cols 0..143 used here)
    const float* __restrict__ w_hh,   // [432, 144]
    const float* __restrict__ b_hh,   // [432]
    const float* __restrict__ spl_w,  // [144, 144]
    const float* __restrict__ spl_b,  // [144]
    float* __restrict__ out)          // d_out + step*144, row stride 24*144
{
    constexpr int BR = 4;
    __shared__ float xin[BR][E_], hs[BR][H_], hnew[BR][H_];
    __shared__ float gi[BR][TH_], gh[BR][TH_];
    const int b0 = blockIdx.x * BR;
    const int tid = threadIdx.x;

    for (int idx = tid; idx < BR * E_; idx += 256) {
        int r = idx / E_, e = idx % E_;
        xin[r][e] = inp[(size_t)(b0 + r) * inp_stride + e];
        hs[r][e]  = h[(size_t)(b0 + r) * H_ + e];
    }
    __syncthreads();

    for (int o = tid; o < BR * TH_; o += 256) {
        int r = o / TH_, f = o % TH_;
        const float4* wr = (const float4*)(w_ih + (size_t)f * GIN_);
        float s = gctx[(size_t)(b0 + r) * TH_ + f];
        const float4* xr = (const float4*)&xin[r][0];
#pragma unroll 9
        for (int e4 = 0; e4 < 36; e4++) {
            float4 wv = wr[e4], xv = xr[e4];
            s += xv.x * wv.x + xv.y * wv.y + xv.z * wv.z + xv.w * wv.w;
        }
        gi[r][f] = s;
        const float4* wh = (const float4*)(w_hh + (size_t)f * H_);
        float s2 = b_hh[f];
        const float4* hr = (const float4*)&hs[r][0];
#pragma unroll 9
        for (int e4 = 0; e4 < 36; e4++) {
            float4 wv = wh[e4], hv = hr[e4];
            s2 += hv.x * wv.x + hv.y * wv.y + hv.z * wv.z + hv.w * wv.w;
        }
        gh[r][f] = s2;
    }
    __syncthreads();

    for (int o = tid; o < BR * H_; o += 256) {
        int r = o / H_, e = o % H_;
        float rr = sigmoidf_(gi[r][e] + gh[r][e]);
        float z  = sigmoidf_(gi[r][H_ + e] + gh[r][H_ + e]);
        float n  = tanhf(gi[r][2 * H_ + e] + rr * gh[r][2 * H_ + e]);
        float hv = (1.f - z) * n + z * hs[r][e];
        hnew[r][e] = hv;
        h[(size_t)(b0 + r) * H_ + e] = hv;
    }
    __syncthreads();

    for (int o = tid; o < BR * E_; o += 256) {
        int r = o / E_, e = o % E_;
        const float4* wr = (const float4*)(spl_w + (size_t)e * H_);
        const float4* hr = (const float4*)&hnew[r][0];
        float s = spl_b[e];
#pragma unroll 9
        for (int e4 = 0; e4 < 36; e4++) {
            float4 wv = wr[e4], hv = hr[e4];
            s += hv.x * wv.x + hv.y * wv.y + hv.z * wv.z + hv.w * wv.w;
        }
        out[(size_t)(b0 + r) * (FUT_ * E_) + e] = s;
    }
}

// =================================================================================
extern "C" void kernel_launch(void* const* d_in, const int* in_sizes, int n_in,
                              void* d_out, int out_size, void* d_ws, size_t ws_size,
                              hipStream_t stream)
{
    const float* seed   = (const float*)d_in[0];
    const float* qkv_w  = (const float*)d_in[1];
    const float* qkv_b  = (const float*)d_in[2];
    const float* out_w  = (const float*)d_in[3];
    const float* out_b  = (const float*)d_in[4];
    const float* ln1_w  = (const float*)d_in[5];
    const float* ln1_b  = (const float*)d_in[6];
    const float* ffn1_w = (const float*)d_in[7];
    const float* ffn1_b = (const float*)d_in[8];
    const float* ffn2_w = (const float*)d_in[9];
    const float* ffn2_b = (const float*)d_in[10];
    const float* ln2_w  = (const float*)d_in[11];
    const float* ln2_b  = (const float*)d_in[12];
    const float* proj_w = (const float*)d_in[13];
    const float* proj_b = (const float*)d_in[14];
    const float* w_ih   = (const float*)d_in[15];
    const float* w_hh   = (const float*)d_in[16];
    const float* b_ih   = (const float*)d_in[17];
    const float* b_hh   = (const float*)d_in[18];
    const float* spl_w  = (const float*)d_in[19];
    const float* spl_b  = (const float*)d_in[20];

    // persistent small buffers: ctxm, ctx, gctx, h
    const size_t persist = (size_t)B_ * 4 * (E_ + E_ + TH_ + H_);  // ~7.1 MB

    // choose batch-chunking so workspace fits ws_size (deterministic: ws_size fixed)
    int nc = 16;
    for (int c = 1; c <= 16; c <<= 1) {
        size_t rows = (size_t)(B_ / c) * T_;
        size_t need = persist
                    + rows * E_ * 4 * 2      // xA, xB (f32)
                    + rows * FF_ * 2         // qf (bf16, shared qkv/ff)
                    + rows * E_ * 2;         // ob (bf16)
        if (need <= ws_size) { nc = c; break; }
    }
    const int BC = B_ / nc;              // batches per chunk
    const int CR = BC * T_;              // rows per chunk (multiple of 64 for nc<=16)

    char* wsp = (char*)d_ws;
    float* xA   = (float*)wsp; wsp += (size_t)CR * E_ * 4;
    float* xB   = (float*)wsp; wsp += (size_t)CR * E_ * 4;
    u16*   qf   = (u16*)wsp;   wsp += (size_t)CR * FF_ * 2;
    u16*   ob   = (u16*)wsp;   wsp += (size_t)CR * E_ * 2;
    float* ctxm = (float*)wsp; wsp += (size_t)B_ * E_ * 4;
    float* ctx  = (float*)wsp; wsp += (size_t)B_ * E_ * 4;
    float* gctx = (float*)wsp; wsp += (size_t)B_ * TH_ * 4;
    float* h    = (float*)wsp; wsp += (size_t)B_ * H_ * 4;

    auto grid = [](int M, int N) { return dim3((N + 63) / 64, M / 64); };

    for (int c = 0; c < nc; c++) {
        const int b0 = c * BC;
        const float* xin = seed + (size_t)b0 * T_ * E_;
        for (int l = 0; l < L_; l++) {
            gemm_kernel<float, u16, true, false, false><<<grid(CR, TH_), 256, 0, stream>>>(
                xin, qkv_w + (size_t)l * TH_ * E_, E_, qkv_b + (size_t)l * TH_,
                nullptr, qf, CR, TH_, E_);
            attn_kernel<<<BC * NH_, 128, 0, stream>>>(qf, ob);
            gemm_kernel<u16, float, true, false, true><<<grid(CR, E_), 256, 0, stream>>>(
                ob, out_w + (size_t)l * E_ * E_, E_, out_b + (size_t)l * E_,
                xin, xB, CR, E_, E_);
            ln_kernel<<<CR / 4, 256, 0, stream>>>(xB, ln1_w + (size_t)l * E_,
                                                  ln1_b + (size_t)l * E_, xA, CR);
            gemm_kernel<float, u16, true, true, false><<<grid(CR, FF_), 256, 0, stream>>>(
                xA, ffn1_w + (size_t)l * FF_ * E_, E_, ffn1_b + (size_t)l * FF_,
                nullptr, qf, CR, FF_, E_);
            gemm_kernel<u16, float, true, false, true><<<grid(CR, E_), 256, 0, stream>>>(
                qf, ffn2_w + (size_t)l * E_ * FF_, FF_, ffn2_b + (size_t)l * E_,
                xA, xB, CR, E_, FF_);
            ln_kernel<<<CR / 4, 256, 0, stream>>>(xB, ln2_w + (size_t)l * E_,
                                                  ln2_b + (size_t)l * E_, xA, CR);
            xin = xA;
        }
        mean_kernel<<<(BC * E_ + 255) / 256, 256, 0, stream>>>(xA, ctxm + (size_t)b0 * E_, BC);
    }

    gemm_kernel<float, float, true, false, false><<<grid(B_, E_), 256, 0, stream>>>(
        ctxm, proj_w, E_, proj_b, nullptr, ctx, B_, E_, E_);
    // ctx-half of gi (constant over steps): gctx = ctx @ w_ih[:,144:]^T + b_ih
    gemm_kernel<float, float, true, false, false><<<grid(B_, TH_), 256, 0, stream>>>(
        ctx, w_ih + E_, GIN_, b_ih, nullptr, gctx, B_, TH_, E_);
    zero_kernel<<<(B_ * H_ + 255) / 256, 256, 0, stream>>>(h, B_ * H_);

    float* out = (float*)d_out;
    for (int s = 0; s < FUT_; s++) {
        const float* inp = s ? (const float*)(out + (size_t)(s - 1) * E_)
                             : seed + (size_t)(T_ - 1) * E_;
        int istr = s ? FUT_ * E_ : T_ * E_;
        gru_step_kernel<<<B_ / 4, 256, 0, stream>>>(
            inp, istr, gctx, h, w_ih, w_hh, b_hh, spl_w, spl_b,
            out + (size_t)s * E_);
    }
}

// Round 3
// 8490.031 us; speedup vs baseline: 1.6672x; 1.6672x over previous
//
#include <hip/hip_runtime.h>

#define B_   2048
#define T_   120
#define E_   144
#define L_   4
#define NH_  8
#define HD_  18
#define FF_  576
#define H_   144
#define GIN_ 288
#define TH_  432   // 3*E = 3*H
#define FUT_ 24
#define BT_  (B_*T_)

typedef unsigned short u16;
typedef unsigned int   u32;

typedef __attribute__((ext_vector_type(8))) short short8v;  // 8 bf16 (4 VGPRs)
typedef __attribute__((ext_vector_type(4))) float f32x4;

__device__ __forceinline__ float bf2f(u16 u) {
    u32 x = ((u32)u) << 16;
    return __uint_as_float(x);
}
__device__ __forceinline__ u16 f2bf(float f) {
    u32 x = __float_as_uint(f);
    u32 r = (x + 0x7fffu + ((x >> 16) & 1u)) >> 16;
    return (u16)r;
}

struct F4 { float x, y, z, w; };

__device__ __forceinline__ F4 load4(const float* p) {
    float4 v = *(const float4*)p;
    return {v.x, v.y, v.z, v.w};
}
__device__ __forceinline__ F4 load4(const u16* p) {
    ushort4 v = *(const ushort4*)p;
    return {bf2f(v.x), bf2f(v.y), bf2f(v.z), bf2f(v.w)};
}
__device__ __forceinline__ void store1(float* p, float v) { *p = v; }
__device__ __forceinline__ void store1(u16* p, float v)   { *p = f2bf(v); }

// ---------------- weight convert + K-pad to bf16 --------------------------------
__global__ void wconv_kernel(const float* __restrict__ src, u16* __restrict__ dst,
                             int rows, int K, int KP)
{
    int i = blockIdx.x * 256 + threadIdx.x;
    if (i >= rows * KP) return;
    int r = i / KP, k = i - r * KP;
    dst[i] = (k < K) ? f2bf(src[(size_t)r * K + k]) : (u16)0;
}

// ---------------- MFMA GEMM: C[M,N] = A[M,K] @ Wb[N,KP]^T (+bias)(+res)(relu) ---
// 192 threads = 3 waves. Block tile 64 x 144. Wave tile 64 x 48 (4x3 MFMA tiles).
// M % 64 == 0, N % 144 == 0, K in {144, 576}. Wb is bf16, rows padded to KP.
template<int K, typename AT, typename OT, bool RELU, bool RES>
__global__ __launch_bounds__(192) void gemm_mfma(
    const AT* __restrict__ A, const u16* __restrict__ Wb,
    const float* __restrict__ bias, const float* __restrict__ res,
    OT* __restrict__ C, int M, int N)
{
    constexpr int KP    = (K == 144) ? 160 : 576;
    constexpr int KC    = (K == 144) ? 160 : 192;  // k-chunk staged in LDS
    constexpr int NCH   = (K == 144) ? 1 : 3;
    constexpr int NSTEP = KC / 32;                 // 5 or 6
    constexpr int RS32  = KC / 2 + 4;              // LDS row stride in u32 (84/100)

    __shared__ u32 lds[64 * RS32];

    const int tid = threadIdx.x;
    const int w   = tid >> 6;       // wave 0..2
    const int l   = tid & 63;
    const int lg  = l >> 4;         // lane group 0..3
    const int li  = l & 15;
    const int bm  = blockIdx.y * 64;
    const int n0w = blockIdx.x * 144 + w * 48;

    f32x4 acc[4][3];
#pragma unroll
    for (int rt = 0; rt < 4; rt++)
#pragma unroll
        for (int ct = 0; ct < 3; ct++) acc[rt][ct] = {0.f, 0.f, 0.f, 0.f};

    for (int c = 0; c < NCH; ++c) {
        __syncthreads();
        if constexpr (sizeof(AT) == 4) {
            // f32 source, K==144: stage+convert, zero-pad k 144..159
            int row = tid / 80, kk = tid - row * 80;
            for (int i = tid; i < 64 * 80; i += 192) {
                u32 v = 0;
                if (kk < 72) {
                    float2 t = *(const float2*)(A + (size_t)(bm + row) * K + 2 * kk);
                    v = ((u32)f2bf(t.y) << 16) | (u32)f2bf(t.x);
                }
                lds[row * RS32 + kk] = v;
                kk += 32; row += 2; if (kk >= 80) { kk -= 80; row += 1; }
            }
        } else if constexpr (K == 144) {
            // bf16 source: pure copy, zero-pad
            const u32* __restrict__ a32 = (const u32*)A;
            int row = tid / 80, kk = tid - row * 80;
            for (int i = tid; i < 64 * 80; i += 192) {
                u32 v = (kk < 72) ? a32[(size_t)(bm + row) * 72 + kk] : 0u;
                lds[row * RS32 + kk] = v;
                kk += 32; row += 2; if (kk >= 80) { kk -= 80; row += 1; }
            }
        } else {
            // bf16 source, K==576: chunk c covers 192 k's (96 u32)
            const u32* __restrict__ a32 = (const u32*)A;
            int row = tid / 96, kk = tid - row * 96;
            for (int i = tid; i < 64 * 96; i += 192) {
                lds[row * RS32 + kk] = a32[(size_t)(bm + row) * 288 + c * 96 + kk];
                row += 2;
            }
        }
        __syncthreads();

        const u16* lds16 = (const u16*)lds;
#pragma unroll
        for (int s = 0; s < NSTEP; ++s) {
            short8v bf[3];
#pragma unroll
            for (int ct = 0; ct < 3; ++ct) {
                int n = n0w + ct * 16 + li;
                bf[ct] = *(const short8v*)(Wb + (size_t)n * KP + c * KC + s * 32 + lg * 8);
            }
            short8v af[4];
#pragma unroll
            for (int rt = 0; rt < 4; ++rt)
                af[rt] = *(const short8v*)(lds16 + (rt * 16 + li) * (2 * RS32) + s * 32 + lg * 8);
#pragma unroll
            for (int rt = 0; rt < 4; ++rt)
#pragma unroll
                for (int ct = 0; ct < 3; ++ct)
                    acc[rt][ct] = __builtin_amdgcn_mfma_f32_16x16x32_bf16(
                        af[rt], bf[ct], acc[rt][ct], 0, 0, 0);
        }
    }

    // epilogue: C/D layout col=lane&15, row=(lane>>4)*4+reg
#pragma unroll
    for (int ct = 0; ct < 3; ++ct) {
        int col = n0w + ct * 16 + li;
        float bv = bias[col];
#pragma unroll
        for (int rt = 0; rt < 4; ++rt) {
#pragma unroll
            for (int j = 0; j < 4; ++j) {
                int row = bm + rt * 16 + lg * 4 + j;
                float v = acc[rt][ct][j] + bv;
                if (RES)  v += res[(size_t)row * N + col];
                if (RELU) v = fmaxf(v, 0.f);
                store1(&C[(size_t)row * N + col], v);
            }
        }
    }
}

// ---------------- f32 GEMM (small, for ctx path): C = A @ W^T ------------------
template<typename AT, typename OT, bool BIAS, bool RELU, bool RES>
__global__ __launch_bounds__(256) void gemm_kernel(
    const AT* __restrict__ A, const float* __restrict__ W, int ldw,
    const float* __restrict__ bias, const float* __restrict__ res,
    OT* __restrict__ C, int M, int N, int K)
{
    constexpr int BM = 64, BN = 64, BK = 16;
    __shared__ float As[BK][BM + 4];
    __shared__ float Ws[BK][BN + 4];
    const int tid = threadIdx.x;
    const int bm = blockIdx.y * BM;
    const int bn = blockIdx.x * BN;
    const int tx = tid & 15, ty = tid >> 4;
    const int lr = tid >> 2;
    const int lc = (tid & 3) << 2;

    float acc[4][4];
#pragma unroll
    for (int i = 0; i < 4; i++)
#pragma unroll
        for (int j = 0; j < 4; j++) acc[i][j] = 0.f;

    for (int k0 = 0; k0 < K; k0 += BK) {
        F4 av = load4(A + (size_t)(bm + lr) * K + k0 + lc);
        As[lc + 0][lr] = av.x; As[lc + 1][lr] = av.y;
        As[lc + 2][lr] = av.z; As[lc + 3][lr] = av.w;
        int n = bn + lr;
        F4 wv = {0.f, 0.f, 0.f, 0.f};
        if (n < N) {
            float4 t = *(const float4*)(W + (size_t)n * ldw + k0 + lc);
            wv = {t.x, t.y, t.z, t.w};
        }
        Ws[lc + 0][lr] = wv.x; Ws[lc + 1][lr] = wv.y;
        Ws[lc + 2][lr] = wv.z; Ws[lc + 3][lr] = wv.w;
        __syncthreads();
#pragma unroll
        for (int kk = 0; kk < BK; ++kk) {
            float a[4], wr[4];
#pragma unroll
            for (int i = 0; i < 4; i++) a[i] = As[kk][ty * 4 + i];
#pragma unroll
            for (int j = 0; j < 4; j++) wr[j] = Ws[kk][tx * 4 + j];
#pragma unroll
            for (int i = 0; i < 4; i++)
#pragma unroll
                for (int j = 0; j < 4; j++) acc[i][j] += a[i] * wr[j];
        }
        __syncthreads();
    }
#pragma unroll
    for (int i = 0; i < 4; i++) {
        int m = bm + ty * 4 + i;
#pragma unroll
        for (int j = 0; j < 4; j++) {
            int n = bn + tx * 4 + j;
            if (n < N) {
                float v = acc[i][j];
                if (BIAS) v += bias[n];
                if (RES)  v += res[(size_t)m * N + n];
                if (RELU) v = fmaxf(v, 0.f);
                store1(&C[(size_t)m * N + n], v);
            }
        }
    }
}

// ---------------- attention: one block per (b, head) ---------------------------
__global__ __launch_bounds__(128) void attn_kernel(const u16* __restrict__ qkv,
                                                   u16* __restrict__ o)
{
    const int bh = blockIdx.x;
    const int b = bh >> 3, h = bh & 7;
    __shared__ float ks[T_][HD_];
    __shared__ float vs[T_][HD_];
    const size_t base = (size_t)b * T_ * TH_;
    const int tid = threadIdx.x;
    for (int idx = tid; idx < T_ * HD_; idx += 128) {
        int t = idx / HD_, d = idx % HD_;
        ks[t][d] = bf2f(qkv[base + (size_t)t * TH_ + E_ + h * HD_ + d]);
        vs[t][d] = bf2f(qkv[base + (size_t)t * TH_ + 2 * E_ + h * HD_ + d]);
    }
    __syncthreads();
    if (tid < T_) {
        float q[HD_];
#pragma unroll
        for (int d = 0; d < HD_; d++)
            q[d] = bf2f(qkv[base + (size_t)tid * TH_ + h * HD_ + d]);
        const float scale = 0.23570226039551584f; // 1/sqrt(18)
        float m = -1e30f, l = 0.f;
        for (int j = 0; j < T_; j++) {
            float s = 0.f;
#pragma unroll
            for (int d = 0; d < HD_; d++) s += q[d] * ks[j][d];
            s *= scale;
            if (s > m) { l = l * __expf(m - s) + 1.f; m = s; }
            else       { l += __expf(s - m); }
        }
        float inv_l = 1.f / l;
        float acc[HD_];
#pragma unroll
        for (int d = 0; d < HD_; d++) acc[d] = 0.f;
        for (int j = 0; j < T_; j++) {
            float s = 0.f;
#pragma unroll
            for (int d = 0; d < HD_; d++) s += q[d] * ks[j][d];
            float p = __expf(s * scale - m);
#pragma unroll
            for (int d = 0; d < HD_; d++) acc[d] += p * vs[j][d];
        }
        u16* op = o + ((size_t)b * T_ + tid) * E_ + h * HD_;
#pragma unroll
        for (int d = 0; d < HD_; d++) op[d] = f2bf(acc[d] * inv_l);
    }
}

// ---------------- LayerNorm over rows of 144 (wave per row) --------------------
__global__ __launch_bounds__(256) void ln_kernel(const float* __restrict__ y,
                                                 const float* __restrict__ w,
                                                 const float* __restrict__ bsc,
                                                 float* __restrict__ out, int rows)
{
    int wid = threadIdx.x >> 6, lane = threadIdx.x & 63;
    int row = blockIdx.x * 4 + wid;
    if (row >= rows) return;
    const float* yr = y + (size_t)row * E_;
    float v0 = yr[lane], v1 = yr[lane + 64];
    float v2 = (lane < 16) ? yr[lane + 128] : 0.f;
    float s = v0 + v1 + v2;
    for (int off = 32; off; off >>= 1) s += __shfl_xor(s, off);
    float mean = s * (1.f / 144.f);
    float d0 = v0 - mean, d1 = v1 - mean;
    float d2 = (lane < 16) ? (v2 - mean) : 0.f;
    float q = d0 * d0 + d1 * d1 + d2 * d2;
    for (int off = 32; off; off >>= 1) q += __shfl_xor(q, off);
    float rstd = rsqrtf(q * (1.f / 144.f) + 1e-5f);
    float* orow = out + (size_t)row * E_;
    orow[lane]      = d0 * rstd * w[lane]      + bsc[lane];
    orow[lane + 64] = d1 * rstd * w[lane + 64] + bsc[lane + 64];
    if (lane < 16)
        orow[lane + 128] = d2 * rstd * w[lane + 128] + bsc[lane + 128];
}

// ---------------- mean over T (one chunk of nb batches) -------------------------
__global__ void mean_kernel(const float* __restrict__ x, float* __restrict__ out,
                            int nb)
{
    int idx = blockIdx.x * blockDim.x + threadIdx.x;
    if (idx >= nb * E_) return;
    int b = idx / E_, e = idx % E_;
    const float* p = x + (size_t)b * T_ * E_ + e;
    float s = 0.f;
    for (int t = 0; t < T_; t++) s += p[(size_t)t * E_];
    out[idx] = s * (1.f / 120.f);
}

__global__ void zero_kernel(float* __restrict__ p, int n)
{
    int i = blockIdx.x * blockDim.x + threadIdx.x;
    if (i < n) p[i] = 0.f;
}

__device__ __forceinline__ float sigmoidf_(float x) {
    return 1.f / (1.f + __expf(-x));
}

// ---------------- one GRU decode step (fused) -----------------------------------
__global__ __launch_bounds__(256) void gru_step_kernel(
    const float* __restrict__ inp, int inp_stride,
    const float* __restrict__ gctx,
    float* __restrict__ h,
    const float* __restrict__ w_ih,
    const float* __restrict__ w_hh,
    const float* __restrict__ b_hh,
    const float* __restrict__ spl_w,
    const float* __restrict__ spl_b,
    float* __restrict__ out)
{
    constexpr int BR = 4;
    __shared__ float xin[BR][E_], hs[BR][H_], hnew[BR][H_];
    __shared__ float gi[BR][TH_], gh[BR][TH_];
    const int b0 = blockIdx.x * BR;
    const int tid = threadIdx.x;

    for (int idx = tid; idx < BR * E_; idx += 256) {
        int r = idx / E_, e = idx % E_;
        xin[r][e] = inp[(size_t)(b0 + r) * inp_stride + e];
        hs[r][e]  = h[(size_t)(b0 + r) * H_ + e];
    }
    __syncthreads();

    for (int o = tid; o < BR * TH_; o += 256) {
        int r = o / TH_, f = o % TH_;
        const float4* wr = (const float4*)(w_ih + (size_t)f * GIN_);
        float s = gctx[(size_t)(b0 + r) * TH_ + f];
        const float4* xr = (const float4*)&xin[r][0];
#pragma unroll 9
        for (int e4 = 0; e4 < 36; e4++) {
            float4 wv = wr[e4], xv = xr[e4];
            s += xv.x * wv.x + xv.y * wv.y + xv.z * wv.z + xv.w * wv.w;
        }
        gi[r][f] = s;
        const float4* wh = (const float4*)(w_hh + (size_t)f * H_);
        float s2 = b_hh[f];
        const float4* hr = (const float4*)&hs[r][0];
#pragma unroll 9
        for (int e4 = 0; e4 < 36; e4++) {
            float4 wv = wh[e4], hv = hr[e4];
            s2 += hv.x * wv.x + hv.y * wv.y + hv.z * wv.z + hv.w * wv.w;
        }
        gh[r][f] = s2;
    }
    __syncthreads();

    for (int o = tid; o < BR * H_; o += 256) {
        int r = o / H_, e = o % H_;
        float rr = sigmoidf_(gi[r][e] + gh[r][e]);
        float z  = sigmoidf_(gi[r][H_ + e] + gh[r][H_ + e]);
        float n  = tanhf(gi[r][2 * H_ + e] + rr * gh[r][2 * H_ + e]);
        float hv = (1.f - z) * n + z * hs[r][e];
        hnew[r][e] = hv;
        h[(size_t)(b0 + r) * H_ + e] = hv;
    }
    __syncthreads();

    for (int o = tid; o < BR * E_; o += 256) {
        int r = o / E_, e = o % E_;
        const float4* wr = (const float4*)(spl_w + (size_t)e * H_);
        const float4* hr = (const float4*)&hnew[r][0];
        float s = spl_b[e];
#pragma unroll 9
        for (int e4 = 0; e4 < 36; e4++) {
            float4 wv = wr[e4], hv = hr[e4];
            s += hv.x * wv.x + hv.y * wv.y + hv.z * wv.z + hv.w * wv.w;
        }
        out[(size_t)(b0 + r) * (FUT_ * E_) + e] = s;
    }
}

// =================================================================================
extern "C" void kernel_launch(void* const* d_in, const int* in_sizes, int n_in,
                              void* d_out, int out_size, void* d_ws, size_t ws_size,
                              hipStream_t stream)
{
    const float* seed   = (const float*)d_in[0];
    const float* qkv_w  = (const float*)d_in[1];
    const float* qkv_b  = (const float*)d_in[2];
    const float* out_w  = (const float*)d_in[3];
    const float* out_b  = (const float*)d_in[4];
    const float* ln1_w  = (const float*)d_in[5];
    const float* ln1_b  = (const float*)d_in[6];
    const float* ffn1_w = (const float*)d_in[7];
    const float* ffn1_b = (const float*)d_in[8];
    const float* ffn2_w = (const float*)d_in[9];
    const float* ffn2_b = (const float*)d_in[10];
    const float* ln2_w  = (const float*)d_in[11];
    const float* ln2_b  = (const float*)d_in[12];
    const float* proj_w = (const float*)d_in[13];
    const float* proj_b = (const float*)d_in[14];
    const float* w_ih   = (const float*)d_in[15];
    const float* w_hh   = (const float*)d_in[16];
    const float* b_ih   = (const float*)d_in[17];
    const float* b_hh   = (const float*)d_in[18];
    const float* spl_w  = (const float*)d_in[19];
    const float* spl_b  = (const float*)d_in[20];

    // bf16 padded weight copies
    const size_t qkvW_n  = (size_t)L_ * TH_ * 160;
    const size_t outW_n  = (size_t)L_ * E_ * 160;
    const size_t ffn1W_n = (size_t)L_ * FF_ * 160;
    const size_t ffn2W_n = (size_t)L_ * E_ * 576;
    const size_t wbytes  = (qkvW_n + outW_n + ffn1W_n + ffn2W_n) * 2;

    const size_t persist = (size_t)B_ * 4 * (E_ + E_ + TH_ + H_) + wbytes;

    int nc = 16;
    for (int c = 1; c <= 16; c <<= 1) {
        size_t rows = (size_t)(B_ / c) * T_;
        size_t need = persist
                    + rows * E_ * 4 * 2
                    + rows * FF_ * 2
                    + rows * E_ * 2;
        if (need <= ws_size) { nc = c; break; }
    }
    const int BC = B_ / nc;
    const int CR = BC * T_;

    char* wsp = (char*)d_ws;
    float* xA   = (float*)wsp; wsp += (size_t)CR * E_ * 4;
    float* xB   = (float*)wsp; wsp += (size_t)CR * E_ * 4;
    u16*   qf   = (u16*)wsp;   wsp += (size_t)CR * FF_ * 2;
    u16*   ob   = (u16*)wsp;   wsp += (size_t)CR * E_ * 2;
    float* ctxm = (float*)wsp; wsp += (size_t)B_ * E_ * 4;
    float* ctx  = (float*)wsp; wsp += (size_t)B_ * E_ * 4;
    float* gctx = (float*)wsp; wsp += (size_t)B_ * TH_ * 4;
    float* h    = (float*)wsp; wsp += (size_t)B_ * H_ * 4;
    u16* qkvWb  = (u16*)wsp;   wsp += qkvW_n * 2;
    u16* outWb  = (u16*)wsp;   wsp += outW_n * 2;
    u16* ffn1Wb = (u16*)wsp;   wsp += ffn1W_n * 2;
    u16* ffn2Wb = (u16*)wsp;   wsp += ffn2W_n * 2;

    // convert weights once per launch (deterministic, ~1M elems total)
    wconv_kernel<<<(int)((qkvW_n + 255) / 256), 256, 0, stream>>>(qkv_w, qkvWb, L_ * TH_, 144, 160);
    wconv_kernel<<<(int)((outW_n + 255) / 256), 256, 0, stream>>>(out_w, outWb, L_ * E_, 144, 160);
    wconv_kernel<<<(int)((ffn1W_n + 255) / 256), 256, 0, stream>>>(ffn1_w, ffn1Wb, L_ * FF_, 144, 160);
    wconv_kernel<<<(int)((ffn2W_n + 255) / 256), 256, 0, stream>>>(ffn2_w, ffn2Wb, L_ * E_, 576, 576);

    auto grid  = [](int M, int N) { return dim3((N + 63) / 64, M / 64); };
    auto gridm = [](int M, int N) { return dim3(N / 144, M / 64); };

    for (int c = 0; c < nc; c++) {
        const int b0 = c * BC;
        const float* xin = seed + (size_t)b0 * T_ * E_;
        for (int l = 0; l < L_; l++) {
            gemm_mfma<144, float, u16, false, false><<<gridm(CR, TH_), 192, 0, stream>>>(
                xin, qkvWb + (size_t)l * TH_ * 160, qkv_b + (size_t)l * TH_,
                nullptr, qf, CR, TH_);
            attn_kernel<<<BC * NH_, 128, 0, stream>>>(qf, ob);
            gemm_mfma<144, u16, float, false, true><<<gridm(CR, E_), 192, 0, stream>>>(
                ob, outWb + (size_t)l * E_ * 160, out_b + (size_t)l * E_,
                xin, xB, CR, E_);
            ln_kernel<<<CR / 4, 256, 0, stream>>>(xB, ln1_w + (size_t)l * E_,
                                                  ln1_b + (size_t)l * E_, xA, CR);
            gemm_mfma<144, float, u16, true, false><<<gridm(CR, FF_), 192, 0, stream>>>(
                xA, ffn1Wb + (size_t)l * FF_ * 160, ffn1_b + (size_t)l * FF_,
                nullptr, qf, CR, FF_);
            gemm_mfma<576, u16, float, false, true><<<gridm(CR, E_), 192, 0, stream>>>(
                qf, ffn2Wb + (size_t)l * E_ * 576, ffn2_b + (size_t)l * E_,
                xA, xB, CR, E_);
            ln_kernel<<<CR / 4, 256, 0, stream>>>(xB, ln2_w + (size_t)l * E_,
                                                  ln2_b + (size_t)l * E_, xA, CR);
            xin = xA;
        }
        mean_kernel<<<(BC * E_ + 255) / 256, 256, 0, stream>>>(xA, ctxm + (size_t)b0 * E_, BC);
    }

    gemm_kernel<float, float, true, false, false><<<grid(B_, E_), 256, 0, stream>>>(
        ctxm, proj_w, E_, proj_b, nullptr, ctx, B_, E_, E_);
    gemm_kernel<float, float, true, false, false><<<grid(B_, TH_), 256, 0, stream>>>(
        ctx, w_ih + E_, GIN_, b_ih, nullptr, gctx, B_, TH_, E_);
    zero_kernel<<<(B_ * H_ + 255) / 256, 256, 0, stream>>>(h, B_ * H_);

    float* out = (float*)d_out;
    for (int s = 0; s < FUT_; s++) {
        const float* inp = s ? (const float*)(out + (size_t)(s - 1) * E_)
                             : seed + (size_t)(T_ - 1) * E_;
        int istr = s ? FUT_ * E_ : T_ * E_;
        gru_step_kernel<<<B_ / 4, 256, 0, stream>>>(
            inp, istr, gctx, h, w_ih, w_hh, b_hh, spl_w, spl_b,
            out + (size_t)s * E_);
    }
}

// Round 4
// 7101.129 us; speedup vs baseline: 1.9933x; 1.1956x over previous
//
#include <hip/hip_runtime.h>

#define B_   2048
#define T_   120
#define E_   144
#define L_   4
#define NH_  8
#define HD_  18
#define FF_  576
#define H_   144
#define GIN_ 288
#define TH_  432   // 3*E = 3*H
#define FUT_ 24
#define BT_  (B_*T_)

typedef unsigned short u16;
typedef unsigned int   u32;

typedef __attribute__((ext_vector_type(8))) short short8v;  // 8 bf16 (4 VGPRs)
typedef __attribute__((ext_vector_type(4))) float f32x4;

__device__ __forceinline__ float bf2f(u16 u) {
    u32 x = ((u32)u) << 16;
    return __uint_as_float(x);
}
__device__ __forceinline__ u16 f2bf(float f) {
    u32 x = __float_as_uint(f);
    u32 r = (x + 0x7fffu + ((x >> 16) & 1u)) >> 16;
    return (u16)r;
}

struct F4 { float x, y, z, w; };

__device__ __forceinline__ F4 load4(const float* p) {
    float4 v = *(const float4*)p;
    return {v.x, v.y, v.z, v.w};
}
__device__ __forceinline__ F4 load4(const u16* p) {
    ushort4 v = *(const ushort4*)p;
    return {bf2f(v.x), bf2f(v.y), bf2f(v.z), bf2f(v.w)};
}
__device__ __forceinline__ void store1(float* p, float v) { *p = v; }
__device__ __forceinline__ void store1(u16* p, float v)   { *p = f2bf(v); }

// ---------------- weight convert + K-pad to bf16 --------------------------------
__global__ void wconv_kernel(const float* __restrict__ src, u16* __restrict__ dst,
                             int rows, int K, int KP)
{
    int i = blockIdx.x * 256 + threadIdx.x;
    if (i >= rows * KP) return;
    int r = i / KP, k = i - r * KP;
    dst[i] = (k < K) ? f2bf(src[(size_t)r * K + k]) : (u16)0;
}

// ---------------- MFMA GEMM: C[M,N] = A[M,K] @ Wb[N,KP]^T (+bias)(+res)(relu) ---
// 192 threads = 3 waves. Block tile 64 x 144. Wave tile 64 x 48 (4x3 MFMA tiles).
// M % 64 == 0, N % 144 == 0, K in {144, 576}. Wb is bf16, rows padded to KP.
template<int K, typename AT, typename OT, bool RELU, bool RES>
__global__ __launch_bounds__(192) void gemm_mfma(
    const AT* __restrict__ A, const u16* __restrict__ Wb,
    const float* __restrict__ bias, const float* __restrict__ res,
    OT* __restrict__ C, int M, int N)
{
    constexpr int KP    = (K == 144) ? 160 : 576;
    constexpr int KC    = (K == 144) ? 160 : 192;  // k-chunk staged in LDS
    constexpr int NCH   = (K == 144) ? 1 : 3;
    constexpr int NSTEP = KC / 32;                 // 5 or 6
    constexpr int RS32  = KC / 2 + 4;              // LDS row stride in u32 (84/100)

    __shared__ u32 lds[64 * RS32];

    const int tid = threadIdx.x;
    const int w   = tid >> 6;       // wave 0..2
    const int l   = tid & 63;
    const int lg  = l >> 4;         // lane group 0..3
    const int li  = l & 15;
    const int bm  = blockIdx.y * 64;
    const int n0w = blockIdx.x * 144 + w * 48;

    f32x4 acc[4][3];
#pragma unroll
    for (int rt = 0; rt < 4; rt++)
#pragma unroll
        for (int ct = 0; ct < 3; ct++) acc[rt][ct] = {0.f, 0.f, 0.f, 0.f};

    for (int c = 0; c < NCH; ++c) {
        __syncthreads();
        if constexpr (sizeof(AT) == 4) {
            // f32 source, K==144: stage+convert, zero-pad k 144..159
            int row = tid / 80, kk = tid - row * 80;
            for (int i = tid; i < 64 * 80; i += 192) {
                u32 v = 0;
                if (kk < 72) {
                    float2 t = *(const float2*)(A + (size_t)(bm + row) * K + 2 * kk);
                    v = ((u32)f2bf(t.y) << 16) | (u32)f2bf(t.x);
                }
                lds[row * RS32 + kk] = v;
                kk += 32; row += 2; if (kk >= 80) { kk -= 80; row += 1; }
            }
        } else if constexpr (K == 144) {
            // bf16 source: pure copy, zero-pad
            const u32* __restrict__ a32 = (const u32*)A;
            int row = tid / 80, kk = tid - row * 80;
            for (int i = tid; i < 64 * 80; i += 192) {
                u32 v = (kk < 72) ? a32[(size_t)(bm + row) * 72 + kk] : 0u;
                lds[row * RS32 + kk] = v;
                kk += 32; row += 2; if (kk >= 80) { kk -= 80; row += 1; }
            }
        } else {
            // bf16 source, K==576: chunk c covers 192 k's (96 u32)
            const u32* __restrict__ a32 = (const u32*)A;
            int row = tid / 96, kk = tid - row * 96;
            for (int i = tid; i < 64 * 96; i += 192) {
                lds[row * RS32 + kk] = a32[(size_t)(bm + row) * 288 + c * 96 + kk];
                row += 2;
            }
        }
        __syncthreads();

        const u16* lds16 = (const u16*)lds;
#pragma unroll
        for (int s = 0; s < NSTEP; ++s) {
            short8v bf[3];
#pragma unroll
            for (int ct = 0; ct < 3; ++ct) {
                int n = n0w + ct * 16 + li;
                bf[ct] = *(const short8v*)(Wb + (size_t)n * KP + c * KC + s * 32 + lg * 8);
            }
            short8v af[4];
#pragma unroll
            for (int rt = 0; rt < 4; ++rt)
                af[rt] = *(const short8v*)(lds16 + (rt * 16 + li) * (2 * RS32) + s * 32 + lg * 8);
#pragma unroll
            for (int rt = 0; rt < 4; ++rt)
#pragma unroll
                for (int ct = 0; ct < 3; ++ct)
                    acc[rt][ct] = __builtin_amdgcn_mfma_f32_16x16x32_bf16(
                        af[rt], bf[ct], acc[rt][ct], 0, 0, 0);
        }
    }

    // epilogue: C/D layout col=lane&15, row=(lane>>4)*4+reg
#pragma unroll
    for (int ct = 0; ct < 3; ++ct) {
        int col = n0w + ct * 16 + li;
        float bv = bias[col];
#pragma unroll
        for (int rt = 0; rt < 4; ++rt) {
#pragma unroll
            for (int j = 0; j < 4; ++j) {
                int row = bm + rt * 16 + lg * 4 + j;
                float v = acc[rt][ct][j] + bv;
                if (RES)  v += res[(size_t)row * N + col];
                if (RELU) v = fmaxf(v, 0.f);
                store1(&C[(size_t)row * N + col], v);
            }
        }
    }
}

// ---------------- f32 GEMM (small, for ctx path): C = A @ W^T ------------------
template<typename AT, typename OT, bool BIAS, bool RELU, bool RES>
__global__ __launch_bounds__(256) void gemm_kernel(
    const AT* __restrict__ A, const float* __restrict__ W, int ldw,
    const float* __restrict__ bias, const float* __restrict__ res,
    OT* __restrict__ C, int M, int N, int K)
{
    constexpr int BM = 64, BN = 64, BK = 16;
    __shared__ float As[BK][BM + 4];
    __shared__ float Ws[BK][BN + 4];
    const int tid = threadIdx.x;
    const int bm = blockIdx.y * BM;
    const int bn = blockIdx.x * BN;
    const int tx = tid & 15, ty = tid >> 4;
    const int lr = tid >> 2;
    const int lc = (tid & 3) << 2;

    float acc[4][4];
#pragma unroll
    for (int i = 0; i < 4; i++)
#pragma unroll
        for (int j = 0; j < 4; j++) acc[i][j] = 0.f;

    for (int k0 = 0; k0 < K; k0 += BK) {
        F4 av = load4(A + (size_t)(bm + lr) * K + k0 + lc);
        As[lc + 0][lr] = av.x; As[lc + 1][lr] = av.y;
        As[lc + 2][lr] = av.z; As[lc + 3][lr] = av.w;
        int n = bn + lr;
        F4 wv = {0.f, 0.f, 0.f, 0.f};
        if (n < N) {
            float4 t = *(const float4*)(W + (size_t)n * ldw + k0 + lc);
            wv = {t.x, t.y, t.z, t.w};
        }
        Ws[lc + 0][lr] = wv.x; Ws[lc + 1][lr] = wv.y;
        Ws[lc + 2][lr] = wv.z; Ws[lc + 3][lr] = wv.w;
        __syncthreads();
#pragma unroll
        for (int kk = 0; kk < BK; ++kk) {
            float a[4], wr[4];
#pragma unroll
            for (int i = 0; i < 4; i++) a[i] = As[kk][ty * 4 + i];
#pragma unroll
            for (int j = 0; j < 4; j++) wr[j] = Ws[kk][tx * 4 + j];
#pragma unroll
            for (int i = 0; i < 4; i++)
#pragma unroll
                for (int j = 0; j < 4; j++) acc[i][j] += a[i] * wr[j];
        }
        __syncthreads();
    }
#pragma unroll
    for (int i = 0; i < 4; i++) {
        int m = bm + ty * 4 + i;
#pragma unroll
        for (int j = 0; j < 4; j++) {
            int n = bn + tx * 4 + j;
            if (n < N) {
                float v = acc[i][j];
                if (BIAS) v += bias[n];
                if (RES)  v += res[(size_t)m * N + n];
                if (RELU) v = fmaxf(v, 0.f);
                store1(&C[(size_t)m * N + n], v);
            }
        }
    }
}

// ---------------- MFMA attention: one block (4 waves) per (b, head) -------------
// Q,K staged [128][QS] bf16 (hd padded 18->32); V transposed [32][VS];
// per-wave P buffer [16][VS]. Wave handles 2 query tiles of 16.
__global__ __launch_bounds__(256) void attn_kernel(const u16* __restrict__ qkv,
                                                   u16* __restrict__ o)
{
    constexpr int QS = 40;    // Q/K row stride in bf16 (80 B -> uniform bank spread)
    constexpr int VS = 136;   // Vt/P row stride in bf16 (272 B)
    __shared__ __align__(16) u16 Qs[128 * QS];   // 10240 B
    __shared__ __align__(16) u16 Ks[128 * QS];   // 10240 B
    __shared__ __align__(16) u16 Vt[32 * VS];    //  8704 B
    __shared__ __align__(16) u16 Ps[4][16 * VS]; // 17408 B

    const int bh = blockIdx.x;
    const int b = bh >> 3, h = bh & 7;
    const int tid = threadIdx.x;
    const int w = tid >> 6, l = tid & 63;
    const int lg = l >> 4, li = l & 15;

    // zero Q,K,Vt (pads must be 0 so MFMA sees no garbage/NaN)
    {
        u32* z1 = (u32*)Qs;
        for (int i = tid; i < 128 * QS / 2; i += 256) z1[i] = 0;
        u32* z2 = (u32*)Ks;
        for (int i = tid; i < 128 * QS / 2; i += 256) z2[i] = 0;
        u32* z3 = (u32*)Vt;
        for (int i = tid; i < 32 * VS / 2; i += 256) z3[i] = 0;
    }
    __syncthreads();

    // load Q,K row-major; V transposed. Row t: 216 u32; q at 9h, k at 72+9h, v at 144+9h.
    const u32* q32 = (const u32*)(qkv + (size_t)b * T_ * TH_);
    for (int idx = tid; idx < 120 * 9; idx += 256) {
        int t = idx / 9, dp = idx - t * 9;
        u32 qv = q32[t * 216 + 9 * h + dp];
        u32 kv = q32[t * 216 + 72 + 9 * h + dp];
        u32 vv = q32[t * 216 + 144 + 9 * h + dp];
        ((u32*)(Qs + t * QS))[dp] = qv;
        ((u32*)(Ks + t * QS))[dp] = kv;
        Vt[(2 * dp) * VS + t]     = (u16)(vv & 0xffffu);
        Vt[(2 * dp + 1) * VS + t] = (u16)(vv >> 16);
    }
    __syncthreads();

    const float scale = 0.23570226039551584f; // 1/sqrt(18)
    u16* pw = &Ps[w][0];

    for (int mt = w * 2; mt < w * 2 + 2; ++mt) {
        // ---- S = Q K^T (one k-step, 8 key tiles) ----
        short8v qf = *(const short8v*)(Qs + (mt * 16 + li) * QS + lg * 8);
        f32x4 sacc[8];
#pragma unroll
        for (int nt = 0; nt < 8; ++nt) sacc[nt] = {0.f, 0.f, 0.f, 0.f};
#pragma unroll
        for (int nt = 0; nt < 8; ++nt) {
            short8v kf = *(const short8v*)(Ks + (nt * 16 + li) * QS + lg * 8);
            sacc[nt] = __builtin_amdgcn_mfma_f32_16x16x32_bf16(qf, kf, sacc[nt], 0, 0, 0);
        }

        // ---- wave-parallel softmax; write unnormalized exp to P (bf16) ----
        float invl[4];
#pragma unroll
        for (int j = 0; j < 4; ++j) {
            float v[8];
            float m = -1e30f;
#pragma unroll
            for (int nt = 0; nt < 8; ++nt) {
                float s = sacc[nt][j] * scale;
                if (nt == 7 && li >= 8) s = -1e30f;   // keys 120..127 masked
                v[nt] = s;
                m = fmaxf(m, s);
            }
#pragma unroll
            for (int off = 1; off < 16; off <<= 1)
                m = fmaxf(m, __shfl_xor(m, off));
            float sum = 0.f;
#pragma unroll
            for (int nt = 0; nt < 8; ++nt) {
                float p = __expf(v[nt] - m);          // masked -> exactly 0
                sum += p;
                pw[(lg * 4 + j) * VS + nt * 16 + li] = f2bf(p);
            }
#pragma unroll
            for (int off = 1; off < 16; off <<= 1)
                sum += __shfl_xor(sum, off);
            invl[j] = 1.f / sum;
        }

        // ---- O = P V (4 k-steps, 2 d-tiles); wave-private P, no barrier ----
        f32x4 oacc[2] = {{0.f,0.f,0.f,0.f},{0.f,0.f,0.f,0.f}};
#pragma unroll
        for (int s = 0; s < 4; ++s) {
            short8v pf = *(const short8v*)(pw + li * VS + s * 32 + lg * 8);
#pragma unroll
            for (int dt = 0; dt < 2; ++dt) {
                short8v vf = *(const short8v*)(Vt + (dt * 16 + li) * VS + s * 32 + lg * 8);
                oacc[dt] = __builtin_amdgcn_mfma_f32_16x16x32_bf16(pf, vf, oacc[dt], 0, 0, 0);
            }
        }

        // ---- store (normalize by 1/sum) ----
        const int q0 = mt * 16 + lg * 4;
#pragma unroll
        for (int dt = 0; dt < 2; ++dt) {
            int d = dt * 16 + li;
            if (d < HD_) {
#pragma unroll
                for (int j = 0; j < 4; ++j) {
                    int q = q0 + j;
                    if (q < T_)
                        o[((size_t)b * T_ + q) * E_ + h * HD_ + d] =
                            f2bf(oacc[dt][j] * invl[j]);
                }
            }
        }
    }
}

// ---------------- LayerNorm over rows of 144 (wave per row) --------------------
__global__ __launch_bounds__(256) void ln_kernel(const float* __restrict__ y,
                                                 const float* __restrict__ w,
                                                 const float* __restrict__ bsc,
                                                 float* __restrict__ out, int rows)
{
    int wid = threadIdx.x >> 6, lane = threadIdx.x & 63;
    int row = blockIdx.x * 4 + wid;
    if (row >= rows) return;
    const float* yr = y + (size_t)row * E_;
    float v0 = yr[lane], v1 = yr[lane + 64];
    float v2 = (lane < 16) ? yr[lane + 128] : 0.f;
    float s = v0 + v1 + v2;
    for (int off = 32; off; off >>= 1) s += __shfl_xor(s, off);
    float mean = s * (1.f / 144.f);
    float d0 = v0 - mean, d1 = v1 - mean;
    float d2 = (lane < 16) ? (v2 - mean) : 0.f;
    float q = d0 * d0 + d1 * d1 + d2 * d2;
    for (int off = 32; off; off >>= 1) q += __shfl_xor(q, off);
    float rstd = rsqrtf(q * (1.f / 144.f) + 1e-5f);
    float* orow = out + (size_t)row * E_;
    orow[lane]      = d0 * rstd * w[lane]      + bsc[lane];
    orow[lane + 64] = d1 * rstd * w[lane + 64] + bsc[lane + 64];
    if (lane < 16)
        orow[lane + 128] = d2 * rstd * w[lane + 128] + bsc[lane + 128];
}

// ---------------- mean over T (one chunk of nb batches) -------------------------
__global__ void mean_kernel(const float* __restrict__ x, float* __restrict__ out,
                            int nb)
{
    int idx = blockIdx.x * blockDim.x + threadIdx.x;
    if (idx >= nb * E_) return;
    int b = idx / E_, e = idx % E_;
    const float* p = x + (size_t)b * T_ * E_ + e;
    float s = 0.f;
    for (int t = 0; t < T_; t++) s += p[(size_t)t * E_];
    out[idx] = s * (1.f / 120.f);
}

__global__ void zero_kernel(float* __restrict__ p, int n)
{
    int i = blockIdx.x * blockDim.x + threadIdx.x;
    if (i < n) p[i] = 0.f;
}

__device__ __forceinline__ float sigmoidf_(float x) {
    return 1.f / (1.f + __expf(-x));
}

// ---------------- one GRU decode step (fused) -----------------------------------
__global__ __launch_bounds__(256) void gru_step_kernel(
    const float* __restrict__ inp, int inp_stride,
    const float* __restrict__ gctx,
    float* __restrict__ h,
    const float* __restrict__ w_ih,
    const float* __restrict__ w_hh,
    const float* __restrict__ b_hh,
    const float* __restrict__ spl_w,
    const float* __restrict__ spl_b,
    float* __restrict__ out)
{
    constexpr int BR = 4;
    __shared__ float xin[BR][E_], hs[BR][H_], hnew[BR][H_];
    __shared__ float gi[BR][TH_], gh[BR][TH_];
    const int b0 = blockIdx.x * BR;
    const int tid = threadIdx.x;

    for (int idx = tid; idx < BR * E_; idx += 256) {
        int r = idx / E_, e = idx % E_;
        xin[r][e] = inp[(size_t)(b0 + r) * inp_stride + e];
        hs[r][e]  = h[(size_t)(b0 + r) * H_ + e];
    }
    __syncthreads();

    for (int o = tid; o < BR * TH_; o += 256) {
        int r = o / TH_, f = o % TH_;
        const float4* wr = (const float4*)(w_ih + (size_t)f * GIN_);
        float s = gctx[(size_t)(b0 + r) * TH_ + f];
        const float4* xr = (const float4*)&xin[r][0];
#pragma unroll 9
        for (int e4 = 0; e4 < 36; e4++) {
            float4 wv = wr[e4], xv = xr[e4];
            s += xv.x * wv.x + xv.y * wv.y + xv.z * wv.z + xv.w * wv.w;
        }
        gi[r][f] = s;
        const float4* wh = (const float4*)(w_hh + (size_t)f * H_);
        float s2 = b_hh[f];
        const float4* hr = (const float4*)&hs[r][0];
#pragma unroll 9
        for (int e4 = 0; e4 < 36; e4++) {
            float4 wv = wh[e4], hv = hr[e4];
            s2 += hv.x * wv.x + hv.y * wv.y + hv.z * wv.z + hv.w * wv.w;
        }
        gh[r][f] = s2;
    }
    __syncthreads();

    for (int o = tid; o < BR * H_; o += 256) {
        int r = o / H_, e = o % H_;
        float rr = sigmoidf_(gi[r][e] + gh[r][e]);
        float z  = sigmoidf_(gi[r][H_ + e] + gh[r][H_ + e]);
        float n  = tanhf(gi[r][2 * H_ + e] + rr * gh[r][2 * H_ + e]);
        float hv = (1.f - z) * n + z * hs[r][e];
        hnew[r][e] = hv;
        h[(size_t)(b0 + r) * H_ + e] = hv;
    }
    __syncthreads();

    for (int o = tid; o < BR * E_; o += 256) {
        int r = o / E_, e = o % E_;
        const float4* wr = (const float4*)(spl_w + (size_t)e * H_);
        const float4* hr = (const float4*)&hnew[r][0];
        float s = spl_b[e];
#pragma unroll 9
        for (int e4 = 0; e4 < 36; e4++) {
            float4 wv = wr[e4], hv = hr[e4];
            s += hv.x * wv.x + hv.y * wv.y + hv.z * wv.z + hv.w * wv.w;
        }
        out[(size_t)(b0 + r) * (FUT_ * E_) + e] = s;
    }
}

// =================================================================================
extern "C" void kernel_launch(void* const* d_in, const int* in_sizes, int n_in,
                              void* d_out, int out_size, void* d_ws, size_t ws_size,
                              hipStream_t stream)
{
    const float* seed   = (const float*)d_in[0];
    const float* qkv_w  = (const float*)d_in[1];
    const float* qkv_b  = (const float*)d_in[2];
    const float* out_w  = (const float*)d_in[3];
    const float* out_b  = (const float*)d_in[4];
    const float* ln1_w  = (const float*)d_in[5];
    const float* ln1_b  = (const float*)d_in[6];
    const float* ffn1_w = (const float*)d_in[7];
    const float* ffn1_b = (const float*)d_in[8];
    const float* ffn2_w = (const float*)d_in[9];
    const float* ffn2_b = (const float*)d_in[10];
    const float* ln2_w  = (const float*)d_in[11];
    const float* ln2_b  = (const float*)d_in[12];
    const float* proj_w = (const float*)d_in[13];
    const float* proj_b = (const float*)d_in[14];
    const float* w_ih   = (const float*)d_in[15];
    const float* w_hh   = (const float*)d_in[16];
    const float* b_ih   = (const float*)d_in[17];
    const float* b_hh   = (const float*)d_in[18];
    const float* spl_w  = (const float*)d_in[19];
    const float* spl_b  = (const float*)d_in[20];

    // bf16 padded weight copies
    const size_t qkvW_n  = (size_t)L_ * TH_ * 160;
    const size_t outW_n  = (size_t)L_ * E_ * 160;
    const size_t ffn1W_n = (size_t)L_ * FF_ * 160;
    const size_t ffn2W_n = (size_t)L_ * E_ * 576;
    const size_t wbytes  = (qkvW_n + outW_n + ffn1W_n + ffn2W_n) * 2;

    const size_t persist = (size_t)B_ * 4 * (E_ + E_ + TH_ + H_) + wbytes;

    int nc = 16;
    for (int c = 1; c <= 16; c <<= 1) {
        size_t rows = (size_t)(B_ / c) * T_;
        size_t need = persist
                    + rows * E_ * 4 * 2
                    + rows * FF_ * 2
                    + rows * E_ * 2;
        if (need <= ws_size) { nc = c; break; }
    }
    const int BC = B_ / nc;
    const int CR = BC * T_;

    char* wsp = (char*)d_ws;
    float* xA   = (float*)wsp; wsp += (size_t)CR * E_ * 4;
    float* xB   = (float*)wsp; wsp += (size_t)CR * E_ * 4;
    u16*   qf   = (u16*)wsp;   wsp += (size_t)CR * FF_ * 2;
    u16*   ob   = (u16*)wsp;   wsp += (size_t)CR * E_ * 2;
    float* ctxm = (float*)wsp; wsp += (size_t)B_ * E_ * 4;
    float* ctx  = (float*)wsp; wsp += (size_t)B_ * E_ * 4;
    float* gctx = (float*)wsp; wsp += (size_t)B_ * TH_ * 4;
    float* h    = (float*)wsp; wsp += (size_t)B_ * H_ * 4;
    u16* qkvWb  = (u16*)wsp;   wsp += qkvW_n * 2;
    u16* outWb  = (u16*)wsp;   wsp += outW_n * 2;
    u16* ffn1Wb = (u16*)wsp;   wsp += ffn1W_n * 2;
    u16* ffn2Wb = (u16*)wsp;   wsp += ffn2W_n * 2;

    // convert weights once per launch (deterministic, ~1M elems total)
    wconv_kernel<<<(int)((qkvW_n + 255) / 256), 256, 0, stream>>>(qkv_w, qkvWb, L_ * TH_, 144, 160);
    wconv_kernel<<<(int)((outW_n + 255) / 256), 256, 0, stream>>>(out_w, outWb, L_ * E_, 144, 160);
    wconv_kernel<<<(int)((ffn1W_n + 255) / 256), 256, 0, stream>>>(ffn1_w, ffn1Wb, L_ * FF_, 144, 160);
    wconv_kernel<<<(int)((ffn2W_n + 255) / 256), 256, 0, stream>>>(ffn2_w, ffn2Wb, L_ * E_, 576, 576);

    auto grid  = [](int M, int N) { return dim3((N + 63) / 64, M / 64); };
    auto gridm = [](int M, int N) { return dim3(N / 144, M / 64); };

    for (int c = 0; c < nc; c++) {
        const int b0 = c * BC;
        const float* xin = seed + (size_t)b0 * T_ * E_;
        for (int l = 0; l < L_; l++) {
            gemm_mfma<144, float, u16, false, false><<<gridm(CR, TH_), 192, 0, stream>>>(
                xin, qkvWb + (size_t)l * TH_ * 160, qkv_b + (size_t)l * TH_,
                nullptr, qf, CR, TH_);
            attn_kernel<<<BC * NH_, 256, 0, stream>>>(qf, ob);
            gemm_mfma<144, u16, float, false, true><<<gridm(CR, E_), 192, 0, stream>>>(
                ob, outWb + (size_t)l * E_ * 160, out_b + (size_t)l * E_,
                xin, xB, CR, E_);
            ln_kernel<<<CR / 4, 256, 0, stream>>>(xB, ln1_w + (size_t)l * E_,
                                                  ln1_b + (size_t)l * E_, xA, CR);
            gemm_mfma<144, float, u16, true, false><<<gridm(CR, FF_), 192, 0, stream>>>(
                xA, ffn1Wb + (size_t)l * FF_ * 160, ffn1_b + (size_t)l * FF_,
                nullptr, qf, CR, FF_);
            gemm_mfma<576, u16, float, false, true><<<gridm(CR, E_), 192, 0, stream>>>(
                qf, ffn2Wb + (size_t)l * E_ * 576, ffn2_b + (size_t)l * E_,
                xA, xB, CR, E_);
            ln_kernel<<<CR / 4, 256, 0, stream>>>(xB, ln2_w + (size_t)l * E_,
                                                  ln2_b + (size_t)l * E_, xA, CR);
            xin = xA;
        }
        mean_kernel<<<(BC * E_ + 255) / 256, 256, 0, stream>>>(xA, ctxm + (size_t)b0 * E_, BC);
    }

    gemm_kernel<float, float, true, false, false><<<grid(B_, E_), 256, 0, stream>>>(
        ctxm, proj_w, E_, proj_b, nullptr, ctx, B_, E_, E_);
    gemm_kernel<float, float, true, false, false><<<grid(B_, TH_), 256, 0, stream>>>(
        ctx, w_ih + E_, GIN_, b_ih, nullptr, gctx, B_, TH_, E_);
    zero_kernel<<<(B_ * H_ + 255) / 256, 256, 0, stream>>>(h, B_ * H_);

    float* out = (float*)d_out;
    for (int s = 0; s < FUT_; s++) {
        const float* inp = s ? (const float*)(out + (size_t)(s - 1) * E_)
                             : seed + (size_t)(T_ - 1) * E_;
        int istr = s ? FUT_ * E_ : T_ * E_;
        gru_step_kernel<<<B_ / 4, 256, 0, stream>>>(
            inp, istr, gctx, h, w_ih, w_hh, b_hh, spl_w, spl_b,
            out + (size_t)s * E_);
    }
}

// Round 5
// 6011.512 us; speedup vs baseline: 2.3546x; 1.1813x over previous
//
#include <hip/hip_runtime.h>

#define B_   2048
#define T_   120
#define E_   144
#define L_   4
#define NH_  8
#define HD_  18
#define FF_  576
#define H_   144
#define GIN_ 288
#define TH_  432   // 3*E = 3*H
#define FUT_ 24
#define BT_  (B_*T_)

typedef unsigned short u16;
typedef unsigned int   u32;

typedef __attribute__((ext_vector_type(8))) short short8v;  // 8 bf16 (4 VGPRs)
typedef __attribute__((ext_vector_type(4))) float f32x4;

__device__ __forceinline__ float bf2f(u16 u) {
    u32 x = ((u32)u) << 16;
    return __uint_as_float(x);
}
__device__ __forceinline__ u16 f2bf(float f) {
    u32 x = __float_as_uint(f);
    u32 r = (x + 0x7fffu + ((x >> 16) & 1u)) >> 16;
    return (u16)r;
}

struct F4 { float x, y, z, w; };

__device__ __forceinline__ F4 load4(const float* p) {
    float4 v = *(const float4*)p;
    return {v.x, v.y, v.z, v.w};
}
__device__ __forceinline__ void store1(float* p, float v) { *p = v; }
__device__ __forceinline__ void store1(u16* p, float v)   { *p = f2bf(v); }

// ---------------- weight convert + K-pad to bf16 --------------------------------
__global__ void wconv_kernel(const float* __restrict__ src, u16* __restrict__ dst,
                             int rows, int K, int KP)
{
    int i = blockIdx.x * 256 + threadIdx.x;
    if (i >= rows * KP) return;
    int r = i / KP, k = i - r * KP;
    dst[i] = (k < K) ? f2bf(src[(size_t)r * K + k]) : (u16)0;
}

// ---------------- f32 -> bf16 cast (paired) -------------------------------------
__global__ void cast_bf_kernel(const float* __restrict__ src, u16* __restrict__ dst,
                               int n2)
{
    int i = blockIdx.x * 256 + threadIdx.x;
    if (i >= n2) return;
    float2 t = ((const float2*)src)[i];
    ((u32*)dst)[i] = ((u32)f2bf(t.y) << 16) | (u32)f2bf(t.x);
}

// ---------------- MFMA GEMM: C[M,N] = A[M,K] @ Wb[N,KP]^T (+bias) ---------------
// 192 threads = 3 waves. Block tile 64 x 144. Wave tile 64 x 48 (4x3 MFMA tiles).
// A is bf16 [M,K]. K = 144 (padded 160 in Wb). Used for qkv projection.
template<typename OT>
__global__ __launch_bounds__(192) void gemm_mfma(
    const u16* __restrict__ A, const u16* __restrict__ Wb,
    const float* __restrict__ bias, OT* __restrict__ C, int M, int N)
{
    constexpr int RS32 = 84;
    __shared__ u32 lds[64 * RS32];

    const int tid = threadIdx.x;
    const int w   = tid >> 6;
    const int l   = tid & 63;
    const int lg  = l >> 4;
    const int li  = l & 15;
    const int bm  = blockIdx.y * 64;
    const int n0w = blockIdx.x * 144 + w * 48;

    f32x4 acc[4][3];
#pragma unroll
    for (int rt = 0; rt < 4; rt++)
#pragma unroll
        for (int ct = 0; ct < 3; ct++) acc[rt][ct] = {0.f, 0.f, 0.f, 0.f};

    {
        const u32* __restrict__ a32 = (const u32*)A;
        int row = tid / 80, kk = tid - row * 80;
        for (int i = tid; i < 64 * 80; i += 192) {
            u32 v = (kk < 72) ? a32[(size_t)(bm + row) * 72 + kk] : 0u;
            lds[row * RS32 + kk] = v;
            kk += 32; row += 2; if (kk >= 80) { kk -= 80; row += 1; }
        }
    }
    __syncthreads();

    const u16* lds16 = (const u16*)lds;
#pragma unroll
    for (int s = 0; s < 5; ++s) {
        short8v bf[3];
#pragma unroll
        for (int ct = 0; ct < 3; ++ct) {
            int n = n0w + ct * 16 + li;
            bf[ct] = *(const short8v*)(Wb + (size_t)n * 160 + s * 32 + lg * 8);
        }
        short8v af[4];
#pragma unroll
        for (int rt = 0; rt < 4; ++rt)
            af[rt] = *(const short8v*)(lds16 + (rt * 16 + li) * (2 * RS32) + s * 32 + lg * 8);
#pragma unroll
        for (int rt = 0; rt < 4; ++rt)
#pragma unroll
            for (int ct = 0; ct < 3; ++ct)
                acc[rt][ct] = __builtin_amdgcn_mfma_f32_16x16x32_bf16(
                    af[rt], bf[ct], acc[rt][ct], 0, 0, 0);
    }

#pragma unroll
    for (int ct = 0; ct < 3; ++ct) {
        int col = n0w + ct * 16 + li;
        float bv = bias[col];
#pragma unroll
        for (int rt = 0; rt < 4; ++rt) {
#pragma unroll
            for (int j = 0; j < 4; ++j) {
                int row = bm + rt * 16 + lg * 4 + j;
                store1(&C[(size_t)row * N + col], acc[rt][ct][j] + bv);
            }
        }
    }
}

// ---------------- out-proj + bias + residual + LayerNorm (fused) ----------------
// A[M,144] bf16 @ Wb[144,160]^T + bias + res(f32) -> LN -> obf(bf16), of(f32)
__global__ __launch_bounds__(192) void outln_kernel(
    const u16* __restrict__ A, const u16* __restrict__ Wb,
    const float* __restrict__ bias, const float* __restrict__ res,
    const float* __restrict__ lnw, const float* __restrict__ lnb,
    u16* __restrict__ obf, float* __restrict__ of)
{
    constexpr int RS32 = 84;
    __shared__ u32 lds[64 * RS32];
    __shared__ float lnS[3][64], lnQ[3][64];

    const int tid = threadIdx.x;
    const int w   = tid >> 6;
    const int l   = tid & 63;
    const int lg  = l >> 4;
    const int li  = l & 15;
    const int bm  = blockIdx.x * 64;

    f32x4 acc[4][3];
#pragma unroll
    for (int rt = 0; rt < 4; rt++)
#pragma unroll
        for (int ct = 0; ct < 3; ct++) acc[rt][ct] = {0.f, 0.f, 0.f, 0.f};

    {
        const u32* __restrict__ a32 = (const u32*)A;
        int row = tid / 80, kk = tid - row * 80;
        for (int i = tid; i < 64 * 80; i += 192) {
            u32 v = (kk < 72) ? a32[(size_t)(bm + row) * 72 + kk] : 0u;
            lds[row * RS32 + kk] = v;
            kk += 32; row += 2; if (kk >= 80) { kk -= 80; row += 1; }
        }
    }
    __syncthreads();

    const u16* lds16 = (const u16*)lds;
#pragma unroll
    for (int s = 0; s < 5; ++s) {
        short8v bf[3];
#pragma unroll
        for (int ct = 0; ct < 3; ++ct) {
            int n = w * 48 + ct * 16 + li;
            bf[ct] = *(const short8v*)(Wb + (size_t)n * 160 + s * 32 + lg * 8);
        }
        short8v af[4];
#pragma unroll
        for (int rt = 0; rt < 4; ++rt)
            af[rt] = *(const short8v*)(lds16 + (rt * 16 + li) * (2 * RS32) + s * 32 + lg * 8);
#pragma unroll
        for (int rt = 0; rt < 4; ++rt)
#pragma unroll
            for (int ct = 0; ct < 3; ++ct)
                acc[rt][ct] = __builtin_amdgcn_mfma_f32_16x16x32_bf16(
                    af[rt], bf[ct], acc[rt][ct], 0, 0, 0);
    }

    // v = gemm + bias + residual
    float vv[4][3][4];
#pragma unroll
    for (int ct = 0; ct < 3; ++ct) {
        int col = w * 48 + ct * 16 + li;
        float bv = bias[col];
#pragma unroll
        for (int rt = 0; rt < 4; ++rt)
#pragma unroll
            for (int j = 0; j < 4; ++j) {
                int row = bm + rt * 16 + lg * 4 + j;
                vv[rt][ct][j] = acc[rt][ct][j] + bv + res[(size_t)row * E_ + col];
            }
    }
    // per-row sum / sumsq (48-col partial per wave)
#pragma unroll
    for (int rt = 0; rt < 4; ++rt)
#pragma unroll
        for (int j = 0; j < 4; ++j) {
            float s = vv[rt][0][j] + vv[rt][1][j] + vv[rt][2][j];
            float q = vv[rt][0][j] * vv[rt][0][j] + vv[rt][1][j] * vv[rt][1][j]
                    + vv[rt][2][j] * vv[rt][2][j];
#pragma unroll
            for (int off = 1; off < 16; off <<= 1) {
                s += __shfl_xor(s, off);
                q += __shfl_xor(q, off);
            }
            if (li == 0) {
                lnS[w][rt * 16 + lg * 4 + j] = s;
                lnQ[w][rt * 16 + lg * 4 + j] = q;
            }
        }
    __syncthreads();
#pragma unroll
    for (int rt = 0; rt < 4; ++rt)
#pragma unroll
        for (int j = 0; j < 4; ++j) {
            int r = rt * 16 + lg * 4 + j;
            float mean = (lnS[0][r] + lnS[1][r] + lnS[2][r]) * (1.f / 144.f);
            float var  = (lnQ[0][r] + lnQ[1][r] + lnQ[2][r]) * (1.f / 144.f) - mean * mean;
            float rstd = rsqrtf(var + 1e-5f);
            int row = bm + r;
#pragma unroll
            for (int ct = 0; ct < 3; ++ct) {
                int col = w * 48 + ct * 16 + li;
                float o = (vv[rt][ct][j] - mean) * rstd * lnw[col] + lnb[col];
                obf[(size_t)row * E_ + col] = f2bf(o);
                of[(size_t)row * E_ + col]  = o;
            }
        }
}

// ---------------- fused FFN: relu(A@W1^T+b1)@W2^T+b2 + res -> LN -> out ---------
// A[M,144] bf16; W1[576,160] bf16; W2[144,576] bf16. ff chunked 3x192 in LDS.
__global__ __launch_bounds__(192) void ffn_kernel(
    const u16* __restrict__ A, const u16* __restrict__ W1,
    const float* __restrict__ b1, const u16* __restrict__ W2,
    const float* __restrict__ b2, const float* __restrict__ res,
    const float* __restrict__ lnw, const float* __restrict__ lnb,
    u16* __restrict__ obf, float* __restrict__ of)
{
    constexpr int RSA = 84;    // A-stage row stride (u32)
    constexpr int RSF = 100;   // ff-chunk row stride (u32) = 200 bf16
    __shared__ u32 Als[64 * RSA];   // 21504 B
    __shared__ u32 Fls[64 * RSF];   // 25600 B
    __shared__ float lnS[3][64], lnQ[3][64];

    const int tid = threadIdx.x;
    const int w   = tid >> 6;
    const int l   = tid & 63;
    const int lg  = l >> 4;
    const int li  = l & 15;
    const int bm  = blockIdx.x * 64;

    {
        const u32* __restrict__ a32 = (const u32*)A;
        int row = tid / 80, kk = tid - row * 80;
        for (int i = tid; i < 64 * 80; i += 192) {
            u32 v = (kk < 72) ? a32[(size_t)(bm + row) * 72 + kk] : 0u;
            Als[row * RSA + kk] = v;
            kk += 32; row += 2; if (kk >= 80) { kk -= 80; row += 1; }
        }
    }
    __syncthreads();

    const u16* als16 = (const u16*)Als;
    u16* fls16 = (u16*)Fls;

    f32x4 acc2[4][3];
#pragma unroll
    for (int rt = 0; rt < 4; rt++)
#pragma unroll
        for (int ct = 0; ct < 3; ct++) acc2[rt][ct] = {0.f, 0.f, 0.f, 0.f};

    for (int c = 0; c < 3; ++c) {
        // ---- ffn1 chunk: cols [c*192, c*192+192); wave covers 64 of them ----
        f32x4 acc1[4][4];
#pragma unroll
        for (int rt = 0; rt < 4; rt++)
#pragma unroll
            for (int ct = 0; ct < 4; ct++) acc1[rt][ct] = {0.f, 0.f, 0.f, 0.f};
#pragma unroll
        for (int s = 0; s < 5; ++s) {
            short8v bf[4];
#pragma unroll
            for (int ct = 0; ct < 4; ++ct) {
                int n1 = c * 192 + w * 64 + ct * 16 + li;
                bf[ct] = *(const short8v*)(W1 + (size_t)n1 * 160 + s * 32 + lg * 8);
            }
            short8v af[4];
#pragma unroll
            for (int rt = 0; rt < 4; ++rt)
                af[rt] = *(const short8v*)(als16 + (rt * 16 + li) * (2 * RSA) + s * 32 + lg * 8);
#pragma unroll
            for (int rt = 0; rt < 4; ++rt)
#pragma unroll
                for (int ct = 0; ct < 4; ++ct)
                    acc1[rt][ct] = __builtin_amdgcn_mfma_f32_16x16x32_bf16(
                        af[rt], bf[ct], acc1[rt][ct], 0, 0, 0);
        }
        __syncthreads();   // prev-chunk ffn2 reads of Fls complete
        // write relu(ff) chunk to LDS as bf16
#pragma unroll
        for (int ct = 0; ct < 4; ++ct) {
            int colc = w * 64 + ct * 16 + li;
            float bv = b1[c * 192 + colc];
#pragma unroll
            for (int rt = 0; rt < 4; ++rt)
#pragma unroll
                for (int j = 0; j < 4; ++j) {
                    int row = rt * 16 + lg * 4 + j;
                    float v = fmaxf(acc1[rt][ct][j] + bv, 0.f);
                    fls16[row * (2 * RSF) + colc] = f2bf(v);
                }
        }
        __syncthreads();
        // ---- ffn2 partial: K-range [c*192, c*192+192) ----
#pragma unroll
        for (int s2 = 0; s2 < 6; ++s2) {
            short8v wf[3];
#pragma unroll
            for (int ct = 0; ct < 3; ++ct) {
                int n2 = w * 48 + ct * 16 + li;
                wf[ct] = *(const short8v*)(W2 + (size_t)n2 * 576 + c * 192 + s2 * 32 + lg * 8);
            }
            short8v pf[4];
#pragma unroll
            for (int rt = 0; rt < 4; ++rt)
                pf[rt] = *(const short8v*)(fls16 + (rt * 16 + li) * (2 * RSF) + s2 * 32 + lg * 8);
#pragma unroll
            for (int rt = 0; rt < 4; ++rt)
#pragma unroll
                for (int ct = 0; ct < 3; ++ct)
                    acc2[rt][ct] = __builtin_amdgcn_mfma_f32_16x16x32_bf16(
                        pf[rt], wf[ct], acc2[rt][ct], 0, 0, 0);
        }
    }

    // ---- epilogue: + b2 + res -> LN -> write bf16 + f32 ----
    float vv[4][3][4];
#pragma unroll
    for (int ct = 0; ct < 3; ++ct) {
        int col = w * 48 + ct * 16 + li;
        float bv = b2[col];
#pragma unroll
        for (int rt = 0; rt < 4; ++rt)
#pragma unroll
            for (int j = 0; j < 4; ++j) {
                int row = bm + rt * 16 + lg * 4 + j;
                vv[rt][ct][j] = acc2[rt][ct][j] + bv + res[(size_t)row * E_ + col];
            }
    }
#pragma unroll
    for (int rt = 0; rt < 4; ++rt)
#pragma unroll
        for (int j = 0; j < 4; ++j) {
            float s = vv[rt][0][j] + vv[rt][1][j] + vv[rt][2][j];
            float q = vv[rt][0][j] * vv[rt][0][j] + vv[rt][1][j] * vv[rt][1][j]
                    + vv[rt][2][j] * vv[rt][2][j];
#pragma unroll
            for (int off = 1; off < 16; off <<= 1) {
                s += __shfl_xor(s, off);
                q += __shfl_xor(q, off);
            }
            if (li == 0) {
                lnS[w][rt * 16 + lg * 4 + j] = s;
                lnQ[w][rt * 16 + lg * 4 + j] = q;
            }
        }
    __syncthreads();
#pragma unroll
    for (int rt = 0; rt < 4; ++rt)
#pragma unroll
        for (int j = 0; j < 4; ++j) {
            int r = rt * 16 + lg * 4 + j;
            float mean = (lnS[0][r] + lnS[1][r] + lnS[2][r]) * (1.f / 144.f);
            float var  = (lnQ[0][r] + lnQ[1][r] + lnQ[2][r]) * (1.f / 144.f) - mean * mean;
            float rstd = rsqrtf(var + 1e-5f);
            int row = bm + r;
#pragma unroll
            for (int ct = 0; ct < 3; ++ct) {
                int col = w * 48 + ct * 16 + li;
                float o = (vv[rt][ct][j] - mean) * rstd * lnw[col] + lnb[col];
                obf[(size_t)row * E_ + col] = f2bf(o);
                of[(size_t)row * E_ + col]  = o;
            }
        }
}

// ---------------- f32 GEMM (small, ctx path): C = A @ W^T + bias ----------------
template<typename AT, typename OT, bool BIAS, bool RELU, bool RES>
__global__ __launch_bounds__(256) void gemm_kernel(
    const AT* __restrict__ A, const float* __restrict__ W, int ldw,
    const float* __restrict__ bias, const float* __restrict__ res,
    OT* __restrict__ C, int M, int N, int K)
{
    constexpr int BM = 64, BN = 64, BK = 16;
    __shared__ float As[BK][BM + 4];
    __shared__ float Ws[BK][BN + 4];
    const int tid = threadIdx.x;
    const int bm = blockIdx.y * BM;
    const int bn = blockIdx.x * BN;
    const int tx = tid & 15, ty = tid >> 4;
    const int lr = tid >> 2;
    const int lc = (tid & 3) << 2;

    float acc[4][4];
#pragma unroll
    for (int i = 0; i < 4; i++)
#pragma unroll
        for (int j = 0; j < 4; j++) acc[i][j] = 0.f;

    for (int k0 = 0; k0 < K; k0 += BK) {
        F4 av = load4(A + (size_t)(bm + lr) * K + k0 + lc);
        As[lc + 0][lr] = av.x; As[lc + 1][lr] = av.y;
        As[lc + 2][lr] = av.z; As[lc + 3][lr] = av.w;
        int n = bn + lr;
        F4 wv = {0.f, 0.f, 0.f, 0.f};
        if (n < N) {
            float4 t = *(const float4*)(W + (size_t)n * ldw + k0 + lc);
            wv = {t.x, t.y, t.z, t.w};
        }
        Ws[lc + 0][lr] = wv.x; Ws[lc + 1][lr] = wv.y;
        Ws[lc + 2][lr] = wv.z; Ws[lc + 3][lr] = wv.w;
        __syncthreads();
#pragma unroll
        for (int kk = 0; kk < BK; ++kk) {
            float a[4], wr[4];
#pragma unroll
            for (int i = 0; i < 4; i++) a[i] = As[kk][ty * 4 + i];
#pragma unroll
            for (int j = 0; j < 4; j++) wr[j] = Ws[kk][tx * 4 + j];
#pragma unroll
            for (int i = 0; i < 4; i++)
#pragma unroll
                for (int j = 0; j < 4; j++) acc[i][j] += a[i] * wr[j];
        }
        __syncthreads();
    }
#pragma unroll
    for (int i = 0; i < 4; i++) {
        int m = bm + ty * 4 + i;
#pragma unroll
        for (int j = 0; j < 4; j++) {
            int n = bn + tx * 4 + j;
            if (n < N) {
                float v = acc[i][j];
                if (BIAS) v += bias[n];
                if (RES)  v += res[(size_t)m * N + n];
                if (RELU) v = fmaxf(v, 0.f);
                store1(&C[(size_t)m * N + n], v);
            }
        }
    }
}

// ---------------- MFMA attention: one block (4 waves) per (b, head) -------------
__global__ __launch_bounds__(256) void attn_kernel(const u16* __restrict__ qkv,
                                                   u16* __restrict__ o)
{
    constexpr int QS = 40;
    constexpr int VS = 136;
    __shared__ __align__(16) u16 Qs[128 * QS];
    __shared__ __align__(16) u16 Ks[128 * QS];
    __shared__ __align__(16) u16 Vt[32 * VS];
    __shared__ __align__(16) u16 Ps[4][16 * VS];

    const int bh = blockIdx.x;
    const int b = bh >> 3, h = bh & 7;
    const int tid = threadIdx.x;
    const int w = tid >> 6, l = tid & 63;
    const int lg = l >> 4, li = l & 15;

    {
        u32* z1 = (u32*)Qs;
        for (int i = tid; i < 128 * QS / 2; i += 256) z1[i] = 0;
        u32* z2 = (u32*)Ks;
        for (int i = tid; i < 128 * QS / 2; i += 256) z2[i] = 0;
        u32* z3 = (u32*)Vt;
        for (int i = tid; i < 32 * VS / 2; i += 256) z3[i] = 0;
    }
    __syncthreads();

    const u32* q32 = (const u32*)(qkv + (size_t)b * T_ * TH_);
    for (int idx = tid; idx < 120 * 9; idx += 256) {
        int t = idx / 9, dp = idx - t * 9;
        u32 qv = q32[t * 216 + 9 * h + dp];
        u32 kv = q32[t * 216 + 72 + 9 * h + dp];
        u32 vv = q32[t * 216 + 144 + 9 * h + dp];
        ((u32*)(Qs + t * QS))[dp] = qv;
        ((u32*)(Ks + t * QS))[dp] = kv;
        Vt[(2 * dp) * VS + t]     = (u16)(vv & 0xffffu);
        Vt[(2 * dp + 1) * VS + t] = (u16)(vv >> 16);
    }
    __syncthreads();

    const float scale = 0.23570226039551584f; // 1/sqrt(18)
    u16* pw = &Ps[w][0];

    for (int mt = w * 2; mt < w * 2 + 2; ++mt) {
        short8v qf = *(const short8v*)(Qs + (mt * 16 + li) * QS + lg * 8);
        f32x4 sacc[8];
#pragma unroll
        for (int nt = 0; nt < 8; ++nt) sacc[nt] = {0.f, 0.f, 0.f, 0.f};
#pragma unroll
        for (int nt = 0; nt < 8; ++nt) {
            short8v kf = *(const short8v*)(Ks + (nt * 16 + li) * QS + lg * 8);
            sacc[nt] = __builtin_amdgcn_mfma_f32_16x16x32_bf16(qf, kf, sacc[nt], 0, 0, 0);
        }

        float invl[4];
#pragma unroll
        for (int j = 0; j < 4; ++j) {
            float v[8];
            float m = -1e30f;
#pragma unroll
            for (int nt = 0; nt < 8; ++nt) {
                float s = sacc[nt][j] * scale;
                if (nt == 7 && li >= 8) s = -1e30f;
                v[nt] = s;
                m = fmaxf(m, s);
            }
#pragma unroll
            for (int off = 1; off < 16; off <<= 1)
                m = fmaxf(m, __shfl_xor(m, off));
            float sum = 0.f;
#pragma unroll
            for (int nt = 0; nt < 8; ++nt) {
                float p = __expf(v[nt] - m);
                sum += p;
                pw[(lg * 4 + j) * VS + nt * 16 + li] = f2bf(p);
            }
#pragma unroll
            for (int off = 1; off < 16; off <<= 1)
                sum += __shfl_xor(sum, off);
            invl[j] = 1.f / sum;
        }

        f32x4 oacc[2] = {{0.f,0.f,0.f,0.f},{0.f,0.f,0.f,0.f}};
#pragma unroll
        for (int s = 0; s < 4; ++s) {
            short8v pf = *(const short8v*)(pw + li * VS + s * 32 + lg * 8);
#pragma unroll
            for (int dt = 0; dt < 2; ++dt) {
                short8v vf = *(const short8v*)(Vt + (dt * 16 + li) * VS + s * 32 + lg * 8);
                oacc[dt] = __builtin_amdgcn_mfma_f32_16x16x32_bf16(pf, vf, oacc[dt], 0, 0, 0);
            }
        }

        const int q0 = mt * 16 + lg * 4;
#pragma unroll
        for (int dt = 0; dt < 2; ++dt) {
            int d = dt * 16 + li;
            if (d < HD_) {
#pragma unroll
                for (int j = 0; j < 4; ++j) {
                    int q = q0 + j;
                    if (q < T_)
                        o[((size_t)b * T_ + q) * E_ + h * HD_ + d] =
                            f2bf(oacc[dt][j] * invl[j]);
                }
            }
        }
    }
}

// ---------------- mean over T (one chunk of nb batches) -------------------------
__global__ void mean_kernel(const float* __restrict__ x, float* __restrict__ out,
                            int nb)
{
    int idx = blockIdx.x * blockDim.x + threadIdx.x;
    if (idx >= nb * E_) return;
    int b = idx / E_, e = idx % E_;
    const float* p = x + (size_t)b * T_ * E_ + e;
    float s = 0.f;
    for (int t = 0; t < T_; t++) s += p[(size_t)t * E_];
    out[idx] = s * (1.f / 120.f);
}

__global__ void zero_kernel(float* __restrict__ p, int n)
{
    int i = blockIdx.x * blockDim.x + threadIdx.x;
    if (i < n) p[i] = 0.f;
}

__device__ __forceinline__ float sigmoidf_(float x) {
    return 1.f / (1.f + __expf(-x));
}

// ---------------- one GRU decode step (fused) -----------------------------------
__global__ __launch_bounds__(256) void gru_step_kernel(
    const float* __restrict__ inp, int inp_stride,
    const float* __restrict__ gctx,
    float* __restrict__ h,
    const float* __restrict__ w_ih,
    const float* __restrict__ w_hh,
    const float* __restrict__ b_hh,
    const float* __restrict__ spl_w,
    const float* __restrict__ spl_b,
    float* __restrict__ out)
{
    constexpr int BR = 4;
    __shared__ float xin[BR][E_], hs[BR][H_], hnew[BR][H_];
    __shared__ float gi[BR][TH_], gh[BR][TH_];
    const int b0 = blockIdx.x * BR;
    const int tid = threadIdx.x;

    for (int idx = tid; idx < BR * E_; idx += 256) {
        int r = idx / E_, e = idx % E_;
        xin[r][e] = inp[(size_t)(b0 + r) * inp_stride + e];
        hs[r][e]  = h[(size_t)(b0 + r) * H_ + e];
    }
    __syncthreads();

    for (int o = tid; o < BR * TH_; o += 256) {
        int r = o / TH_, f = o % TH_;
        const float4* wr = (const float4*)(w_ih + (size_t)f * GIN_);
        float s = gctx[(size_t)(b0 + r) * TH_ + f];
        const float4* xr = (const float4*)&xin[r][0];
#pragma unroll 9
        for (int e4 = 0; e4 < 36; e4++) {
            float4 wv = wr[e4], xv = xr[e4];
            s += xv.x * wv.x + xv.y * wv.y + xv.z * wv.z + xv.w * wv.w;
        }
        gi[r][f] = s;
        const float4* wh = (const float4*)(w_hh + (size_t)f * H_);
        float s2 = b_hh[f];
        const float4* hr = (const float4*)&hs[r][0];
#pragma unroll 9
        for (int e4 = 0; e4 < 36; e4++) {
            float4 wv = wh[e4], hv = hr[e4];
            s2 += hv.x * wv.x + hv.y * wv.y + hv.z * wv.z + hv.w * wv.w;
        }
        gh[r][f] = s2;
    }
    __syncthreads();

    for (int o = tid; o < BR * H_; o += 256) {
        int r = o / H_, e = o % H_;
        float rr = sigmoidf_(gi[r][e] + gh[r][e]);
        float z  = sigmoidf_(gi[r][H_ + e] + gh[r][H_ + e]);
        float n  = tanhf(gi[r][2 * H_ + e] + rr * gh[r][2 * H_ + e]);
        float hv = (1.f - z) * n + z * hs[r][e];
        hnew[r][e] = hv;
        h[(size_t)(b0 + r) * H_ + e] = hv;
    }
    __syncthreads();

    for (int o = tid; o < BR * E_; o += 256) {
        int r = o / E_, e = o % E_;
        const float4* wr = (const float4*)(spl_w + (size_t)e * H_);
        const float4* hr = (const float4*)&hnew[r][0];
        float s = spl_b[e];
#pragma unroll 9
        for (int e4 = 0; e4 < 36; e4++) {
            float4 wv = wr[e4], hv = hr[e4];
            s += hv.x * wv.x + hv.y * wv.y + hv.z * wv.z + hv.w * wv.w;
        }
        out[(size_t)(b0 + r) * (FUT_ * E_) + e] = s;
    }
}

// =================================================================================
extern "C" void kernel_launch(void* const* d_in, const int* in_sizes, int n_in,
                              void* d_out, int out_size, void* d_ws, size_t ws_size,
                              hipStream_t stream)
{
    const float* seed   = (const float*)d_in[0];
    const float* qkv_w  = (const float*)d_in[1];
    const float* qkv_b  = (const float*)d_in[2];
    const float* out_w  = (const float*)d_in[3];
    const float* out_b  = (const float*)d_in[4];
    const float* ln1_w  = (const float*)d_in[5];
    const float* ln1_b  = (const float*)d_in[6];
    const float* ffn1_w = (const float*)d_in[7];
    const float* ffn1_b = (const float*)d_in[8];
    const float* ffn2_w = (const float*)d_in[9];
    const float* ffn2_b = (const float*)d_in[10];
    const float* ln2_w  = (const float*)d_in[11];
    const float* ln2_b  = (const float*)d_in[12];
    const float* proj_w = (const float*)d_in[13];
    const float* proj_b = (const float*)d_in[14];
    const float* w_ih   = (const float*)d_in[15];
    const float* w_hh   = (const float*)d_in[16];
    const float* b_ih   = (const float*)d_in[17];
    const float* b_hh   = (const float*)d_in[18];
    const float* spl_w  = (const float*)d_in[19];
    const float* spl_b  = (const float*)d_in[20];

    // bf16 padded weight copies
    const size_t qkvW_n  = (size_t)L_ * TH_ * 160;
    const size_t outW_n  = (size_t)L_ * E_ * 160;
    const size_t ffn1W_n = (size_t)L_ * FF_ * 160;
    const size_t ffn2W_n = (size_t)L_ * E_ * 576;
    const size_t wbytes  = (qkvW_n + outW_n + ffn1W_n + ffn2W_n) * 2;

    const size_t persist = (size_t)B_ * 4 * (E_ + E_ + TH_ + H_) + wbytes;

    // per-chunk bytes/row: xbfA+xbfB (2*288) + xresA+xresB (2*576) + qf (864) + ob (288)
    int nc = 16;
    for (int c = 1; c <= 16; c <<= 1) {
        size_t rows = (size_t)(B_ / c) * T_;
        size_t need = persist + rows * 2880;
        if (need <= ws_size) { nc = c; break; }
    }
    const int BC = B_ / nc;
    const int CR = BC * T_;

    char* wsp = (char*)d_ws;
    u16*   xbfA  = (u16*)wsp;   wsp += (size_t)CR * E_ * 2;
    u16*   xbfB  = (u16*)wsp;   wsp += (size_t)CR * E_ * 2;
    float* xresA = (float*)wsp; wsp += (size_t)CR * E_ * 4;
    float* xresB = (float*)wsp; wsp += (size_t)CR * E_ * 4;
    u16*   qf    = (u16*)wsp;   wsp += (size_t)CR * TH_ * 2;
    u16*   ob    = (u16*)wsp;   wsp += (size_t)CR * E_ * 2;
    float* ctxm  = (float*)wsp; wsp += (size_t)B_ * E_ * 4;
    float* ctx   = (float*)wsp; wsp += (size_t)B_ * E_ * 4;
    float* gctx  = (float*)wsp; wsp += (size_t)B_ * TH_ * 4;
    float* h     = (float*)wsp; wsp += (size_t)B_ * H_ * 4;
    u16* qkvWb   = (u16*)wsp;   wsp += qkvW_n * 2;
    u16* outWb   = (u16*)wsp;   wsp += outW_n * 2;
    u16* ffn1Wb  = (u16*)wsp;   wsp += ffn1W_n * 2;
    u16* ffn2Wb  = (u16*)wsp;   wsp += ffn2W_n * 2;

    wconv_kernel<<<(int)((qkvW_n + 255) / 256), 256, 0, stream>>>(qkv_w, qkvWb, L_ * TH_, 144, 160);
    wconv_kernel<<<(int)((outW_n + 255) / 256), 256, 0, stream>>>(out_w, outWb, L_ * E_, 144, 160);
    wconv_kernel<<<(int)((ffn1W_n + 255) / 256), 256, 0, stream>>>(ffn1_w, ffn1Wb, L_ * FF_, 144, 160);
    wconv_kernel<<<(int)((ffn2W_n + 255) / 256), 256, 0, stream>>>(ffn2_w, ffn2Wb, L_ * E_, 576, 576);

    auto grid = [](int M, int N) { return dim3((N + 63) / 64, M / 64); };

    for (int c = 0; c < nc; c++) {
        const int b0 = c * BC;
        cast_bf_kernel<<<(CR * 72 + 255) / 256, 256, 0, stream>>>(
            seed + (size_t)b0 * T_ * E_, xbfA, CR * 72);
        const float* resIn = seed + (size_t)b0 * T_ * E_;
        for (int l = 0; l < L_; l++) {
            gemm_mfma<u16><<<dim3(3, CR / 64), 192, 0, stream>>>(
                xbfA, qkvWb + (size_t)l * TH_ * 160, qkv_b + (size_t)l * TH_,
                qf, CR, TH_);
            attn_kernel<<<BC * NH_, 256, 0, stream>>>(qf, ob);
            outln_kernel<<<CR / 64, 192, 0, stream>>>(
                ob, outWb + (size_t)l * E_ * 160, out_b + (size_t)l * E_, resIn,
                ln1_w + (size_t)l * E_, ln1_b + (size_t)l * E_, xbfB, xresB);
            ffn_kernel<<<CR / 64, 192, 0, stream>>>(
                xbfB, ffn1Wb + (size_t)l * FF_ * 160, ffn1_b + (size_t)l * FF_,
                ffn2Wb + (size_t)l * E_ * 576, ffn2_b + (size_t)l * E_, xresB,
                ln2_w + (size_t)l * E_, ln2_b + (size_t)l * E_, xbfA, xresA);
            resIn = xresA;
        }
        mean_kernel<<<(BC * E_ + 255) / 256, 256, 0, stream>>>(xresA, ctxm + (size_t)b0 * E_, BC);
    }

    gemm_kernel<float, float, true, false, false><<<grid(B_, E_), 256, 0, stream>>>(
        ctxm, proj_w, E_, proj_b, nullptr, ctx, B_, E_, E_);
    gemm_kernel<float, float, true, false, false><<<grid(B_, TH_), 256, 0, stream>>>(
        ctx, w_ih + E_, GIN_, b_ih, nullptr, gctx, B_, TH_, E_);
    zero_kernel<<<(B_ * H_ + 255) / 256, 256, 0, stream>>>(h, B_ * H_);

    float* out = (float*)d_out;
    for (int s = 0; s < FUT_; s++) {
        const float* inp = s ? (const float*)(out + (size_t)(s - 1) * E_)
                             : seed + (size_t)(T_ - 1) * E_;
        int istr = s ? FUT_ * E_ : T_ * E_;
        gru_step_kernel<<<B_ / 4, 256, 0, stream>>>(
            inp, istr, gctx, h, w_ih, w_hh, b_hh, spl_w, spl_b,
            out + (size_t)s * E_);
    }
}

// Round 6
// 5791.768 us; speedup vs baseline: 2.4439x; 1.0379x over previous
//
#include <hip/hip_runtime.h>

#define B_   2048
#define T_   120
#define E_   144
#define L_   4
#define NH_  8
#define HD_  18
#define FF_  576
#define H_   144
#define GIN_ 288
#define TH_  432   // 3*E = 3*H
#define FUT_ 24
#define BT_  (B_*T_)

typedef unsigned short u16;
typedef unsigned int   u32;

typedef __attribute__((ext_vector_type(8))) short short8v;  // 8 bf16 (4 VGPRs)
typedef __attribute__((ext_vector_type(4))) float f32x4;

__device__ __forceinline__ float bf2f(u16 u) {
    u32 x = ((u32)u) << 16;
    return __uint_as_float(x);
}
__device__ __forceinline__ u16 f2bf(float f) {
    u32 x = __float_as_uint(f);
    u32 r = (x + 0x7fffu + ((x >> 16) & 1u)) >> 16;
    return (u16)r;
}

struct F4 { float x, y, z, w; };

__device__ __forceinline__ F4 load4(const float* p) {
    float4 v = *(const float4*)p;
    return {v.x, v.y, v.z, v.w};
}
__device__ __forceinline__ void store1(float* p, float v) { *p = v; }
__device__ __forceinline__ void store1(u16* p, float v)   { *p = f2bf(v); }

// ---------------- weight convert + K-pad to bf16 --------------------------------
__global__ void wconv_kernel(const float* __restrict__ src, u16* __restrict__ dst,
                             int rows, int K, int KP)
{
    int i = blockIdx.x * 256 + threadIdx.x;
    if (i >= rows * KP) return;
    int r = i / KP, k = i - r * KP;
    dst[i] = (k < K) ? f2bf(src[(size_t)r * K + k]) : (u16)0;
}

// ---------------- f32 -> bf16 cast (paired) -------------------------------------
__global__ void cast_bf_kernel(const float* __restrict__ src, u16* __restrict__ dst,
                               int n2)
{
    int i = blockIdx.x * 256 + threadIdx.x;
    if (i >= n2) return;
    float2 t = ((const float2*)src)[i];
    ((u32*)dst)[i] = ((u32)f2bf(t.y) << 16) | (u32)f2bf(t.x);
}

// ---------------- MFMA GEMM: C[M,N] = A[M,K] @ Wb[N,KP]^T (+bias) ---------------
// 192 threads = 3 waves. Block tile 64 x 144. Used for qkv projection (N=432).
template<typename OT>
__global__ __launch_bounds__(192) void gemm_mfma(
    const u16* __restrict__ A, const u16* __restrict__ Wb,
    const float* __restrict__ bias, OT* __restrict__ C, int M, int N)
{
    constexpr int RS32 = 84;
    __shared__ u32 lds[64 * RS32];

    const int tid = threadIdx.x;
    const int w   = tid >> 6;
    const int l   = tid & 63;
    const int lg  = l >> 4;
    const int li  = l & 15;
    const int bm  = blockIdx.y * 64;
    const int n0w = blockIdx.x * 144 + w * 48;

    f32x4 acc[4][3];
#pragma unroll
    for (int rt = 0; rt < 4; rt++)
#pragma unroll
        for (int ct = 0; ct < 3; ct++) acc[rt][ct] = {0.f, 0.f, 0.f, 0.f};

    {
        const u32* __restrict__ a32 = (const u32*)A;
        int row = tid / 80, kk = tid - row * 80;
        for (int i = tid; i < 64 * 80; i += 192) {
            u32 v = (kk < 72) ? a32[(size_t)(bm + row) * 72 + kk] : 0u;
            lds[row * RS32 + kk] = v;
            kk += 32; row += 2; if (kk >= 80) { kk -= 80; row += 1; }
        }
    }
    __syncthreads();

    const u16* lds16 = (const u16*)lds;
#pragma unroll
    for (int s = 0; s < 5; ++s) {
        short8v bf[3];
#pragma unroll
        for (int ct = 0; ct < 3; ++ct) {
            int n = n0w + ct * 16 + li;
            bf[ct] = *(const short8v*)(Wb + (size_t)n * 160 + s * 32 + lg * 8);
        }
        short8v af[4];
#pragma unroll
        for (int rt = 0; rt < 4; ++rt)
            af[rt] = *(const short8v*)(lds16 + (rt * 16 + li) * (2 * RS32) + s * 32 + lg * 8);
#pragma unroll
        for (int rt = 0; rt < 4; ++rt)
#pragma unroll
            for (int ct = 0; ct < 3; ++ct)
                acc[rt][ct] = __builtin_amdgcn_mfma_f32_16x16x32_bf16(
                    af[rt], bf[ct], acc[rt][ct], 0, 0, 0);
    }

#pragma unroll
    for (int ct = 0; ct < 3; ++ct) {
        int col = n0w + ct * 16 + li;
        float bv = bias[col];
#pragma unroll
        for (int rt = 0; rt < 4; ++rt) {
#pragma unroll
            for (int j = 0; j < 4; ++j) {
                int row = bm + rt * 16 + lg * 4 + j;
                store1(&C[(size_t)row * N + col], acc[rt][ct][j] + bv);
            }
        }
    }
}

// ======== fused: out-proj + bias + res + LN1 + FFN + res + LN2 -> bf16,f32 ======
// 192 thr (3 waves), 64 rows/block. LDS 35.5 KB -> 4 blocks/CU.
__global__ __launch_bounds__(192) void olnffn_kernel(
    const u16* __restrict__ ob, const u16* __restrict__ Wo,
    const float* __restrict__ ob_b, const float* __restrict__ res,
    const float* __restrict__ ln1w, const float* __restrict__ ln1b,
    const u16* __restrict__ W1, const float* __restrict__ b1,
    const u16* __restrict__ W2, const float* __restrict__ b2,
    const float* __restrict__ ln2w, const float* __restrict__ ln2b,
    u16* __restrict__ obf, float* __restrict__ of)
{
    constexpr int RSA = 84;   // A-buffer row stride (u32)
    constexpr int RSF = 52;   // ff 96-col chunk row stride (u32)
    __shared__ u32 Als[64 * RSA];   // 21504 B
    __shared__ u32 Fls[64 * RSF];   // 13312 B
    __shared__ float lnS[3][64], lnQ[3][64];  // 1536 B

    const int tid = threadIdx.x;
    const int w   = tid >> 6;
    const int l   = tid & 63;
    const int lg  = l >> 4;
    const int li  = l & 15;
    const int bm  = blockIdx.x * 64;

    // ---- stage attention-output rows (bf16) into Als, zero k-pad ----
    {
        const u32* __restrict__ a32 = (const u32*)ob;
        int row = tid / 80, kk = tid - row * 80;
        for (int i = tid; i < 64 * 80; i += 192) {
            u32 v = (kk < 72) ? a32[(size_t)(bm + row) * 72 + kk] : 0u;
            Als[row * RSA + kk] = v;
            kk += 32; row += 2; if (kk >= 80) { kk -= 80; row += 1; }
        }
    }
    __syncthreads();

    const u16* als16 = (const u16*)Als;
    u16* als16w = (u16*)Als;
    u16* fls16 = (u16*)Fls;

    // ---- out-proj MFMA ----
    f32x4 acc[4][3];
#pragma unroll
    for (int rt = 0; rt < 4; rt++)
#pragma unroll
        for (int ct = 0; ct < 3; ct++) acc[rt][ct] = {0.f, 0.f, 0.f, 0.f};
#pragma unroll
    for (int s = 0; s < 5; ++s) {
        short8v bf[3];
#pragma unroll
        for (int ct = 0; ct < 3; ++ct) {
            int n = w * 48 + ct * 16 + li;
            bf[ct] = *(const short8v*)(Wo + (size_t)n * 160 + s * 32 + lg * 8);
        }
        short8v af[4];
#pragma unroll
        for (int rt = 0; rt < 4; ++rt)
            af[rt] = *(const short8v*)(als16 + (rt * 16 + li) * (2 * RSA) + s * 32 + lg * 8);
#pragma unroll
        for (int rt = 0; rt < 4; ++rt)
#pragma unroll
            for (int ct = 0; ct < 3; ++ct)
                acc[rt][ct] = __builtin_amdgcn_mfma_f32_16x16x32_bf16(
                    af[rt], bf[ct], acc[rt][ct], 0, 0, 0);
    }

    // ---- + bias + residual ----
    float vv[4][3][4];
#pragma unroll
    for (int ct = 0; ct < 3; ++ct) {
        int col = w * 48 + ct * 16 + li;
        float bv = ob_b[col];
#pragma unroll
        for (int rt = 0; rt < 4; ++rt)
#pragma unroll
            for (int j = 0; j < 4; ++j) {
                int row = bm + rt * 16 + lg * 4 + j;
                vv[rt][ct][j] = acc[rt][ct][j] + bv + res[(size_t)row * E_ + col];
            }
    }
    // ---- LN1 cross-wave reduce ----
#pragma unroll
    for (int rt = 0; rt < 4; ++rt)
#pragma unroll
        for (int j = 0; j < 4; ++j) {
            float s = vv[rt][0][j] + vv[rt][1][j] + vv[rt][2][j];
            float q = vv[rt][0][j] * vv[rt][0][j] + vv[rt][1][j] * vv[rt][1][j]
                    + vv[rt][2][j] * vv[rt][2][j];
#pragma unroll
            for (int off = 1; off < 16; off <<= 1) {
                s += __shfl_xor(s, off);
                q += __shfl_xor(q, off);
            }
            if (li == 0) {
                lnS[w][rt * 16 + lg * 4 + j] = s;
                lnQ[w][rt * 16 + lg * 4 + j] = q;
            }
        }
    __syncthreads();   // also guarantees all Als reads (out-proj) retired
    // ---- LN1 apply: keep f32 in vv (= FFN residual), write bf16 into Als ----
#pragma unroll
    for (int rt = 0; rt < 4; ++rt)
#pragma unroll
        for (int j = 0; j < 4; ++j) {
            int r = rt * 16 + lg * 4 + j;
            float mean = (lnS[0][r] + lnS[1][r] + lnS[2][r]) * (1.f / 144.f);
            float var  = (lnQ[0][r] + lnQ[1][r] + lnQ[2][r]) * (1.f / 144.f) - mean * mean;
            float rstd = rsqrtf(var + 1e-5f);
#pragma unroll
            for (int ct = 0; ct < 3; ++ct) {
                int col = w * 48 + ct * 16 + li;
                float o = (vv[rt][ct][j] - mean) * rstd * ln1w[col] + ln1b[col];
                vv[rt][ct][j] = o;                       // res2, f32
                als16w[r * (2 * RSA) + col] = f2bf(o);   // ffn1 A (pads stay 0)
            }
        }
    __syncthreads();

    // ---- FFN: 6 chunks of 96 ff-cols ----
    f32x4 acc2[4][3];
#pragma unroll
    for (int rt = 0; rt < 4; rt++)
#pragma unroll
        for (int ct = 0; ct < 3; ct++) acc2[rt][ct] = {0.f, 0.f, 0.f, 0.f};

    for (int c = 0; c < 6; ++c) {
        f32x4 acc1[4][2];
#pragma unroll
        for (int rt = 0; rt < 4; rt++)
#pragma unroll
            for (int ct = 0; ct < 2; ct++) acc1[rt][ct] = {0.f, 0.f, 0.f, 0.f};
#pragma unroll
        for (int s = 0; s < 5; ++s) {
            short8v bf[2];
#pragma unroll
            for (int ct = 0; ct < 2; ++ct) {
                int n1 = c * 96 + w * 32 + ct * 16 + li;
                bf[ct] = *(const short8v*)(W1 + (size_t)n1 * 160 + s * 32 + lg * 8);
            }
            short8v af[4];
#pragma unroll
            for (int rt = 0; rt < 4; ++rt)
                af[rt] = *(const short8v*)(als16 + (rt * 16 + li) * (2 * RSA) + s * 32 + lg * 8);
#pragma unroll
            for (int rt = 0; rt < 4; ++rt)
#pragma unroll
                for (int ct = 0; ct < 2; ++ct)
                    acc1[rt][ct] = __builtin_amdgcn_mfma_f32_16x16x32_bf16(
                        af[rt], bf[ct], acc1[rt][ct], 0, 0, 0);
        }
        __syncthreads();   // prev-chunk ffn2 reads of Fls complete
#pragma unroll
        for (int ct = 0; ct < 2; ++ct) {
            int colc = w * 32 + ct * 16 + li;
            float bv = b1[c * 96 + colc];
#pragma unroll
            for (int rt = 0; rt < 4; ++rt)
#pragma unroll
                for (int j = 0; j < 4; ++j) {
                    int row = rt * 16 + lg * 4 + j;
                    float v = fmaxf(acc1[rt][ct][j] + bv, 0.f);
                    fls16[row * (2 * RSF) + colc] = f2bf(v);
                }
        }
        __syncthreads();
#pragma unroll
        for (int s2 = 0; s2 < 3; ++s2) {
            short8v wf[3];
#pragma unroll
            for (int ct = 0; ct < 3; ++ct) {
                int n2 = w * 48 + ct * 16 + li;
                wf[ct] = *(const short8v*)(W2 + (size_t)n2 * 576 + c * 96 + s2 * 32 + lg * 8);
            }
            short8v pf[4];
#pragma unroll
            for (int rt = 0; rt < 4; ++rt)
                pf[rt] = *(const short8v*)(fls16 + (rt * 16 + li) * (2 * RSF) + s2 * 32 + lg * 8);
#pragma unroll
            for (int rt = 0; rt < 4; ++rt)
#pragma unroll
                for (int ct = 0; ct < 3; ++ct)
                    acc2[rt][ct] = __builtin_amdgcn_mfma_f32_16x16x32_bf16(
                        pf[rt], wf[ct], acc2[rt][ct], 0, 0, 0);
        }
    }

    // ---- epilogue: + b2 + res2(regs) -> LN2 -> write bf16 + f32 ----
    float v2[4][3][4];
#pragma unroll
    for (int ct = 0; ct < 3; ++ct) {
        int col = w * 48 + ct * 16 + li;
        float bv = b2[col];
#pragma unroll
        for (int rt = 0; rt < 4; ++rt)
#pragma unroll
            for (int j = 0; j < 4; ++j)
                v2[rt][ct][j] = acc2[rt][ct][j] + bv + vv[rt][ct][j];
    }
#pragma unroll
    for (int rt = 0; rt < 4; ++rt)
#pragma unroll
        for (int j = 0; j < 4; ++j) {
            float s = v2[rt][0][j] + v2[rt][1][j] + v2[rt][2][j];
            float q = v2[rt][0][j] * v2[rt][0][j] + v2[rt][1][j] * v2[rt][1][j]
                    + v2[rt][2][j] * v2[rt][2][j];
#pragma unroll
            for (int off = 1; off < 16; off <<= 1) {
                s += __shfl_xor(s, off);
                q += __shfl_xor(q, off);
            }
            if (li == 0) {
                lnS[w][rt * 16 + lg * 4 + j] = s;
                lnQ[w][rt * 16 + lg * 4 + j] = q;
            }
        }
    __syncthreads();
#pragma unroll
    for (int rt = 0; rt < 4; ++rt)
#pragma unroll
        for (int j = 0; j < 4; ++j) {
            int r = rt * 16 + lg * 4 + j;
            float mean = (lnS[0][r] + lnS[1][r] + lnS[2][r]) * (1.f / 144.f);
            float var  = (lnQ[0][r] + lnQ[1][r] + lnQ[2][r]) * (1.f / 144.f) - mean * mean;
            float rstd = rsqrtf(var + 1e-5f);
            int row = bm + r;
#pragma unroll
            for (int ct = 0; ct < 3; ++ct) {
                int col = w * 48 + ct * 16 + li;
                float o = (v2[rt][ct][j] - mean) * rstd * ln2w[col] + ln2b[col];
                obf[(size_t)row * E_ + col] = f2bf(o);
                of[(size_t)row * E_ + col]  = o;
            }
        }
}

// ---------------- f32 GEMM (small, ctx path): C = A @ W^T + bias ----------------
template<typename AT, typename OT, bool BIAS, bool RELU, bool RES>
__global__ __launch_bounds__(256) void gemm_kernel(
    const AT* __restrict__ A, const float* __restrict__ W, int ldw,
    const float* __restrict__ bias, const float* __restrict__ res,
    OT* __restrict__ C, int M, int N, int K)
{
    constexpr int BM = 64, BN = 64, BK = 16;
    __shared__ float As[BK][BM + 4];
    __shared__ float Ws[BK][BN + 4];
    const int tid = threadIdx.x;
    const int bm = blockIdx.y * BM;
    const int bn = blockIdx.x * BN;
    const int tx = tid & 15, ty = tid >> 4;
    const int lr = tid >> 2;
    const int lc = (tid & 3) << 2;

    float acc[4][4];
#pragma unroll
    for (int i = 0; i < 4; i++)
#pragma unroll
        for (int j = 0; j < 4; j++) acc[i][j] = 0.f;

    for (int k0 = 0; k0 < K; k0 += BK) {
        F4 av = load4(A + (size_t)(bm + lr) * K + k0 + lc);
        As[lc + 0][lr] = av.x; As[lc + 1][lr] = av.y;
        As[lc + 2][lr] = av.z; As[lc + 3][lr] = av.w;
        int n = bn + lr;
        F4 wv = {0.f, 0.f, 0.f, 0.f};
        if (n < N) {
            float4 t = *(const float4*)(W + (size_t)n * ldw + k0 + lc);
            wv = {t.x, t.y, t.z, t.w};
        }
        Ws[lc + 0][lr] = wv.x; Ws[lc + 1][lr] = wv.y;
        Ws[lc + 2][lr] = wv.z; Ws[lc + 3][lr] = wv.w;
        __syncthreads();
#pragma unroll
        for (int kk = 0; kk < BK; ++kk) {
            float a[4], wr[4];
#pragma unroll
            for (int i = 0; i < 4; i++) a[i] = As[kk][ty * 4 + i];
#pragma unroll
            for (int j = 0; j < 4; j++) wr[j] = Ws[kk][tx * 4 + j];
#pragma unroll
            for (int i = 0; i < 4; i++)
#pragma unroll
                for (int j = 0; j < 4; j++) acc[i][j] += a[i] * wr[j];
        }
        __syncthreads();
    }
#pragma unroll
    for (int i = 0; i < 4; i++) {
        int m = bm + ty * 4 + i;
#pragma unroll
        for (int j = 0; j < 4; j++) {
            int n = bn + tx * 4 + j;
            if (n < N) {
                float v = acc[i][j];
                if (BIAS) v += bias[n];
                if (RES)  v += res[(size_t)m * N + n];
                if (RELU) v = fmaxf(v, 0.f);
                store1(&C[(size_t)m * N + n], v);
            }
        }
    }
}

// ---------------- MFMA attention: one block (4 waves) per (b, head) -------------
__global__ __launch_bounds__(256) void attn_kernel(const u16* __restrict__ qkv,
                                                   u16* __restrict__ o)
{
    constexpr int QS = 40;
    constexpr int VS = 136;
    __shared__ __align__(16) u16 Qs[128 * QS];
    __shared__ __align__(16) u16 Ks[128 * QS];
    __shared__ __align__(16) u16 Vt[32 * VS];
    __shared__ __align__(16) u16 Ps[4][16 * VS];

    const int bh = blockIdx.x;
    const int b = bh >> 3, h = bh & 7;
    const int tid = threadIdx.x;
    const int w = tid >> 6, l = tid & 63;
    const int lg = l >> 4, li = l & 15;

    {
        u32* z1 = (u32*)Qs;
        for (int i = tid; i < 128 * QS / 2; i += 256) z1[i] = 0;
        u32* z2 = (u32*)Ks;
        for (int i = tid; i < 128 * QS / 2; i += 256) z2[i] = 0;
        u32* z3 = (u32*)Vt;
        for (int i = tid; i < 32 * VS / 2; i += 256) z3[i] = 0;
    }
    __syncthreads();

    const u32* q32 = (const u32*)(qkv + (size_t)b * T_ * TH_);
    for (int idx = tid; idx < 120 * 9; idx += 256) {
        int t = idx / 9, dp = idx - t * 9;
        u32 qv = q32[t * 216 + 9 * h + dp];
        u32 kv = q32[t * 216 + 72 + 9 * h + dp];
        u32 vv = q32[t * 216 + 144 + 9 * h + dp];
        ((u32*)(Qs + t * QS))[dp] = qv;
        ((u32*)(Ks + t * QS))[dp] = kv;
        Vt[(2 * dp) * VS + t]     = (u16)(vv & 0xffffu);
        Vt[(2 * dp + 1) * VS + t] = (u16)(vv >> 16);
    }
    __syncthreads();

    const float scale = 0.23570226039551584f; // 1/sqrt(18)
    u16* pw = &Ps[w][0];

    for (int mt = w * 2; mt < w * 2 + 2; ++mt) {
        short8v qf = *(const short8v*)(Qs + (mt * 16 + li) * QS + lg * 8);
        f32x4 sacc[8];
#pragma unroll
        for (int nt = 0; nt < 8; ++nt) sacc[nt] = {0.f, 0.f, 0.f, 0.f};
#pragma unroll
        for (int nt = 0; nt < 8; ++nt) {
            short8v kf = *(const short8v*)(Ks + (nt * 16 + li) * QS + lg * 8);
            sacc[nt] = __builtin_amdgcn_mfma_f32_16x16x32_bf16(qf, kf, sacc[nt], 0, 0, 0);
        }

        float invl[4];
#pragma unroll
        for (int j = 0; j < 4; ++j) {
            float v[8];
            float m = -1e30f;
#pragma unroll
            for (int nt = 0; nt < 8; ++nt) {
                float s = sacc[nt][j] * scale;
                if (nt == 7 && li >= 8) s = -1e30f;
                v[nt] = s;
                m = fmaxf(m, s);
            }
#pragma unroll
            for (int off = 1; off < 16; off <<= 1)
                m = fmaxf(m, __shfl_xor(m, off));
            float sum = 0.f;
#pragma unroll
            for (int nt = 0; nt < 8; ++nt) {
                float p = __expf(v[nt] - m);
                sum += p;
                pw[(lg * 4 + j) * VS + nt * 16 + li] = f2bf(p);
            }
#pragma unroll
            for (int off = 1; off < 16; off <<= 1)
                sum += __shfl_xor(sum, off);
            invl[j] = 1.f / sum;
        }

        f32x4 oacc[2] = {{0.f,0.f,0.f,0.f},{0.f,0.f,0.f,0.f}};
#pragma unroll
        for (int s = 0; s < 4; ++s) {
            short8v pf = *(const short8v*)(pw + li * VS + s * 32 + lg * 8);
#pragma unroll
            for (int dt = 0; dt < 2; ++dt) {
                short8v vf = *(const short8v*)(Vt + (dt * 16 + li) * VS + s * 32 + lg * 8);
                oacc[dt] = __builtin_amdgcn_mfma_f32_16x16x32_bf16(pf, vf, oacc[dt], 0, 0, 0);
            }
        }

        const int q0 = mt * 16 + lg * 4;
#pragma unroll
        for (int dt = 0; dt < 2; ++dt) {
            int d = dt * 16 + li;
            if (d < HD_) {
#pragma unroll
                for (int j = 0; j < 4; ++j) {
                    int q = q0 + j;
                    if (q < T_)
                        o[((size_t)b * T_ + q) * E_ + h * HD_ + d] =
                            f2bf(oacc[dt][j] * invl[j]);
                }
            }
        }
    }
}

// ---------------- mean over T (one chunk of nb batches) -------------------------
__global__ void mean_kernel(const float* __restrict__ x, float* __restrict__ out,
                            int nb)
{
    int idx = blockIdx.x * blockDim.x + threadIdx.x;
    if (idx >= nb * E_) return;
    int b = idx / E_, e = idx % E_;
    const float* p = x + (size_t)b * T_ * E_ + e;
    float s = 0.f;
    for (int t = 0; t < T_; t++) s += p[(size_t)t * E_];
    out[idx] = s * (1.f / 120.f);
}

__global__ void zero_kernel(float* __restrict__ p, int n)
{
    int i = blockIdx.x * blockDim.x + threadIdx.x;
    if (i < n) p[i] = 0.f;
}

__device__ __forceinline__ float sigmoidf_(float x) {
    return 1.f / (1.f + __expf(-x));
}

// ---------------- one GRU decode step (fused) -----------------------------------
__global__ __launch_bounds__(256) void gru_step_kernel(
    const float* __restrict__ inp, int inp_stride,
    const float* __restrict__ gctx,
    float* __restrict__ h,
    const float* __restrict__ w_ih,
    const float* __restrict__ w_hh,
    const float* __restrict__ b_hh,
    const float* __restrict__ spl_w,
    const float* __restrict__ spl_b,
    float* __restrict__ out)
{
    constexpr int BR = 4;
    __shared__ float xin[BR][E_], hs[BR][H_], hnew[BR][H_];
    __shared__ float gi[BR][TH_], gh[BR][TH_];
    const int b0 = blockIdx.x * BR;
    const int tid = threadIdx.x;

    for (int idx = tid; idx < BR * E_; idx += 256) {
        int r = idx / E_, e = idx % E_;
        xin[r][e] = inp[(size_t)(b0 + r) * inp_stride + e];
        hs[r][e]  = h[(size_t)(b0 + r) * H_ + e];
    }
    __syncthreads();

    for (int o = tid; o < BR * TH_; o += 256) {
        int r = o / TH_, f = o % TH_;
        const float4* wr = (const float4*)(w_ih + (size_t)f * GIN_);
        float s = gctx[(size_t)(b0 + r) * TH_ + f];
        const float4* xr = (const float4*)&xin[r][0];
#pragma unroll 9
        for (int e4 = 0; e4 < 36; e4++) {
            float4 wv = wr[e4], xv = xr[e4];
            s += xv.x * wv.x + xv.y * wv.y + xv.z * wv.z + xv.w * wv.w;
        }
        gi[r][f] = s;
        const float4* wh = (const float4*)(w_hh + (size_t)f * H_);
        float s2 = b_hh[f];
        const float4* hr = (const float4*)&hs[r][0];
#pragma unroll 9
        for (int e4 = 0; e4 < 36; e4++) {
            float4 wv = wh[e4], hv = hr[e4];
            s2 += hv.x * wv.x + hv.y * wv.y + hv.z * wv.z + hv.w * wv.w;
        }
        gh[r][f] = s2;
    }
    __syncthreads();

    for (int o = tid; o < BR * H_; o += 256) {
        int r = o / H_, e = o % H_;
        float rr = sigmoidf_(gi[r][e] + gh[r][e]);
        float z  = sigmoidf_(gi[r][H_ + e] + gh[r][H_ + e]);
        float n  = tanhf(gi[r][2 * H_ + e] + rr * gh[r][2 * H_ + e]);
        float hv = (1.f - z) * n + z * hs[r][e];
        hnew[r][e] = hv;
        h[(size_t)(b0 + r) * H_ + e] = hv;
    }
    __syncthreads();

    for (int o = tid; o < BR * E_; o += 256) {
        int r = o / E_, e = o % E_;
        const float4* wr = (const float4*)(spl_w + (size_t)e * H_);
        const float4* hr = (const float4*)&hnew[r][0];
        float s = spl_b[e];
#pragma unroll 9
        for (int e4 = 0; e4 < 36; e4++) {
            float4 wv = wr[e4], hv = hr[e4];
            s += hv.x * wv.x + hv.y * wv.y + hv.z * wv.z + hv.w * wv.w;
        }
        out[(size_t)(b0 + r) * (FUT_ * E_) + e] = s;
    }
}

// =================================================================================
extern "C" void kernel_launch(void* const* d_in, const int* in_sizes, int n_in,
                              void* d_out, int out_size, void* d_ws, size_t ws_size,
                              hipStream_t stream)
{
    const float* seed   = (const float*)d_in[0];
    const float* qkv_w  = (const float*)d_in[1];
    const float* qkv_b  = (const float*)d_in[2];
    const float* out_w  = (const float*)d_in[3];
    const float* out_b  = (const float*)d_in[4];
    const float* ln1_w  = (const float*)d_in[5];
    const float* ln1_b  = (const float*)d_in[6];
    const float* ffn1_w = (const float*)d_in[7];
    const float* ffn1_b = (const float*)d_in[8];
    const float* ffn2_w = (const float*)d_in[9];
    const float* ffn2_b = (const float*)d_in[10];
    const float* ln2_w  = (const float*)d_in[11];
    const float* ln2_b  = (const float*)d_in[12];
    const float* proj_w = (const float*)d_in[13];
    const float* proj_b = (const float*)d_in[14];
    const float* w_ih   = (const float*)d_in[15];
    const float* w_hh   = (const float*)d_in[16];
    const float* b_ih   = (const float*)d_in[17];
    const float* b_hh   = (const float*)d_in[18];
    const float* spl_w  = (const float*)d_in[19];
    const float* spl_b  = (const float*)d_in[20];

    // bf16 padded weight copies
    const size_t qkvW_n  = (size_t)L_ * TH_ * 160;
    const size_t outW_n  = (size_t)L_ * E_ * 160;
    const size_t ffn1W_n = (size_t)L_ * FF_ * 160;
    const size_t ffn2W_n = (size_t)L_ * E_ * 576;
    const size_t wbytes  = (qkvW_n + outW_n + ffn1W_n + ffn2W_n) * 2;

    const size_t persist = (size_t)B_ * 4 * (E_ + E_ + TH_ + H_) + wbytes;

    // per-chunk bytes/row: xbf(288) + xres(576) + qf(864) + ob(288) = 2016
    int nc = 16;
    for (int c = 1; c <= 16; c <<= 1) {
        size_t rows = (size_t)(B_ / c) * T_;
        size_t need = persist + rows * 2016;
        if (need <= ws_size) { nc = c; break; }
    }
    const int BC = B_ / nc;
    const int CR = BC * T_;

    char* wsp = (char*)d_ws;
    u16*   xbf   = (u16*)wsp;   wsp += (size_t)CR * E_ * 2;
    float* xres  = (float*)wsp; wsp += (size_t)CR * E_ * 4;
    u16*   qf    = (u16*)wsp;   wsp += (size_t)CR * TH_ * 2;
    u16*   ob    = (u16*)wsp;   wsp += (size_t)CR * E_ * 2;
    float* ctxm  = (float*)wsp; wsp += (size_t)B_ * E_ * 4;
    float* ctx   = (float*)wsp; wsp += (size_t)B_ * E_ * 4;
    float* gctx  = (float*)wsp; wsp += (size_t)B_ * TH_ * 4;
    float* h     = (float*)wsp; wsp += (size_t)B_ * H_ * 4;
    u16* qkvWb   = (u16*)wsp;   wsp += qkvW_n * 2;
    u16* outWb   = (u16*)wsp;   wsp += outW_n * 2;
    u16* ffn1Wb  = (u16*)wsp;   wsp += ffn1W_n * 2;
    u16* ffn2Wb  = (u16*)wsp;   wsp += ffn2W_n * 2;

    wconv_kernel<<<(int)((qkvW_n + 255) / 256), 256, 0, stream>>>(qkv_w, qkvWb, L_ * TH_, 144, 160);
    wconv_kernel<<<(int)((outW_n + 255) / 256), 256, 0, stream>>>(out_w, outWb, L_ * E_, 144, 160);
    wconv_kernel<<<(int)((ffn1W_n + 255) / 256), 256, 0, stream>>>(ffn1_w, ffn1Wb, L_ * FF_, 144, 160);
    wconv_kernel<<<(int)((ffn2W_n + 255) / 256), 256, 0, stream>>>(ffn2_w, ffn2Wb, L_ * E_, 576, 576);

    auto grid = [](int M, int N) { return dim3((N + 63) / 64, M / 64); };

    for (int c = 0; c < nc; c++) {
        const int b0 = c * BC;
        cast_bf_kernel<<<(CR * 72 + 255) / 256, 256, 0, stream>>>(
            seed + (size_t)b0 * T_ * E_, xbf, CR * 72);
        const float* resIn = seed + (size_t)b0 * T_ * E_;
        for (int l = 0; l < L_; l++) {
            gemm_mfma<u16><<<dim3(3, CR / 64), 192, 0, stream>>>(
                xbf, qkvWb + (size_t)l * TH_ * 160, qkv_b + (size_t)l * TH_,
                qf, CR, TH_);
            attn_kernel<<<BC * NH_, 256, 0, stream>>>(qf, ob);
            olnffn_kernel<<<CR / 64, 192, 0, stream>>>(
                ob, outWb + (size_t)l * E_ * 160, out_b + (size_t)l * E_, resIn,
                ln1_w + (size_t)l * E_, ln1_b + (size_t)l * E_,
                ffn1Wb + (size_t)l * FF_ * 160, ffn1_b + (size_t)l * FF_,
                ffn2Wb + (size_t)l * E_ * 576, ffn2_b + (size_t)l * E_,
                ln2_w + (size_t)l * E_, ln2_b + (size_t)l * E_, xbf, xres);
            resIn = xres;
        }
        mean_kernel<<<(BC * E_ + 255) / 256, 256, 0, stream>>>(xres, ctxm + (size_t)b0 * E_, BC);
    }

    gemm_kernel<float, float, true, false, false><<<grid(B_, E_), 256, 0, stream>>>(
        ctxm, proj_w, E_, proj_b, nullptr, ctx, B_, E_, E_);
    gemm_kernel<float, float, true, false, false><<<grid(B_, TH_), 256, 0, stream>>>(
        ctx, w_ih + E_, GIN_, b_ih, nullptr, gctx, B_, TH_, E_);
    zero_kernel<<<(B_ * H_ + 255) / 256, 256, 0, stream>>>(h, B_ * H_);

    float* out = (float*)d_out;
    for (int s = 0; s < FUT_; s++) {
        const float* inp = s ? (const float*)(out + (size_t)(s - 1) * E_)
                             : seed + (size_t)(T_ - 1) * E_;
        int istr = s ? FUT_ * E_ : T_ * E_;
        gru_step_kernel<<<B_ / 4, 256, 0, stream>>>(
            inp, istr, gctx, h, w_ih, w_hh, b_hh, spl_w, spl_b,
            out + (size_t)s * E_);
    }
}

// Round 7
// 5663.242 us; speedup vs baseline: 2.4994x; 1.0227x over previous
//
#include <hip/hip_runtime.h>

#define B_   2048
#define T_   120
#define E_   144
#define L_   4
#define NH_  8
#define HD_  18
#define FF_  576
#define H_   144
#define GIN_ 288
#define TH_  432   // 3*E = 3*H
#define FUT_ 24
#define BT_  (B_*T_)

typedef unsigned short u16;
typedef unsigned int   u32;

typedef __attribute__((ext_vector_type(8))) short short8v;  // 8 bf16 (4 VGPRs)
typedef __attribute__((ext_vector_type(4))) float f32x4;

__device__ __forceinline__ float bf2f(u16 u) {
    u32 x = ((u32)u) << 16;
    return __uint_as_float(x);
}
__device__ __forceinline__ u16 f2bf(float f) {
    u32 x = __float_as_uint(f);
    u32 r = (x + 0x7fffu + ((x >> 16) & 1u)) >> 16;
    return (u16)r;
}

struct F4 { float x, y, z, w; };

__device__ __forceinline__ F4 load4(const float* p) {
    float4 v = *(const float4*)p;
    return {v.x, v.y, v.z, v.w};
}
__device__ __forceinline__ void store1(float* p, float v) { *p = v; }
__device__ __forceinline__ void store1(u16* p, float v)   { *p = f2bf(v); }

// ---- async global->LDS, 16B per lane, wave-uniform LDS base ---------------------
__device__ __forceinline__ void gll16(const void* g, void* l) {
    __builtin_amdgcn_global_load_lds(
        (const __attribute__((address_space(1))) u32*)g,
        (__attribute__((address_space(3))) u32*)l, 16, 0, 0);
}

// stage 64 rows x 144 bf16 (contiguous, row stride 288B) into LDS rows of
// stride 168 u16 (=336B = 21 x 16B chunks). Chunk-linear in LDS. Pad chunks
// (col 18..20) duplicate chunk 17 (finite junk x zero weight-pad = 0).
// 192 threads = 3 waves, 7 gll16 per thread, 1344 chunks total.
__device__ __forceinline__ void stage64(const u16* src, u32* lds, int tid) {
    const char* base = (const char*)src;
    char* lbase = (char*)lds;
    const int w = tid >> 6, l = tid & 63;
#pragma unroll
    for (int i = 0; i < 7; ++i) {
        int inst  = w * 7 + i;            // 0..20
        int chunk = inst * 64 + l;        // 0..1343
        int row = chunk / 21;
        int col = chunk - row * 21;
        if (col > 17) col = 17;
        gll16(base + row * 288 + col * 16, lbase + inst * 1024);
    }
}

// ---------------- weight convert + K-pad to bf16 --------------------------------
__global__ void wconv_kernel(const float* __restrict__ src, u16* __restrict__ dst,
                             int rows, int K, int KP)
{
    int i = blockIdx.x * 256 + threadIdx.x;
    if (i >= rows * KP) return;
    int r = i / KP, k = i - r * KP;
    dst[i] = (k < K) ? f2bf(src[(size_t)r * K + k]) : (u16)0;
}

// ---------------- f32 -> bf16 cast (paired) -------------------------------------
__global__ void cast_bf_kernel(const float* __restrict__ src, u16* __restrict__ dst,
                               int n2)
{
    int i = blockIdx.x * 256 + threadIdx.x;
    if (i >= n2) return;
    float2 t = ((const float2*)src)[i];
    ((u32*)dst)[i] = ((u32)f2bf(t.y) << 16) | (u32)f2bf(t.x);
}

// ---------------- MFMA GEMM: C[M,N] = A[M,K] @ Wb[N,160]^T (+bias) --------------
// 192 threads = 3 waves. Block tile 64 x 144. qkv projection (N=432).
template<typename OT>
__global__ __launch_bounds__(192) void gemm_mfma(
    const u16* __restrict__ A, const u16* __restrict__ Wb,
    const float* __restrict__ bias, OT* __restrict__ C, int M, int N)
{
    constexpr int RS32 = 84;
    __shared__ u32 lds[64 * RS32];

    const int tid = threadIdx.x;
    const int w   = tid >> 6;
    const int l   = tid & 63;
    const int lg  = l >> 4;
    const int li  = l & 15;
    const int bm  = blockIdx.y * 64;
    const int n0w = blockIdx.x * 144 + w * 48;

    f32x4 acc[4][3];
#pragma unroll
    for (int rt = 0; rt < 4; rt++)
#pragma unroll
        for (int ct = 0; ct < 3; ct++) acc[rt][ct] = {0.f, 0.f, 0.f, 0.f};

    stage64(A + (size_t)bm * 144, lds, tid);
    __syncthreads();

    const u16* lds16 = (const u16*)lds;
#pragma unroll
    for (int s = 0; s < 5; ++s) {
        short8v bf[3];
#pragma unroll
        for (int ct = 0; ct < 3; ++ct) {
            int n = n0w + ct * 16 + li;
            bf[ct] = *(const short8v*)(Wb + (size_t)n * 160 + s * 32 + lg * 8);
        }
        short8v af[4];
#pragma unroll
        for (int rt = 0; rt < 4; ++rt)
            af[rt] = *(const short8v*)(lds16 + (rt * 16 + li) * (2 * RS32) + s * 32 + lg * 8);
#pragma unroll
        for (int rt = 0; rt < 4; ++rt)
#pragma unroll
            for (int ct = 0; ct < 3; ++ct)
                acc[rt][ct] = __builtin_amdgcn_mfma_f32_16x16x32_bf16(
                    af[rt], bf[ct], acc[rt][ct], 0, 0, 0);
    }

#pragma unroll
    for (int ct = 0; ct < 3; ++ct) {
        int col = n0w + ct * 16 + li;
        float bv = bias[col];
#pragma unroll
        for (int rt = 0; rt < 4; ++rt) {
#pragma unroll
            for (int j = 0; j < 4; ++j) {
                int row = bm + rt * 16 + lg * 4 + j;
                store1(&C[(size_t)row * N + col], acc[rt][ct][j] + bv);
            }
        }
    }
}

// ======== fused: out-proj + bias + res + LN1 + FFN + res + LN2 -> bf16,f32 ======
// 192 thr (3 waves), 64 rows/block. ff in 3 chunks of 192 cols, stride 208 u16.
__global__ __launch_bounds__(192) void olnffn_kernel(
    const u16* __restrict__ ob, const u16* __restrict__ Wo,
    const float* __restrict__ ob_b, const float* __restrict__ res,
    const float* __restrict__ ln1w, const float* __restrict__ ln1b,
    const u16* __restrict__ W1, const float* __restrict__ b1,
    const u16* __restrict__ W2, const float* __restrict__ b2,
    const float* __restrict__ ln2w, const float* __restrict__ ln2b,
    u16* __restrict__ obf, float* __restrict__ of)
{
    constexpr int RSA = 84;    // A-buffer row stride (u32)
    constexpr int RSF = 104;   // ff 192-col chunk row stride (u32) == 8 mod 32
    __shared__ u32 Als[64 * RSA];   // 21504 B
    __shared__ u32 Fls[64 * RSF];   // 26624 B
    __shared__ float lnS[3][64], lnQ[3][64];  // 1536 B

    const int tid = threadIdx.x;
    const int w   = tid >> 6;
    const int l   = tid & 63;
    const int lg  = l >> 4;
    const int li  = l & 15;
    const int bm  = blockIdx.x * 64;

    stage64(ob + (size_t)bm * 144, Als, tid);
    __syncthreads();

    const u16* als16 = (const u16*)Als;
    u16* als16w = (u16*)Als;
    u16* fls16 = (u16*)Fls;

    // ---- out-proj MFMA ----
    f32x4 acc[4][3];
#pragma unroll
    for (int rt = 0; rt < 4; rt++)
#pragma unroll
        for (int ct = 0; ct < 3; ct++) acc[rt][ct] = {0.f, 0.f, 0.f, 0.f};
#pragma unroll
    for (int s = 0; s < 5; ++s) {
        short8v bf[3];
#pragma unroll
        for (int ct = 0; ct < 3; ++ct) {
            int n = w * 48 + ct * 16 + li;
            bf[ct] = *(const short8v*)(Wo + (size_t)n * 160 + s * 32 + lg * 8);
        }
        short8v af[4];
#pragma unroll
        for (int rt = 0; rt < 4; ++rt)
            af[rt] = *(const short8v*)(als16 + (rt * 16 + li) * (2 * RSA) + s * 32 + lg * 8);
#pragma unroll
        for (int rt = 0; rt < 4; ++rt)
#pragma unroll
            for (int ct = 0; ct < 3; ++ct)
                acc[rt][ct] = __builtin_amdgcn_mfma_f32_16x16x32_bf16(
                    af[rt], bf[ct], acc[rt][ct], 0, 0, 0);
    }

    // ---- + bias + residual ----
    float vv[4][3][4];
#pragma unroll
    for (int ct = 0; ct < 3; ++ct) {
        int col = w * 48 + ct * 16 + li;
        float bv = ob_b[col];
#pragma unroll
        for (int rt = 0; rt < 4; ++rt)
#pragma unroll
            for (int j = 0; j < 4; ++j) {
                int row = bm + rt * 16 + lg * 4 + j;
                vv[rt][ct][j] = acc[rt][ct][j] + bv + res[(size_t)row * E_ + col];
            }
    }
    // ---- LN1 cross-wave reduce ----
#pragma unroll
    for (int rt = 0; rt < 4; ++rt)
#pragma unroll
        for (int j = 0; j < 4; ++j) {
            float s = vv[rt][0][j] + vv[rt][1][j] + vv[rt][2][j];
            float q = vv[rt][0][j] * vv[rt][0][j] + vv[rt][1][j] * vv[rt][1][j]
                    + vv[rt][2][j] * vv[rt][2][j];
#pragma unroll
            for (int off = 1; off < 16; off <<= 1) {
                s += __shfl_xor(s, off);
                q += __shfl_xor(q, off);
            }
            if (li == 0) {
                lnS[w][rt * 16 + lg * 4 + j] = s;
                lnQ[w][rt * 16 + lg * 4 + j] = q;
            }
        }
    __syncthreads();   // also guarantees all Als reads (out-proj) retired
    // ---- LN1 apply: keep f32 in vv (= FFN residual), write bf16 into Als ----
#pragma unroll
    for (int rt = 0; rt < 4; ++rt)
#pragma unroll
        for (int j = 0; j < 4; ++j) {
            int r = rt * 16 + lg * 4 + j;
            float mean = (lnS[0][r] + lnS[1][r] + lnS[2][r]) * (1.f / 144.f);
            float var  = (lnQ[0][r] + lnQ[1][r] + lnQ[2][r]) * (1.f / 144.f) - mean * mean;
            float rstd = rsqrtf(var + 1e-5f);
#pragma unroll
            for (int ct = 0; ct < 3; ++ct) {
                int col = w * 48 + ct * 16 + li;
                float o = (vv[rt][ct][j] - mean) * rstd * ln1w[col] + ln1b[col];
                vv[rt][ct][j] = o;                       // res2, f32
                als16w[r * (2 * RSA) + col] = f2bf(o);   // ffn1 A (pads: junk*0)
            }
        }
    __syncthreads();

    // ---- FFN: 3 chunks of 192 ff-cols ----
    f32x4 acc2[4][3];
#pragma unroll
    for (int rt = 0; rt < 4; rt++)
#pragma unroll
        for (int ct = 0; ct < 3; ct++) acc2[rt][ct] = {0.f, 0.f, 0.f, 0.f};

    for (int c = 0; c < 3; ++c) {
        f32x4 acc1[4][4];
#pragma unroll
        for (int rt = 0; rt < 4; rt++)
#pragma unroll
            for (int ct = 0; ct < 4; ct++) acc1[rt][ct] = {0.f, 0.f, 0.f, 0.f};
#pragma unroll
        for (int s = 0; s < 5; ++s) {
            short8v bf[4];
#pragma unroll
            for (int ct = 0; ct < 4; ++ct) {
                int n1 = c * 192 + w * 64 + ct * 16 + li;
                bf[ct] = *(const short8v*)(W1 + (size_t)n1 * 160 + s * 32 + lg * 8);
            }
            short8v af[4];
#pragma unroll
            for (int rt = 0; rt < 4; ++rt)
                af[rt] = *(const short8v*)(als16 + (rt * 16 + li) * (2 * RSA) + s * 32 + lg * 8);
#pragma unroll
            for (int rt = 0; rt < 4; ++rt)
#pragma unroll
                for (int ct = 0; ct < 4; ++ct)
                    acc1[rt][ct] = __builtin_amdgcn_mfma_f32_16x16x32_bf16(
                        af[rt], bf[ct], acc1[rt][ct], 0, 0, 0);
        }
        __syncthreads();   // prev-chunk ffn2 reads of Fls complete
#pragma unroll
        for (int ct = 0; ct < 4; ++ct) {
            int colc = w * 64 + ct * 16 + li;
            float bv = b1[c * 192 + colc];
#pragma unroll
            for (int rt = 0; rt < 4; ++rt)
#pragma unroll
                for (int j = 0; j < 4; ++j) {
                    int row = rt * 16 + lg * 4 + j;
                    float v = fmaxf(acc1[rt][ct][j] + bv, 0.f);
                    fls16[row * (2 * RSF) + colc] = f2bf(v);
                }
        }
        __syncthreads();
#pragma unroll
        for (int s2 = 0; s2 < 6; ++s2) {
            short8v wf[3];
#pragma unroll
            for (int ct = 0; ct < 3; ++ct) {
                int n2 = w * 48 + ct * 16 + li;
                wf[ct] = *(const short8v*)(W2 + (size_t)n2 * 576 + c * 192 + s2 * 32 + lg * 8);
            }
            short8v pf[4];
#pragma unroll
            for (int rt = 0; rt < 4; ++rt)
                pf[rt] = *(const short8v*)(fls16 + (rt * 16 + li) * (2 * RSF) + s2 * 32 + lg * 8);
#pragma unroll
            for (int rt = 0; rt < 4; ++rt)
#pragma unroll
                for (int ct = 0; ct < 3; ++ct)
                    acc2[rt][ct] = __builtin_amdgcn_mfma_f32_16x16x32_bf16(
                        pf[rt], wf[ct], acc2[rt][ct], 0, 0, 0);
        }
    }

    // ---- epilogue: + b2 + res2(regs) -> LN2 -> write bf16 + f32 ----
    float v2[4][3][4];
#pragma unroll
    for (int ct = 0; ct < 3; ++ct) {
        int col = w * 48 + ct * 16 + li;
        float bv = b2[col];
#pragma unroll
        for (int rt = 0; rt < 4; ++rt)
#pragma unroll
            for (int j = 0; j < 4; ++j)
                v2[rt][ct][j] = acc2[rt][ct][j] + bv + vv[rt][ct][j];
    }
#pragma unroll
    for (int rt = 0; rt < 4; ++rt)
#pragma unroll
        for (int j = 0; j < 4; ++j) {
            float s = v2[rt][0][j] + v2[rt][1][j] + v2[rt][2][j];
            float q = v2[rt][0][j] * v2[rt][0][j] + v2[rt][1][j] * v2[rt][1][j]
                    + v2[rt][2][j] * v2[rt][2][j];
#pragma unroll
            for (int off = 1; off < 16; off <<= 1) {
                s += __shfl_xor(s, off);
                q += __shfl_xor(q, off);
            }
            if (li == 0) {
                lnS[w][rt * 16 + lg * 4 + j] = s;
                lnQ[w][rt * 16 + lg * 4 + j] = q;
            }
        }
    __syncthreads();
#pragma unroll
    for (int rt = 0; rt < 4; ++rt)
#pragma unroll
        for (int j = 0; j < 4; ++j) {
            int r = rt * 16 + lg * 4 + j;
            float mean = (lnS[0][r] + lnS[1][r] + lnS[2][r]) * (1.f / 144.f);
            float var  = (lnQ[0][r] + lnQ[1][r] + lnQ[2][r]) * (1.f / 144.f) - mean * mean;
            float rstd = rsqrtf(var + 1e-5f);
            int row = bm + r;
#pragma unroll
            for (int ct = 0; ct < 3; ++ct) {
                int col = w * 48 + ct * 16 + li;
                float o = (v2[rt][ct][j] - mean) * rstd * ln2w[col] + ln2b[col];
                obf[(size_t)row * E_ + col] = f2bf(o);
                of[(size_t)row * E_ + col]  = o;
            }
        }
}

// ---------------- f32 GEMM (small, ctx path): C = A @ W^T + bias ----------------
template<typename AT, typename OT, bool BIAS, bool RELU, bool RES>
__global__ __launch_bounds__(256) void gemm_kernel(
    const AT* __restrict__ A, const float* __restrict__ W, int ldw,
    const float* __restrict__ bias, const float* __restrict__ res,
    OT* __restrict__ C, int M, int N, int K)
{
    constexpr int BM = 64, BN = 64, BK = 16;
    __shared__ float As[BK][BM + 4];
    __shared__ float Ws[BK][BN + 4];
    const int tid = threadIdx.x;
    const int bm = blockIdx.y * BM;
    const int bn = blockIdx.x * BN;
    const int tx = tid & 15, ty = tid >> 4;
    const int lr = tid >> 2;
    const int lc = (tid & 3) << 2;

    float acc[4][4];
#pragma unroll
    for (int i = 0; i < 4; i++)
#pragma unroll
        for (int j = 0; j < 4; j++) acc[i][j] = 0.f;

    for (int k0 = 0; k0 < K; k0 += BK) {
        F4 av = load4(A + (size_t)(bm + lr) * K + k0 + lc);
        As[lc + 0][lr] = av.x; As[lc + 1][lr] = av.y;
        As[lc + 2][lr] = av.z; As[lc + 3][lr] = av.w;
        int n = bn + lr;
        F4 wv = {0.f, 0.f, 0.f, 0.f};
        if (n < N) {
            float4 t = *(const float4*)(W + (size_t)n * ldw + k0 + lc);
            wv = {t.x, t.y, t.z, t.w};
        }
        Ws[lc + 0][lr] = wv.x; Ws[lc + 1][lr] = wv.y;
        Ws[lc + 2][lr] = wv.z; Ws[lc + 3][lr] = wv.w;
        __syncthreads();
#pragma unroll
        for (int kk = 0; kk < BK; ++kk) {
            float a[4], wr[4];
#pragma unroll
            for (int i = 0; i < 4; i++) a[i] = As[kk][ty * 4 + i];
#pragma unroll
            for (int j = 0; j < 4; j++) wr[j] = Ws[kk][tx * 4 + j];
#pragma unroll
            for (int i = 0; i < 4; i++)
#pragma unroll
                for (int j = 0; j < 4; j++) acc[i][j] += a[i] * wr[j];
        }
        __syncthreads();
    }
#pragma unroll
    for (int i = 0; i < 4; i++) {
        int m = bm + ty * 4 + i;
#pragma unroll
        for (int j = 0; j < 4; j++) {
            int n = bn + tx * 4 + j;
            if (n < N) {
                float v = acc[i][j];
                if (BIAS) v += bias[n];
                if (RES)  v += res[(size_t)m * N + n];
                if (RELU) v = fmaxf(v, 0.f);
                store1(&C[(size_t)m * N + n], v);
            }
        }
    }
}

// ---------------- MFMA attention: one block (4 waves) per (b, head) -------------
__global__ __launch_bounds__(256) void attn_kernel(const u16* __restrict__ qkv,
                                                   u16* __restrict__ o)
{
    constexpr int QS = 40;
    constexpr int VS = 136;
    __shared__ __align__(16) u16 Qs[128 * QS];
    __shared__ __align__(16) u16 Ks[128 * QS];
    __shared__ __align__(16) u16 Vt[32 * VS];
    __shared__ __align__(16) u16 Ps[4][16 * VS];

    const int bh = blockIdx.x;
    const int b = bh >> 3, h = bh & 7;
    const int tid = threadIdx.x;
    const int w = tid >> 6, l = tid & 63;
    const int lg = l >> 4, li = l & 15;

    {
        u32* z1 = (u32*)Qs;
        for (int i = tid; i < 128 * QS / 2; i += 256) z1[i] = 0;
        u32* z2 = (u32*)Ks;
        for (int i = tid; i < 128 * QS / 2; i += 256) z2[i] = 0;
        u32* z3 = (u32*)Vt;
        for (int i = tid; i < 32 * VS / 2; i += 256) z3[i] = 0;
    }
    __syncthreads();

    const u32* q32 = (const u32*)(qkv + (size_t)b * T_ * TH_);
    for (int idx = tid; idx < 120 * 9; idx += 256) {
        int t = idx / 9, dp = idx - t * 9;
        u32 qv = q32[t * 216 + 9 * h + dp];
        u32 kv = q32[t * 216 + 72 + 9 * h + dp];
        u32 vv = q32[t * 216 + 144 + 9 * h + dp];
        ((u32*)(Qs + t * QS))[dp] = qv;
        ((u32*)(Ks + t * QS))[dp] = kv;
        Vt[(2 * dp) * VS + t]     = (u16)(vv & 0xffffu);
        Vt[(2 * dp + 1) * VS + t] = (u16)(vv >> 16);
    }
    __syncthreads();

    const float scale = 0.23570226039551584f; // 1/sqrt(18)
    u16* pw = &Ps[w][0];

    for (int mt = w * 2; mt < w * 2 + 2; ++mt) {
        short8v qf = *(const short8v*)(Qs + (mt * 16 + li) * QS + lg * 8);
        f32x4 sacc[8];
#pragma unroll
        for (int nt = 0; nt < 8; ++nt) sacc[nt] = {0.f, 0.f, 0.f, 0.f};
#pragma unroll
        for (int nt = 0; nt < 8; ++nt) {
            short8v kf = *(const short8v*)(Ks + (nt * 16 + li) * QS + lg * 8);
            sacc[nt] = __builtin_amdgcn_mfma_f32_16x16x32_bf16(qf, kf, sacc[nt], 0, 0, 0);
        }

        float invl[4];
#pragma unroll
        for (int j = 0; j < 4; ++j) {
            float v[8];
            float m = -1e30f;
#pragma unroll
            for (int nt = 0; nt < 8; ++nt) {
                float s = sacc[nt][j] * scale;
                if (nt == 7 && li >= 8) s = -1e30f;
                v[nt] = s;
                m = fmaxf(m, s);
            }
#pragma unroll
            for (int off = 1; off < 16; off <<= 1)
                m = fmaxf(m, __shfl_xor(m, off));
            float sum = 0.f;
#pragma unroll
            for (int nt = 0; nt < 8; ++nt) {
                float p = __expf(v[nt] - m);
                sum += p;
                pw[(lg * 4 + j) * VS + nt * 16 + li] = f2bf(p);
            }
#pragma unroll
            for (int off = 1; off < 16; off <<= 1)
                sum += __shfl_xor(sum, off);
            invl[j] = 1.f / sum;
        }

        f32x4 oacc[2] = {{0.f,0.f,0.f,0.f},{0.f,0.f,0.f,0.f}};
#pragma unroll
        for (int s = 0; s < 4; ++s) {
            short8v pf = *(const short8v*)(pw + li * VS + s * 32 + lg * 8);
#pragma unroll
            for (int dt = 0; dt < 2; ++dt) {
                short8v vf = *(const short8v*)(Vt + (dt * 16 + li) * VS + s * 32 + lg * 8);
                oacc[dt] = __builtin_amdgcn_mfma_f32_16x16x32_bf16(pf, vf, oacc[dt], 0, 0, 0);
            }
        }

        const int q0 = mt * 16 + lg * 4;
#pragma unroll
        for (int dt = 0; dt < 2; ++dt) {
            int d = dt * 16 + li;
            if (d < HD_) {
#pragma unroll
                for (int j = 0; j < 4; ++j) {
                    int q = q0 + j;
                    if (q < T_)
                        o[((size_t)b * T_ + q) * E_ + h * HD_ + d] =
                            f2bf(oacc[dt][j] * invl[j]);
                }
            }
        }
    }
}

// ---------------- mean over T (one chunk of nb batches) -------------------------
__global__ void mean_kernel(const float* __restrict__ x, float* __restrict__ out,
                            int nb)
{
    int idx = blockIdx.x * blockDim.x + threadIdx.x;
    if (idx >= nb * E_) return;
    int b = idx / E_, e = idx % E_;
    const float* p = x + (size_t)b * T_ * E_ + e;
    float s = 0.f;
    for (int t = 0; t < T_; t++) s += p[(size_t)t * E_];
    out[idx] = s * (1.f / 120.f);
}

__global__ void zero_kernel(float* __restrict__ p, int n)
{
    int i = blockIdx.x * blockDim.x + threadIdx.x;
    if (i < n) p[i] = 0.f;
}

__device__ __forceinline__ float sigmoidf_(float x) {
    return 1.f / (1.f + __expf(-x));
}

// ---------------- one GRU decode step (fused) -----------------------------------
__global__ __launch_bounds__(256) void gru_step_kernel(
    const float* __restrict__ inp, int inp_stride,
    const float* __restrict__ gctx,
    float* __restrict__ h,
    const float* __restrict__ w_ih,
    const float* __restrict__ w_hh,
    const float* __restrict__ b_hh,
    const float* __restrict__ spl_w,
    const float* __restrict__ spl_b,
    float* __restrict__ out)
{
    constexpr int BR = 4;
    __shared__ float xin[BR][E_], hs[BR][H_], hnew[BR][H_];
    __shared__ float gi[BR][TH_], gh[BR][TH_];
    const int b0 = blockIdx.x * BR;
    const int tid = threadIdx.x;

    for (int idx = tid; idx < BR * E_; idx += 256) {
        int r = idx / E_, e = idx % E_;
        xin[r][e] = inp[(size_t)(b0 + r) * inp_stride + e];
        hs[r][e]  = h[(size_t)(b0 + r) * H_ + e];
    }
    __syncthreads();

    for (int o = tid; o < BR * TH_; o += 256) {
        int r = o / TH_, f = o % TH_;
        const float4* wr = (const float4*)(w_ih + (size_t)f * GIN_);
        float s = gctx[(size_t)(b0 + r) * TH_ + f];
        const float4* xr = (const float4*)&xin[r][0];
#pragma unroll 9
        for (int e4 = 0; e4 < 36; e4++) {
            float4 wv = wr[e4], xv = xr[e4];
            s += xv.x * wv.x + xv.y * wv.y + xv.z * wv.z + xv.w * wv.w;
        }
        gi[r][f] = s;
        const float4* wh = (const float4*)(w_hh + (size_t)f * H_);
        float s2 = b_hh[f];
        const float4* hr = (const float4*)&hs[r][0];
#pragma unroll 9
        for (int e4 = 0; e4 < 36; e4++) {
            float4 wv = wh[e4], hv = hr[e4];
            s2 += hv.x * wv.x + hv.y * wv.y + hv.z * wv.z + hv.w * wv.w;
        }
        gh[r][f] = s2;
    }
    __syncthreads();

    for (int o = tid; o < BR * H_; o += 256) {
        int r = o / H_, e = o % H_;
        float rr = sigmoidf_(gi[r][e] + gh[r][e]);
        float z  = sigmoidf_(gi[r][H_ + e] + gh[r][H_ + e]);
        float n  = tanhf(gi[r][2 * H_ + e] + rr * gh[r][2 * H_ + e]);
        float hv = (1.f - z) * n + z * hs[r][e];
        hnew[r][e] = hv;
        h[(size_t)(b0 + r) * H_ + e] = hv;
    }
    __syncthreads();

    for (int o = tid; o < BR * E_; o += 256) {
        int r = o / E_, e = o % E_;
        const float4* wr = (const float4*)(spl_w + (size_t)e * H_);
        const float4* hr = (const float4*)&hnew[r][0];
        float s = spl_b[e];
#pragma unroll 9
        for (int e4 = 0; e4 < 36; e4++) {
            float4 wv = wr[e4], hv = hr[e4];
            s += hv.x * wv.x + hv.y * wv.y + hv.z * wv.z + hv.w * wv.w;
        }
        out[(size_t)(b0 + r) * (FUT_ * E_) + e] = s;
    }
}

// =================================================================================
extern "C" void kernel_launch(void* const* d_in, const int* in_sizes, int n_in,
                              void* d_out, int out_size, void* d_ws, size_t ws_size,
                              hipStream_t stream)
{
    const float* seed   = (const float*)d_in[0];
    const float* qkv_w  = (const float*)d_in[1];
    const float* qkv_b  = (const float*)d_in[2];
    const float* out_w  = (const float*)d_in[3];
    const float* out_b  = (const float*)d_in[4];
    const float* ln1_w  = (const float*)d_in[5];
    const float* ln1_b  = (const float*)d_in[6];
    const float* ffn1_w = (const float*)d_in[7];
    const float* ffn1_b = (const float*)d_in[8];
    const float* ffn2_w = (const float*)d_in[9];
    const float* ffn2_b = (const float*)d_in[10];
    const float* ln2_w  = (const float*)d_in[11];
    const float* ln2_b  = (const float*)d_in[12];
    const float* proj_w = (const float*)d_in[13];
    const float* proj_b = (const float*)d_in[14];
    const float* w_ih   = (const float*)d_in[15];
    const float* w_hh   = (const float*)d_in[16];
    const float* b_ih   = (const float*)d_in[17];
    const float* b_hh   = (const float*)d_in[18];
    const float* spl_w  = (const float*)d_in[19];
    const float* spl_b  = (const float*)d_in[20];

    // bf16 padded weight copies
    const size_t qkvW_n  = (size_t)L_ * TH_ * 160;
    const size_t outW_n  = (size_t)L_ * E_ * 160;
    const size_t ffn1W_n = (size_t)L_ * FF_ * 160;
    const size_t ffn2W_n = (size_t)L_ * E_ * 576;
    const size_t wbytes  = (qkvW_n + outW_n + ffn1W_n + ffn2W_n) * 2;

    const size_t persist = (size_t)B_ * 4 * (E_ + E_ + TH_ + H_) + wbytes;

    // per-chunk bytes/row: xbf(288) + xres(576) + qf(864) + ob(288) = 2016
    int nc = 16;
    for (int c = 1; c <= 16; c <<= 1) {
        size_t rows = (size_t)(B_ / c) * T_;
        size_t need = persist + rows * 2016;
        if (need <= ws_size) { nc = c; break; }
    }
    const int BC = B_ / nc;
    const int CR = BC * T_;

    char* wsp = (char*)d_ws;
    u16*   xbf   = (u16*)wsp;   wsp += (size_t)CR * E_ * 2;
    float* xres  = (float*)wsp; wsp += (size_t)CR * E_ * 4;
    u16*   qf    = (u16*)wsp;   wsp += (size_t)CR * TH_ * 2;
    u16*   ob    = (u16*)wsp;   wsp += (size_t)CR * E_ * 2;
    float* ctxm  = (float*)wsp; wsp += (size_t)B_ * E_ * 4;
    float* ctx   = (float*)wsp; wsp += (size_t)B_ * E_ * 4;
    float* gctx  = (float*)wsp; wsp += (size_t)B_ * TH_ * 4;
    float* h     = (float*)wsp; wsp += (size_t)B_ * H_ * 4;
    u16* qkvWb   = (u16*)wsp;   wsp += qkvW_n * 2;
    u16* outWb   = (u16*)wsp;   wsp += outW_n * 2;
    u16* ffn1Wb  = (u16*)wsp;   wsp += ffn1W_n * 2;
    u16* ffn2Wb  = (u16*)wsp;   wsp += ffn2W_n * 2;

    wconv_kernel<<<(int)((qkvW_n + 255) / 256), 256, 0, stream>>>(qkv_w, qkvWb, L_ * TH_, 144, 160);
    wconv_kernel<<<(int)((outW_n + 255) / 256), 256, 0, stream>>>(out_w, outWb, L_ * E_, 144, 160);
    wconv_kernel<<<(int)((ffn1W_n + 255) / 256), 256, 0, stream>>>(ffn1_w, ffn1Wb, L_ * FF_, 144, 160);
    wconv_kernel<<<(int)((ffn2W_n + 255) / 256), 256, 0, stream>>>(ffn2_w, ffn2Wb, L_ * E_, 576, 576);

    auto grid = [](int M, int N) { return dim3((N + 63) / 64, M / 64); };

    for (int c = 0; c < nc; c++) {
        const int b0 = c * BC;
        cast_bf_kernel<<<(CR * 72 + 255) / 256, 256, 0, stream>>>(
            seed + (size_t)b0 * T_ * E_, xbf, CR * 72);
        const float* resIn = seed + (size_t)b0 * T_ * E_;
        for (int l = 0; l < L_; l++) {
            gemm_mfma<u16><<<dim3(3, CR / 64), 192, 0, stream>>>(
                xbf, qkvWb + (size_t)l * TH_ * 160, qkv_b + (size_t)l * TH_,
                qf, CR, TH_);
            attn_kernel<<<BC * NH_, 256, 0, stream>>>(qf, ob);
            olnffn_kernel<<<CR / 64, 192, 0, stream>>>(
                ob, outWb + (size_t)l * E_ * 160, out_b + (size_t)l * E_, resIn,
                ln1_w + (size_t)l * E_, ln1_b + (size_t)l * E_,
                ffn1Wb + (size_t)l * FF_ * 160, ffn1_b + (size_t)l * FF_,
                ffn2Wb + (size_t)l * E_ * 576, ffn2_b + (size_t)l * E_,
                ln2_w + (size_t)l * E_, ln2_b + (size_t)l * E_, xbf, xres);
            resIn = xres;
        }
        mean_kernel<<<(BC * E_ + 255) / 256, 256, 0, stream>>>(xres, ctxm + (size_t)b0 * E_, BC);
    }

    gemm_kernel<float, float, true, false, false><<<grid(B_, E_), 256, 0, stream>>>(
        ctxm, proj_w, E_, proj_b, nullptr, ctx, B_, E_, E_);
    gemm_kernel<float, float, true, false, false><<<grid(B_, TH_), 256, 0, stream>>>(
        ctx, w_ih + E_, GIN_, b_ih, nullptr, gctx, B_, TH_, E_);
    zero_kernel<<<(B_ * H_ + 255) / 256, 256, 0, stream>>>(h, B_ * H_);

    float* out = (float*)d_out;
    for (int s = 0; s < FUT_; s++) {
        const float* inp = s ? (const float*)(out + (size_t)(s - 1) * E_)
                             : seed + (size_t)(T_ - 1) * E_;
        int istr = s ? FUT_ * E_ : T_ * E_;
        gru_step_kernel<<<B_ / 4, 256, 0, stream>>>(
            inp, istr, gctx, h, w_ih, w_hh, b_hh, spl_w, spl_b,
            out + (size_t)s * E_);
    }
}

// Round 8
// 2773.679 us; speedup vs baseline: 5.1032x; 2.0418x over previous
//
#include <hip/hip_runtime.h>

#define B_   2048
#define T_   120
#define E_   144
#define L_   4
#define NH_  8
#define HD_  18
#define FF_  576
#define H_   144
#define GIN_ 288
#define TH_  432   // 3*E = 3*H
#define FUT_ 24
#define BT_  (B_*T_)

typedef unsigned short u16;
typedef unsigned int   u32;

typedef __attribute__((ext_vector_type(8))) short short8v;  // 8 bf16 (4 VGPRs)
typedef __attribute__((ext_vector_type(4))) float f32x4;

__device__ __forceinline__ float bf2f(u16 u) {
    u32 x = ((u32)u) << 16;
    return __uint_as_float(x);
}
__device__ __forceinline__ u16 f2bf(float f) {
    u32 x = __float_as_uint(f);
    u32 r = (x + 0x7fffu + ((x >> 16) & 1u)) >> 16;
    return (u16)r;
}

struct F4 { float x, y, z, w; };

__device__ __forceinline__ F4 load4(const float* p) {
    float4 v = *(const float4*)p;
    return {v.x, v.y, v.z, v.w};
}
__device__ __forceinline__ void store1(float* p, float v) { *p = v; }
__device__ __forceinline__ void store1(u16* p, float v)   { *p = f2bf(v); }

// ---- async global->LDS, 16B per lane, wave-uniform LDS base ---------------------
__device__ __forceinline__ void gll16(const void* g, void* l) {
    __builtin_amdgcn_global_load_lds(
        (const __attribute__((address_space(1))) u32*)g,
        (__attribute__((address_space(3))) u32*)l, 16, 0, 0);
}

// stage 64 rows x 144 bf16 (contiguous, row stride 288B) into LDS rows of
// stride 168 u16 (=336B = 21 x 16B chunks). Chunk-linear in LDS. Pad chunks
// (col 18..20) duplicate chunk 17 (finite junk x zero weight-pad = 0).
__device__ __forceinline__ void stage64(const u16* src, u32* lds, int tid) {
    const char* base = (const char*)src;
    char* lbase = (char*)lds;
    const int w = tid >> 6, l = tid & 63;
#pragma unroll
    for (int i = 0; i < 7; ++i) {
        int inst  = w * 7 + i;            // 0..20
        int chunk = inst * 64 + l;        // 0..1343
        int row = chunk / 21;
        int col = chunk - row * 21;
        if (col > 17) col = 17;
        gll16(base + row * 288 + col * 16, lbase + inst * 1024);
    }
}

// ---------------- weight convert + K-pad to bf16 (src row stride sstr) ----------
__global__ void wconv_kernel(const float* __restrict__ src, u16* __restrict__ dst,
                             int rows, int K, int KP, int sstr)
{
    int i = blockIdx.x * 256 + threadIdx.x;
    if (i >= rows * KP) return;
    int r = i / KP, k = i - r * KP;
    dst[i] = (k < K) ? f2bf(src[(size_t)r * sstr + k]) : (u16)0;
}

// ---------------- f32 -> bf16 cast (paired) -------------------------------------
__global__ void cast_bf_kernel(const float* __restrict__ src, u16* __restrict__ dst,
                               int n2)
{
    int i = blockIdx.x * 256 + threadIdx.x;
    if (i >= n2) return;
    float2 t = ((const float2*)src)[i];
    ((u32*)dst)[i] = ((u32)f2bf(t.y) << 16) | (u32)f2bf(t.x);
}

// ---------------- MFMA GEMM: C[M,N] = A[M,K] @ Wb[N,160]^T (+bias) --------------
// 192 threads = 3 waves. Block tile 64 x 144. qkv projection (N=432).
template<typename OT>
__global__ __launch_bounds__(192) void gemm_mfma(
    const u16* __restrict__ A, const u16* __restrict__ Wb,
    const float* __restrict__ bias, OT* __restrict__ C, int M, int N)
{
    constexpr int RS32 = 84;
    __shared__ u32 lds[64 * RS32];

    const int tid = threadIdx.x;
    const int w   = tid >> 6;
    const int l   = tid & 63;
    const int lg  = l >> 4;
    const int li  = l & 15;
    const int bm  = blockIdx.y * 64;
    const int n0w = blockIdx.x * 144 + w * 48;

    f32x4 acc[4][3];
#pragma unroll
    for (int rt = 0; rt < 4; rt++)
#pragma unroll
        for (int ct = 0; ct < 3; ct++) acc[rt][ct] = {0.f, 0.f, 0.f, 0.f};

    stage64(A + (size_t)bm * 144, lds, tid);
    __syncthreads();

    const u16* lds16 = (const u16*)lds;
#pragma unroll
    for (int s = 0; s < 5; ++s) {
        short8v bf[3];
#pragma unroll
        for (int ct = 0; ct < 3; ++ct) {
            int n = n0w + ct * 16 + li;
            bf[ct] = *(const short8v*)(Wb + (size_t)n * 160 + s * 32 + lg * 8);
        }
        short8v af[4];
#pragma unroll
        for (int rt = 0; rt < 4; ++rt)
            af[rt] = *(const short8v*)(lds16 + (rt * 16 + li) * (2 * RS32) + s * 32 + lg * 8);
#pragma unroll
        for (int rt = 0; rt < 4; ++rt)
#pragma unroll
            for (int ct = 0; ct < 3; ++ct)
                acc[rt][ct] = __builtin_amdgcn_mfma_f32_16x16x32_bf16(
                    af[rt], bf[ct], acc[rt][ct], 0, 0, 0);
    }

#pragma unroll
    for (int ct = 0; ct < 3; ++ct) {
        int col = n0w + ct * 16 + li;
        float bv = bias[col];
#pragma unroll
        for (int rt = 0; rt < 4; ++rt) {
#pragma unroll
            for (int j = 0; j < 4; ++j) {
                int row = bm + rt * 16 + lg * 4 + j;
                store1(&C[(size_t)row * N + col], acc[rt][ct][j] + bv);
            }
        }
    }
}

// ======== fused: out-proj + bias + res + LN1 + FFN + res + LN2 -> bf16,f32 ======
// 192 thr (3 waves), 64 rows/block. ff in 6 chunks of 96 cols (low VGPR/LDS).
__global__ __launch_bounds__(192) void olnffn_kernel(
    const u16* __restrict__ ob, const u16* __restrict__ Wo,
    const float* __restrict__ ob_b, const float* __restrict__ res,
    const float* __restrict__ ln1w, const float* __restrict__ ln1b,
    const u16* __restrict__ W1, const float* __restrict__ b1,
    const u16* __restrict__ W2, const float* __restrict__ b2,
    const float* __restrict__ ln2w, const float* __restrict__ ln2b,
    u16* __restrict__ obf, float* __restrict__ of)
{
    constexpr int RSA = 84;    // A-buffer row stride (u32)
    constexpr int RSF = 52;    // ff 96-col chunk row stride (u32)
    __shared__ u32 Als[64 * RSA];   // 21504 B
    __shared__ u32 Fls[64 * RSF];   // 13312 B
    __shared__ float lnS[3][64], lnQ[3][64];  // 1536 B

    const int tid = threadIdx.x;
    const int w   = tid >> 6;
    const int l   = tid & 63;
    const int lg  = l >> 4;
    const int li  = l & 15;
    const int bm  = blockIdx.x * 64;

    stage64(ob + (size_t)bm * 144, Als, tid);
    __syncthreads();

    const u16* als16 = (const u16*)Als;
    u16* als16w = (u16*)Als;
    u16* fls16 = (u16*)Fls;

    // ---- out-proj MFMA ----
    f32x4 acc[4][3];
#pragma unroll
    for (int rt = 0; rt < 4; rt++)
#pragma unroll
        for (int ct = 0; ct < 3; ct++) acc[rt][ct] = {0.f, 0.f, 0.f, 0.f};
#pragma unroll
    for (int s = 0; s < 5; ++s) {
        short8v bf[3];
#pragma unroll
        for (int ct = 0; ct < 3; ++ct) {
            int n = w * 48 + ct * 16 + li;
            bf[ct] = *(const short8v*)(Wo + (size_t)n * 160 + s * 32 + lg * 8);
        }
        short8v af[4];
#pragma unroll
        for (int rt = 0; rt < 4; ++rt)
            af[rt] = *(const short8v*)(als16 + (rt * 16 + li) * (2 * RSA) + s * 32 + lg * 8);
#pragma unroll
        for (int rt = 0; rt < 4; ++rt)
#pragma unroll
            for (int ct = 0; ct < 3; ++ct)
                acc[rt][ct] = __builtin_amdgcn_mfma_f32_16x16x32_bf16(
                    af[rt], bf[ct], acc[rt][ct], 0, 0, 0);
    }

    // ---- + bias + residual ----
    float vv[4][3][4];
#pragma unroll
    for (int ct = 0; ct < 3; ++ct) {
        int col = w * 48 + ct * 16 + li;
        float bv = ob_b[col];
#pragma unroll
        for (int rt = 0; rt < 4; ++rt)
#pragma unroll
            for (int j = 0; j < 4; ++j) {
                int row = bm + rt * 16 + lg * 4 + j;
                vv[rt][ct][j] = acc[rt][ct][j] + bv + res[(size_t)row * E_ + col];
            }
    }
    // ---- LN1 cross-wave reduce ----
#pragma unroll
    for (int rt = 0; rt < 4; ++rt)
#pragma unroll
        for (int j = 0; j < 4; ++j) {
            float s = vv[rt][0][j] + vv[rt][1][j] + vv[rt][2][j];
            float q = vv[rt][0][j] * vv[rt][0][j] + vv[rt][1][j] * vv[rt][1][j]
                    + vv[rt][2][j] * vv[rt][2][j];
#pragma unroll
            for (int off = 1; off < 16; off <<= 1) {
                s += __shfl_xor(s, off);
                q += __shfl_xor(q, off);
            }
            if (li == 0) {
                lnS[w][rt * 16 + lg * 4 + j] = s;
                lnQ[w][rt * 16 + lg * 4 + j] = q;
            }
        }
    __syncthreads();   // also guarantees all Als reads (out-proj) retired
    // ---- LN1 apply: keep f32 in vv (= FFN residual), write bf16 into Als ----
#pragma unroll
    for (int rt = 0; rt < 4; ++rt)
#pragma unroll
        for (int j = 0; j < 4; ++j) {
            int r = rt * 16 + lg * 4 + j;
            float mean = (lnS[0][r] + lnS[1][r] + lnS[2][r]) * (1.f / 144.f);
            float var  = (lnQ[0][r] + lnQ[1][r] + lnQ[2][r]) * (1.f / 144.f) - mean * mean;
            float rstd = rsqrtf(var + 1e-5f);
#pragma unroll
            for (int ct = 0; ct < 3; ++ct) {
                int col = w * 48 + ct * 16 + li;
                float o = (vv[rt][ct][j] - mean) * rstd * ln1w[col] + ln1b[col];
                vv[rt][ct][j] = o;                       // res2, f32
                als16w[r * (2 * RSA) + col] = f2bf(o);   // ffn1 A (pads: junk*0)
            }
        }
    __syncthreads();

    // ---- FFN: 6 chunks of 96 ff-cols ----
    f32x4 acc2[4][3];
#pragma unroll
    for (int rt = 0; rt < 4; rt++)
#pragma unroll
        for (int ct = 0; ct < 3; ct++) acc2[rt][ct] = {0.f, 0.f, 0.f, 0.f};

    for (int c = 0; c < 6; ++c) {
        f32x4 acc1[4][2];
#pragma unroll
        for (int rt = 0; rt < 4; rt++)
#pragma unroll
            for (int ct = 0; ct < 2; ct++) acc1[rt][ct] = {0.f, 0.f, 0.f, 0.f};
#pragma unroll
        for (int s = 0; s < 5; ++s) {
            short8v bf[2];
#pragma unroll
            for (int ct = 0; ct < 2; ++ct) {
                int n1 = c * 96 + w * 32 + ct * 16 + li;
                bf[ct] = *(const short8v*)(W1 + (size_t)n1 * 160 + s * 32 + lg * 8);
            }
            short8v af[4];
#pragma unroll
            for (int rt = 0; rt < 4; ++rt)
                af[rt] = *(const short8v*)(als16 + (rt * 16 + li) * (2 * RSA) + s * 32 + lg * 8);
#pragma unroll
            for (int rt = 0; rt < 4; ++rt)
#pragma unroll
                for (int ct = 0; ct < 2; ++ct)
                    acc1[rt][ct] = __builtin_amdgcn_mfma_f32_16x16x32_bf16(
                        af[rt], bf[ct], acc1[rt][ct], 0, 0, 0);
        }
        __syncthreads();   // prev-chunk ffn2 reads of Fls complete
#pragma unroll
        for (int ct = 0; ct < 2; ++ct) {
            int colc = w * 32 + ct * 16 + li;
            float bv = b1[c * 96 + colc];
#pragma unroll
            for (int rt = 0; rt < 4; ++rt)
#pragma unroll
                for (int j = 0; j < 4; ++j) {
                    int row = rt * 16 + lg * 4 + j;
                    float v = fmaxf(acc1[rt][ct][j] + bv, 0.f);
                    fls16[row * (2 * RSF) + colc] = f2bf(v);
                }
        }
        __syncthreads();
#pragma unroll
        for (int s2 = 0; s2 < 3; ++s2) {
            short8v wf[3];
#pragma unroll
            for (int ct = 0; ct < 3; ++ct) {
                int n2 = w * 48 + ct * 16 + li;
                wf[ct] = *(const short8v*)(W2 + (size_t)n2 * 576 + c * 96 + s2 * 32 + lg * 8);
            }
            short8v pf[4];
#pragma unroll
            for (int rt = 0; rt < 4; ++rt)
                pf[rt] = *(const short8v*)(fls16 + (rt * 16 + li) * (2 * RSF) + s2 * 32 + lg * 8);
#pragma unroll
            for (int rt = 0; rt < 4; ++rt)
#pragma unroll
                for (int ct = 0; ct < 3; ++ct)
                    acc2[rt][ct] = __builtin_amdgcn_mfma_f32_16x16x32_bf16(
                        pf[rt], wf[ct], acc2[rt][ct], 0, 0, 0);
        }
    }

    // ---- epilogue: + b2 + res2(regs) -> LN2 -> write bf16 + f32 ----
    float v2[4][3][4];
#pragma unroll
    for (int ct = 0; ct < 3; ++ct) {
        int col = w * 48 + ct * 16 + li;
        float bv = b2[col];
#pragma unroll
        for (int rt = 0; rt < 4; ++rt)
#pragma unroll
            for (int j = 0; j < 4; ++j)
                v2[rt][ct][j] = acc2[rt][ct][j] + bv + vv[rt][ct][j];
    }
#pragma unroll
    for (int rt = 0; rt < 4; ++rt)
#pragma unroll
        for (int j = 0; j < 4; ++j) {
            float s = v2[rt][0][j] + v2[rt][1][j] + v2[rt][2][j];
            float q = v2[rt][0][j] * v2[rt][0][j] + v2[rt][1][j] * v2[rt][1][j]
                    + v2[rt][2][j] * v2[rt][2][j];
#pragma unroll
            for (int off = 1; off < 16; off <<= 1) {
                s += __shfl_xor(s, off);
                q += __shfl_xor(q, off);
            }
            if (li == 0) {
                lnS[w][rt * 16 + lg * 4 + j] = s;
                lnQ[w][rt * 16 + lg * 4 + j] = q;
            }
        }
    __syncthreads();
#pragma unroll
    for (int rt = 0; rt < 4; ++rt)
#pragma unroll
        for (int j = 0; j < 4; ++j) {
            int r = rt * 16 + lg * 4 + j;
            float mean = (lnS[0][r] + lnS[1][r] + lnS[2][r]) * (1.f / 144.f);
            float var  = (lnQ[0][r] + lnQ[1][r] + lnQ[2][r]) * (1.f / 144.f) - mean * mean;
            float rstd = rsqrtf(var + 1e-5f);
            int row = bm + r;
#pragma unroll
            for (int ct = 0; ct < 3; ++ct) {
                int col = w * 48 + ct * 16 + li;
                float o = (v2[rt][ct][j] - mean) * rstd * ln2w[col] + ln2b[col];
                obf[(size_t)row * E_ + col] = f2bf(o);
                of[(size_t)row * E_ + col]  = o;
            }
        }
}

// ---------------- f32 GEMM (small, ctx path): C = A @ W^T + bias ----------------
template<typename AT, typename OT, bool BIAS, bool RELU, bool RES>
__global__ __launch_bounds__(256) void gemm_kernel(
    const AT* __restrict__ A, const float* __restrict__ W, int ldw,
    const float* __restrict__ bias, const float* __restrict__ res,
    OT* __restrict__ C, int M, int N, int K)
{
    constexpr int BM = 64, BN = 64, BK = 16;
    __shared__ float As[BK][BM + 4];
    __shared__ float Ws[BK][BN + 4];
    const int tid = threadIdx.x;
    const int bm = blockIdx.y * BM;
    const int bn = blockIdx.x * BN;
    const int tx = tid & 15, ty = tid >> 4;
    const int lr = tid >> 2;
    const int lc = (tid & 3) << 2;

    float acc[4][4];
#pragma unroll
    for (int i = 0; i < 4; i++)
#pragma unroll
        for (int j = 0; j < 4; j++) acc[i][j] = 0.f;

    for (int k0 = 0; k0 < K; k0 += BK) {
        F4 av = load4(A + (size_t)(bm + lr) * K + k0 + lc);
        As[lc + 0][lr] = av.x; As[lc + 1][lr] = av.y;
        As[lc + 2][lr] = av.z; As[lc + 3][lr] = av.w;
        int n = bn + lr;
        F4 wv = {0.f, 0.f, 0.f, 0.f};
        if (n < N) {
            float4 t = *(const float4*)(W + (size_t)n * ldw + k0 + lc);
            wv = {t.x, t.y, t.z, t.w};
        }
        Ws[lc + 0][lr] = wv.x; Ws[lc + 1][lr] = wv.y;
        Ws[lc + 2][lr] = wv.z; Ws[lc + 3][lr] = wv.w;
        __syncthreads();
#pragma unroll
        for (int kk = 0; kk < BK; ++kk) {
            float a[4], wr[4];
#pragma unroll
            for (int i = 0; i < 4; i++) a[i] = As[kk][ty * 4 + i];
#pragma unroll
            for (int j = 0; j < 4; j++) wr[j] = Ws[kk][tx * 4 + j];
#pragma unroll
            for (int i = 0; i < 4; i++)
#pragma unroll
                for (int j = 0; j < 4; j++) acc[i][j] += a[i] * wr[j];
        }
        __syncthreads();
    }
#pragma unroll
    for (int i = 0; i < 4; i++) {
        int m = bm + ty * 4 + i;
#pragma unroll
        for (int j = 0; j < 4; j++) {
            int n = bn + tx * 4 + j;
            if (n < N) {
                float v = acc[i][j];
                if (BIAS) v += bias[n];
                if (RES)  v += res[(size_t)m * N + n];
                if (RELU) v = fmaxf(v, 0.f);
                store1(&C[(size_t)m * N + n], v);
            }
        }
    }
}

// ---------------- MFMA attention: one block (4 waves) per (b, head) -------------
__global__ __launch_bounds__(256) void attn_kernel(const u16* __restrict__ qkv,
                                                   u16* __restrict__ o)
{
    constexpr int QS = 40;
    constexpr int VS = 136;
    __shared__ __align__(16) u16 Qs[128 * QS];
    __shared__ __align__(16) u16 Ks[128 * QS];
    __shared__ __align__(16) u16 Vt[32 * VS];
    __shared__ __align__(16) u16 Ps[4][16 * VS];

    const int bh = blockIdx.x;
    const int b = bh >> 3, h = bh & 7;
    const int tid = threadIdx.x;
    const int w = tid >> 6, l = tid & 63;
    const int lg = l >> 4, li = l & 15;

    {
        u32* z1 = (u32*)Qs;
        for (int i = tid; i < 128 * QS / 2; i += 256) z1[i] = 0;
        u32* z2 = (u32*)Ks;
        for (int i = tid; i < 128 * QS / 2; i += 256) z2[i] = 0;
        u32* z3 = (u32*)Vt;
        for (int i = tid; i < 32 * VS / 2; i += 256) z3[i] = 0;
    }
    __syncthreads();

    const u32* q32 = (const u32*)(qkv + (size_t)b * T_ * TH_);
    for (int idx = tid; idx < 120 * 9; idx += 256) {
        int t = idx / 9, dp = idx - t * 9;
        u32 qv = q32[t * 216 + 9 * h + dp];
        u32 kv = q32[t * 216 + 72 + 9 * h + dp];
        u32 vv = q32[t * 216 + 144 + 9 * h + dp];
        ((u32*)(Qs + t * QS))[dp] = qv;
        ((u32*)(Ks + t * QS))[dp] = kv;
        Vt[(2 * dp) * VS + t]     = (u16)(vv & 0xffffu);
        Vt[(2 * dp + 1) * VS + t] = (u16)(vv >> 16);
    }
    __syncthreads();

    const float scale = 0.23570226039551584f; // 1/sqrt(18)
    u16* pw = &Ps[w][0];

    for (int mt = w * 2; mt < w * 2 + 2; ++mt) {
        short8v qf = *(const short8v*)(Qs + (mt * 16 + li) * QS + lg * 8);
        f32x4 sacc[8];
#pragma unroll
        for (int nt = 0; nt < 8; ++nt) sacc[nt] = {0.f, 0.f, 0.f, 0.f};
#pragma unroll
        for (int nt = 0; nt < 8; ++nt) {
            short8v kf = *(const short8v*)(Ks + (nt * 16 + li) * QS + lg * 8);
            sacc[nt] = __builtin_amdgcn_mfma_f32_16x16x32_bf16(qf, kf, sacc[nt], 0, 0, 0);
        }

        float invl[4];
#pragma unroll
        for (int j = 0; j < 4; ++j) {
            float v[8];
            float m = -1e30f;
#pragma unroll
            for (int nt = 0; nt < 8; ++nt) {
                float s = sacc[nt][j] * scale;
                if (nt == 7 && li >= 8) s = -1e30f;
                v[nt] = s;
                m = fmaxf(m, s);
            }
#pragma unroll
            for (int off = 1; off < 16; off <<= 1)
                m = fmaxf(m, __shfl_xor(m, off));
            float sum = 0.f;
#pragma unroll
            for (int nt = 0; nt < 8; ++nt) {
                float p = __expf(v[nt] - m);
                sum += p;
                pw[(lg * 4 + j) * VS + nt * 16 + li] = f2bf(p);
            }
#pragma unroll
            for (int off = 1; off < 16; off <<= 1)
                sum += __shfl_xor(sum, off);
            invl[j] = 1.f / sum;
        }

        f32x4 oacc[2] = {{0.f,0.f,0.f,0.f},{0.f,0.f,0.f,0.f}};
#pragma unroll
        for (int s = 0; s < 4; ++s) {
            short8v pf = *(const short8v*)(pw + li * VS + s * 32 + lg * 8);
#pragma unroll
            for (int dt = 0; dt < 2; ++dt) {
                short8v vf = *(const short8v*)(Vt + (dt * 16 + li) * VS + s * 32 + lg * 8);
                oacc[dt] = __builtin_amdgcn_mfma_f32_16x16x32_bf16(pf, vf, oacc[dt], 0, 0, 0);
            }
        }

        const int q0 = mt * 16 + lg * 4;
#pragma unroll
        for (int dt = 0; dt < 2; ++dt) {
            int d = dt * 16 + li;
            if (d < HD_) {
#pragma unroll
                for (int j = 0; j < 4; ++j) {
                    int q = q0 + j;
                    if (q < T_)
                        o[((size_t)b * T_ + q) * E_ + h * HD_ + d] =
                            f2bf(oacc[dt][j] * invl[j]);
                }
            }
        }
    }
}

// ---------------- mean over T (one chunk of nb batches) -------------------------
__global__ void mean_kernel(const float* __restrict__ x, float* __restrict__ out,
                            int nb)
{
    int idx = blockIdx.x * blockDim.x + threadIdx.x;
    if (idx >= nb * E_) return;
    int b = idx / E_, e = idx % E_;
    const float* p = x + (size_t)b * T_ * E_ + e;
    float s = 0.f;
    for (int t = 0; t < T_; t++) s += p[(size_t)t * E_];
    out[idx] = s * (1.f / 120.f);
}

__device__ __forceinline__ float sigmoidf_(float x) {
    return 1.f / (1.f + __expf(-x));
}

// ======== persistent GRU decode: all 24 steps in one kernel =====================
// Rows are independent across the recurrence -> block owns 16 batch rows for all
// steps. h kept f32 in registers (exact recurrence); MFMA inputs bf16 in LDS.
// 192 threads = 3 waves; wave w owns cols w*48..w*48+47 (per gate / output).
#define GRU_M 16
__global__ __launch_bounds__(192) void gru_all_kernel(
    const float* __restrict__ seed,      // inp0 = seed[:, T-1, :]
    const float* __restrict__ gctx,      // [B,432] ctx-half + b_ih
    const u16* __restrict__ WxB,         // [432,160] w_ih[:, :144] bf16
    const u16* __restrict__ WhB,         // [432,160] w_hh bf16
    const u16* __restrict__ SpB,         // [144,160] spl_w bf16
    const float* __restrict__ b_hh,
    const float* __restrict__ spl_b,
    float* __restrict__ out)             // [B, FUT, 144]
{
    __shared__ __align__(16) u16 xls[GRU_M * 168];
    __shared__ __align__(16) u16 hls[GRU_M * 168];

    const int tid = threadIdx.x;
    const int w = tid >> 6, l = tid & 63;
    const int lg = l >> 4, li = l & 15;
    const int b0 = blockIdx.x * GRU_M;
    const int fr = w * 48 + li;          // col base (+ct*16)

    for (int i = tid; i < GRU_M * 84; i += 192) {
        ((u32*)xls)[i] = 0; ((u32*)hls)[i] = 0;
    }
    __syncthreads();
    for (int i = tid; i < GRU_M * 72; i += 192) {
        int r = i / 72, e2 = i - r * 72;
        float2 t = *(const float2*)(seed + (size_t)(b0 + r) * T_ * E_
                                    + (size_t)(T_ - 1) * E_ + 2 * e2);
        ((u32*)(xls + r * 168))[e2] = ((u32)f2bf(t.y) << 16) | (u32)f2bf(t.x);
    }

    float gctxv[3][3][4];
    float bhh[3][3];
    float splb[3];
#pragma unroll
    for (int g = 0; g < 3; ++g)
#pragma unroll
        for (int ct = 0; ct < 3; ++ct) {
            int f = g * 144 + fr + ct * 16;
            bhh[g][ct] = b_hh[f];
#pragma unroll
            for (int j = 0; j < 4; ++j)
                gctxv[g][ct][j] = gctx[(size_t)(b0 + lg * 4 + j) * TH_ + f];
        }
#pragma unroll
    for (int ct = 0; ct < 3; ++ct) splb[ct] = spl_b[fr + ct * 16];

    float hold[3][4];
#pragma unroll
    for (int ct = 0; ct < 3; ++ct)
#pragma unroll
        for (int j = 0; j < 4; ++j) hold[ct][j] = 0.f;

    __syncthreads();

    for (int st = 0; st < FUT_; ++st) {
        f32x4 aRZ[2][3], aNi[3], aNh[3];
#pragma unroll
        for (int g = 0; g < 2; ++g)
#pragma unroll
            for (int ct = 0; ct < 3; ++ct) aRZ[g][ct] = {0.f, 0.f, 0.f, 0.f};
#pragma unroll
        for (int ct = 0; ct < 3; ++ct) {
            aNi[ct] = {0.f, 0.f, 0.f, 0.f};
            aNh[ct] = {0.f, 0.f, 0.f, 0.f};
        }
#pragma unroll
        for (int s = 0; s < 5; ++s) {
            short8v ax = *(const short8v*)(xls + li * 168 + s * 32 + lg * 8);
            short8v ah = *(const short8v*)(hls + li * 168 + s * 32 + lg * 8);
#pragma unroll
            for (int ct = 0; ct < 3; ++ct) {
#pragma unroll
                for (int g = 0; g < 2; ++g) {
                    int f = g * 144 + fr + ct * 16;
                    short8v bx = *(const short8v*)(WxB + (size_t)f * 160 + s * 32 + lg * 8);
                    aRZ[g][ct] = __builtin_amdgcn_mfma_f32_16x16x32_bf16(ax, bx, aRZ[g][ct], 0, 0, 0);
                    short8v bh = *(const short8v*)(WhB + (size_t)f * 160 + s * 32 + lg * 8);
                    aRZ[g][ct] = __builtin_amdgcn_mfma_f32_16x16x32_bf16(ah, bh, aRZ[g][ct], 0, 0, 0);
                }
                int f2 = 288 + fr + ct * 16;
                short8v bx2 = *(const short8v*)(WxB + (size_t)f2 * 160 + s * 32 + lg * 8);
                aNi[ct] = __builtin_amdgcn_mfma_f32_16x16x32_bf16(ax, bx2, aNi[ct], 0, 0, 0);
                short8v bh2 = *(const short8v*)(WhB + (size_t)f2 * 160 + s * 32 + lg * 8);
                aNh[ct] = __builtin_amdgcn_mfma_f32_16x16x32_bf16(ah, bh2, aNh[ct], 0, 0, 0);
            }
        }
        __syncthreads();   // all xls/hls reads retired before hls overwrite
#pragma unroll
        for (int ct = 0; ct < 3; ++ct)
#pragma unroll
            for (int j = 0; j < 4; ++j) {
                float r = sigmoidf_(aRZ[0][ct][j] + gctxv[0][ct][j] + bhh[0][ct]);
                float z = sigmoidf_(aRZ[1][ct][j] + gctxv[1][ct][j] + bhh[1][ct]);
                float n = tanhf(aNi[ct][j] + gctxv[2][ct][j]
                                + r * (aNh[ct][j] + bhh[2][ct]));
                float hv = (1.f - z) * n + z * hold[ct][j];
                hold[ct][j] = hv;
                hls[(lg * 4 + j) * 168 + fr + ct * 16] = f2bf(hv);
            }
        __syncthreads();
        // spl projection: rot = h_new @ spl^T + spl_b
        f32x4 aS[3];
#pragma unroll
        for (int ct = 0; ct < 3; ++ct) aS[ct] = {0.f, 0.f, 0.f, 0.f};
#pragma unroll
        for (int s = 0; s < 5; ++s) {
            short8v ah = *(const short8v*)(hls + li * 168 + s * 32 + lg * 8);
#pragma unroll
            for (int ct = 0; ct < 3; ++ct) {
                short8v bs = *(const short8v*)(SpB + (size_t)(fr + ct * 16) * 160 + s * 32 + lg * 8);
                aS[ct] = __builtin_amdgcn_mfma_f32_16x16x32_bf16(ah, bs, aS[ct], 0, 0, 0);
            }
        }
#pragma unroll
        for (int ct = 0; ct < 3; ++ct) {
            int col = fr + ct * 16;
#pragma unroll
            for (int j = 0; j < 4; ++j) {
                float rv = aS[ct][j] + splb[ct];
                out[(size_t)(b0 + lg * 4 + j) * (FUT_ * E_) + (size_t)st * E_ + col] = rv;
                xls[(lg * 4 + j) * 168 + col] = f2bf(rv);   // next step's input
            }
        }
        __syncthreads();
    }
}

// =================================================================================
extern "C" void kernel_launch(void* const* d_in, const int* in_sizes, int n_in,
                              void* d_out, int out_size, void* d_ws, size_t ws_size,
                              hipStream_t stream)
{
    const float* seed   = (const float*)d_in[0];
    const float* qkv_w  = (const float*)d_in[1];
    const float* qkv_b  = (const float*)d_in[2];
    const float* out_w  = (const float*)d_in[3];
    const float* out_b  = (const float*)d_in[4];
    const float* ln1_w  = (const float*)d_in[5];
    const float* ln1_b  = (const float*)d_in[6];
    const float* ffn1_w = (const float*)d_in[7];
    const float* ffn1_b = (const float*)d_in[8];
    const float* ffn2_w = (const float*)d_in[9];
    const float* ffn2_b = (const float*)d_in[10];
    const float* ln2_w  = (const float*)d_in[11];
    const float* ln2_b  = (const float*)d_in[12];
    const float* proj_w = (const float*)d_in[13];
    const float* proj_b = (const float*)d_in[14];
    const float* w_ih   = (const float*)d_in[15];
    const float* w_hh   = (const float*)d_in[16];
    const float* b_ih   = (const float*)d_in[17];
    const float* b_hh   = (const float*)d_in[18];
    const float* spl_w  = (const float*)d_in[19];
    const float* spl_b  = (const float*)d_in[20];

    // bf16 padded weight copies
    const size_t qkvW_n  = (size_t)L_ * TH_ * 160;
    const size_t outW_n  = (size_t)L_ * E_ * 160;
    const size_t ffn1W_n = (size_t)L_ * FF_ * 160;
    const size_t ffn2W_n = (size_t)L_ * E_ * 576;
    const size_t wxW_n   = (size_t)TH_ * 160;
    const size_t whW_n   = (size_t)TH_ * 160;
    const size_t spW_n   = (size_t)E_ * 160;
    const size_t wbytes  = (qkvW_n + outW_n + ffn1W_n + ffn2W_n
                            + wxW_n + whW_n + spW_n) * 2;

    const size_t persist = (size_t)B_ * 4 * (E_ + E_ + TH_) + wbytes;

    // per-chunk bytes/row: xbf(288) + xres(576) + qf(864) + ob(288) = 2016
    int nc = 16;
    for (int c = 1; c <= 16; c <<= 1) {
        size_t rows = (size_t)(B_ / c) * T_;
        size_t need = persist + rows * 2016;
        if (need <= ws_size) { nc = c; break; }
    }
    const int BC = B_ / nc;
    const int CR = BC * T_;

    char* wsp = (char*)d_ws;
    u16*   xbf   = (u16*)wsp;   wsp += (size_t)CR * E_ * 2;
    float* xres  = (float*)wsp; wsp += (size_t)CR * E_ * 4;
    u16*   qf    = (u16*)wsp;   wsp += (size_t)CR * TH_ * 2;
    u16*   ob    = (u16*)wsp;   wsp += (size_t)CR * E_ * 2;
    float* ctxm  = (float*)wsp; wsp += (size_t)B_ * E_ * 4;
    float* ctx   = (float*)wsp; wsp += (size_t)B_ * E_ * 4;
    float* gctx  = (float*)wsp; wsp += (size_t)B_ * TH_ * 4;
    u16* qkvWb   = (u16*)wsp;   wsp += qkvW_n * 2;
    u16* outWb   = (u16*)wsp;   wsp += outW_n * 2;
    u16* ffn1Wb  = (u16*)wsp;   wsp += ffn1W_n * 2;
    u16* ffn2Wb  = (u16*)wsp;   wsp += ffn2W_n * 2;
    u16* wxB     = (u16*)wsp;   wsp += wxW_n * 2;
    u16* whB     = (u16*)wsp;   wsp += whW_n * 2;
    u16* splWb   = (u16*)wsp;   wsp += spW_n * 2;

    wconv_kernel<<<(int)((qkvW_n + 255) / 256), 256, 0, stream>>>(qkv_w, qkvWb, L_ * TH_, 144, 160, 144);
    wconv_kernel<<<(int)((outW_n + 255) / 256), 256, 0, stream>>>(out_w, outWb, L_ * E_, 144, 160, 144);
    wconv_kernel<<<(int)((ffn1W_n + 255) / 256), 256, 0, stream>>>(ffn1_w, ffn1Wb, L_ * FF_, 144, 160, 144);
    wconv_kernel<<<(int)((ffn2W_n + 255) / 256), 256, 0, stream>>>(ffn2_w, ffn2Wb, L_ * E_, 576, 576, 576);
    wconv_kernel<<<(int)((wxW_n + 255) / 256), 256, 0, stream>>>(w_ih, wxB, TH_, 144, 160, GIN_);
    wconv_kernel<<<(int)((whW_n + 255) / 256), 256, 0, stream>>>(w_hh, whB, TH_, 144, 160, 144);
    wconv_kernel<<<(int)((spW_n + 255) / 256), 256, 0, stream>>>(spl_w, splWb, E_, 144, 160, 144);

    auto grid = [](int M, int N) { return dim3((N + 63) / 64, M / 64); };

    for (int c = 0; c < nc; c++) {
        const int b0 = c * BC;
        cast_bf_kernel<<<(CR * 72 + 255) / 256, 256, 0, stream>>>(
            seed + (size_t)b0 * T_ * E_, xbf, CR * 72);
        const float* resIn = seed + (size_t)b0 * T_ * E_;
        for (int l = 0; l < L_; l++) {
            gemm_mfma<u16><<<dim3(3, CR / 64), 192, 0, stream>>>(
                xbf, qkvWb + (size_t)l * TH_ * 160, qkv_b + (size_t)l * TH_,
                qf, CR, TH_);
            attn_kernel<<<BC * NH_, 256, 0, stream>>>(qf, ob);
            olnffn_kernel<<<CR / 64, 192, 0, stream>>>(
                ob, outWb + (size_t)l * E_ * 160, out_b + (size_t)l * E_, resIn,
                ln1_w + (size_t)l * E_, ln1_b + (size_t)l * E_,
                ffn1Wb + (size_t)l * FF_ * 160, ffn1_b + (size_t)l * FF_,
                ffn2Wb + (size_t)l * E_ * 576, ffn2_b + (size_t)l * E_,
                ln2_w + (size_t)l * E_, ln2_b + (size_t)l * E_, xbf, xres);
            resIn = xres;
        }
        mean_kernel<<<(BC * E_ + 255) / 256, 256, 0, stream>>>(xres, ctxm + (size_t)b0 * E_, BC);
    }

    gemm_kernel<float, float, true, false, false><<<grid(B_, E_), 256, 0, stream>>>(
        ctxm, proj_w, E_, proj_b, nullptr, ctx, B_, E_, E_);
    gemm_kernel<float, float, true, false, false><<<grid(B_, TH_), 256, 0, stream>>>(
        ctx, w_ih + E_, GIN_, b_ih, nullptr, gctx, B_, TH_, E_);

    gru_all_kernel<<<B_ / GRU_M, 192, 0, stream>>>(
        seed, gctx, wxB, whB, splWb, b_hh, spl_b, (float*)d_out);
}